// Round 12
// baseline (765.523 us; speedup 1.0000x reference)
//
#include <hip/hip_runtime.h>
#include <hip/hip_bf16.h>
#include <cmath>

#define BB 512
#define CC 128
#define HW 225
#define CIP 136     // ushort stride of D2 [px][ci] rows (272 B)
#define CIPH 40     // ushort stride for 32-ch hidden rows
#define NPMAX 2048  // max partial-stat blocks

typedef __attribute__((ext_vector_type(8))) short short8;
typedef __attribute__((ext_vector_type(4))) float f32x4;
typedef __attribute__((ext_vector_type(4))) unsigned short us4;

union U8 { unsigned short u[8]; short8 v; };

__device__ __forceinline__ unsigned short f2bf(float v) {
  __hip_bfloat16 h = __float2bfloat16(v);
  return *(unsigned short*)&h;
}
__device__ __forceinline__ float bf2f(unsigned short u) {
  __hip_bfloat16 h = *(__hip_bfloat16*)&u;
  return __bfloat162float(h);
}

template<int NT>
__device__ __forceinline__ float br_max(float v, float* red, int t) {
  red[t] = v; __syncthreads();
  for (int st = NT/2; st > 0; st >>= 1) { if (t < st) red[t] = fmaxf(red[t], red[t+st]); __syncthreads(); }
  float r = red[0]; __syncthreads();
  return r;
}
template<int NT>
__device__ __forceinline__ float br_sum(float v, float* red, int t) {
  red[t] = v; __syncthreads();
  for (int st = NT/2; st > 0; st >>= 1) { if (t < st) red[t] += red[t+st]; __syncthreads(); }
  float r = red[0]; __syncthreads();
  return r;
}

// finalize fused per-block partials ps/pq[c][NPMAX], np valid slots
__global__ __launch_bounds__(256) void k_bnfin2(const float* __restrict__ ps, const float* __restrict__ pq,
                         int np,
                         const float* __restrict__ g, const float* __restrict__ bt,
                         float* __restrict__ scale, float* __restrict__ shift) {
  int c = blockIdx.x, t = threadIdx.x;
  __shared__ float rs[256], rq[256];
  float s = 0.f, q = 0.f;
  for (int i = t; i < np; i += 256) { s += ps[(size_t)c*NPMAX + i]; q += pq[(size_t)c*NPMAX + i]; }
  rs[t] = s; rq[t] = q; __syncthreads();
  for (int st = 128; st > 0; st >>= 1) { if (t < st) { rs[t]+=rs[t+st]; rq[t]+=rq[t+st]; } __syncthreads(); }
  if (t == 0) {
    const float N = (float)BB*HW;
    float mean = rs[0]/N, var = rq[0]/N - mean*mean;
    float sc = g[c]*rsqrtf(var + 1e-5f);
    scale[c] = sc; shift[c] = bt[c] - mean*sc;
  }
}

// ---------- attn1 stage A: per (image, ch-group) pixel partials ----------
__global__ __launch_bounds__(256) void k_at1a(const float* __restrict__ x1, const float* __restrict__ x2,
                       float* __restrict__ part) {
  int b = blockIdx.x, cg = blockIdx.y, t = threadIdx.x;
  __shared__ float cent[32];
  const float* xb1 = x1 + (size_t)b*64*HW;
  const float* xb2 = x2 + (size_t)b*64*HW;
  if (t < 32) { int c = cg*32 + t; cent[t] = (c < 64) ? xb1[c*HW + 112] : xb2[(c-64)*HW + 112]; }
  __syncthreads();
  if (t < HW) {
    float e2 = 0.f, dot = 0.f, qn2 = 0.f;
    for (int k = 0; k < 32; ++k) {
      int c = cg*32 + k;
      float xv = (c < 64) ? xb1[c*HW + t] : xb2[(c-64)*HW + t];
      float ce = cent[k];
      float d = xv - ce;
      e2 += d*d; dot += xv*ce; qn2 += xv*xv;
    }
    size_t base = ((size_t)(b*4 + cg)*3)*256;
    part[base + t] = e2; part[base + 256 + t] = dot; part[base + 512 + t] = qn2;
  }
}

// ---------- attn1 stage B: combine + dual softmax -> am[b][p] ----------
__global__ __launch_bounds__(256) void k_at1b(const float* __restrict__ x1, const float* __restrict__ x2,
                       const float* __restrict__ part, const float* __restrict__ lam,
                       float* __restrict__ am) {
  int b = blockIdx.x, t = threadIdx.x;
  __shared__ float red[256];
  float cv = 0.f;
  if (t < CC) {
    float ce = (t < 64) ? x1[(size_t)b*64*HW + t*HW + 112] : x2[(size_t)b*64*HW + (t-64)*HW + 112];
    cv = ce*ce;
  }
  float cn2 = br_sum<256>(cv, red, t);
  float e2 = 0.f, dot = 0.f, qn2 = 0.f;
  if (t < HW) {
    #pragma unroll
    for (int cg = 0; cg < 4; ++cg) {
      size_t base = ((size_t)(b*4 + cg)*3)*256;
      e2 += part[base + t]; dot += part[base + 256 + t]; qn2 += part[base + 512 + t];
    }
  }
  float sim_e = 0.f, sim_c = 0.f;
  if (t < HW) {
    sim_e = 1.f/(1.f + sqrtf(e2));
    float qn = sqrtf(qn2), cn = sqrtf(cn2);
    sim_c = dot / (fmaxf(cn, 1e-8f) * fmaxf(qn, 1e-8f));
  }
  float m1 = br_max<256>((t<HW)? sim_e : -1e30f, red, t);
  float e1v = (t<HW)? expf(sim_e - m1) : 0.f;
  float s1 = br_sum<256>(e1v, red, t);
  float m2 = br_max<256>((t<HW)? sim_c : -1e30f, red, t);
  float e2v = (t<HW)? expf(sim_c - m2) : 0.f;
  float s2 = br_sum<256>(e2v, red, t);
  float lmd = 1.f/(1.f + expf(-lam[0]));
  if (t < HW) am[(size_t)b*HW + t] = 1.f + lmd*e1v/s1 + (1.f - lmd)*e2v/s2;
}

// ---------- attn1 stage C: A = x*am (+ fused bn1 partials per 32-ch group) ----------
__global__ __launch_bounds__(256) void k_at1c(const float* __restrict__ x1, const float* __restrict__ x2,
                       const float* __restrict__ am, float* __restrict__ A,
                       float* __restrict__ ps, float* __restrict__ pq) {
  int b = blockIdx.x, cg = blockIdx.y, t = threadIdx.x;
  __shared__ float pS[4][32], pQ[4][32];
  const float* xb1 = x1 + (size_t)b*64*HW;
  const float* xb2 = x2 + (size_t)b*64*HW;
  float* Ab = A + (size_t)b*CC*HW;
  float amv = (t < HW) ? am[(size_t)b*HW + t] : 0.f;
  int w = t >> 6, lane = t & 63;
  for (int k = 0; k < 32; ++k) {
    int c = cg*32 + k;
    float xv = 0.f;
    if (t < HW) xv = (c < 64) ? xb1[c*HW + t] : xb2[(c-64)*HW + t];
    float val = xv*amv;
    if (t < HW) Ab[(size_t)c*HW + t] = val;
    float s = val, q = val*val;
    #pragma unroll
    for (int m = 1; m < 64; m <<= 1) { s += __shfl_xor(s, m); q += __shfl_xor(q, m); }
    if (lane == 0) { pS[w][k] = s; pQ[w][k] = q; }
  }
  __syncthreads();
  if (t < 32) {
    int c = cg*32 + t;
    ps[(size_t)c*NPMAX + b] = pS[0][t]+pS[1][t]+pS[2][t]+pS[3][t];
    pq[(size_t)c*NPMAX + b] = pQ[0][t]+pQ[1][t]+pQ[2][t]+pQ[3][t];
  }
}

// ---------- merged weight pre-pack (layouts unchanged) ----------
__global__ __launch_bounds__(256) void k_prep_all(
    const float* __restrict__ sa_w1, const float* __restrict__ sa_w2,
    const float* __restrict__ pW1, const float* __restrict__ pW2,
    const float* __restrict__ qkvW, const float* __restrict__ ca_w1, const float* __restrict__ ca_w2,
    unsigned short* __restrict__ Wa, unsigned short* __restrict__ Wb,
    unsigned short* __restrict__ W1h, unsigned short* __restrict__ W1l,
    unsigned short* __restrict__ W2h, unsigned short* __restrict__ W2l,
    unsigned short* __restrict__ Wk, unsigned short* __restrict__ Wv,
    unsigned short* __restrict__ Wc1, unsigned short* __restrict__ Wc2) {
  int id = blockIdx.x*256 + threadIdx.x;
  const int NA = 49*4096;
  if (id < NA) {
    int j = id & 7, l = (id >> 3) & 63, ct = (id >> 9) & 1, cs = (id >> 10) & 3, s = id >> 12;
    int co = ct*16 + (l & 15);
    int ci = cs*32 + ((l >> 4) << 3) + j;
    Wa[id] = f2bf(sa_w1[(co*128 + ci)*49 + s]);
    return;
  }
  id -= NA;
  if (id < NA) {
    int j = id & 7, l = (id >> 3) & 63, ct = (id >> 9) & 7, s = id >> 12;
    int co = ct*16 + (l & 15);
    int ci = ((l >> 4) << 3) + j;
    Wb[id] = f2bf(sa_w2[(co*32 + ci)*49 + s]);
    return;
  }
  id -= NA;
  if (id < 16384) {
    int j = id & 7, l = (id >> 3) & 63, ct = (id >> 9) & 7, cs = id >> 12;
    int co = ct*16 + (l & 15);
    int ci = cs*32 + ((l >> 4) << 3) + j;
    float v = pW1[co*128 + ci];
    __hip_bfloat16 h = __float2bfloat16(v);
    W1h[id] = *(unsigned short*)&h;
    W1l[id] = f2bf(v - __bfloat162float(h));
    return;
  }
  id -= 16384;
  if (id < 16384) {
    int j = id & 7, l = (id >> 3) & 63, ct = (id >> 9) & 7, cs = id >> 12;
    int co = ct*16 + (l & 15);
    int ci = cs*32 + ((l >> 4) << 3) + j;
    float v = pW2[co*128 + ci];
    __hip_bfloat16 h = __float2bfloat16(v);
    W2h[id] = *(unsigned short*)&h;
    W2l[id] = f2bf(v - __bfloat162float(h));
    return;
  }
  id -= 16384;
  if (id < 16384) {
    int j = id & 7, l = (id >> 3) & 63, ct = (id >> 9) & 7, cs = id >> 12;
    int co = ct*16 + (l & 15);
    int ci = cs*32 + ((l >> 4) << 3) + j;
    Wk[id] = f2bf(qkvW[(size_t)(128 + co)*128 + ci]);
    Wv[id] = f2bf(qkvW[(size_t)(256 + co)*128 + ci]);
    return;
  }
  id -= 16384;
  if (id < 4096) {
    int j = id & 7, l = (id >> 3) & 63, ct = (id >> 9) & 1, cs = (id >> 10) & 3;
    int co = ct*16 + (l & 15);
    int ci = cs*32 + ((l >> 4) << 3) + j;
    Wc1[id] = f2bf(ca_w1[co*128 + ci]);
    return;
  }
  id -= 4096;
  {
    int j = id & 7, l = (id >> 3) & 63, ct = (id >> 9) & 7;
    int co = ct*16 + (l & 15);
    int ci = ((l >> 4) << 3) + j;
    Wc2[id] = f2bf(ca_w2[co*32 + ci]);
  }
}

// ---------- fused BN + 1x1 conv, pixel-tile GEMM, ct-split waves, in-place ----------
template<int MODE>
__global__ __launch_bounds__(256) void k_pw_v3(float* __restrict__ A,
        const unsigned short* __restrict__ Whi, const unsigned short* __restrict__ Wlo,
        const float* __restrict__ scale, const float* __restrict__ shift,
        const float* __restrict__ dw, const float* __restrict__ db,
        float* __restrict__ ps, float* __restrict__ pq) {
  int blk = blockIdx.x;
  int b = blk >> 2, tile = blk & 3, p0 = tile*64;
  int t = threadIdx.x;
  __shared__ __align__(16) unsigned short xh[16*64*8];   // [oct][px][8] 16 KB
  __shared__ __align__(16) unsigned short xl[16*64*8];
  __shared__ float scl[CC], shf[CC], dwl[CC], dbl[CC];
  __shared__ float pS[CC], pQ[CC];
  if (t < CC) {
    scl[t] = scale[t]; shf[t] = shift[t];
    if (MODE == 1) { dwl[t] = dw[t]; dbl[t] = db[t]; }
  }
  __syncthreads();
  float* Ab = A + (size_t)b*CC*HW;
  {
    int px = t & 63, cig = t >> 6;
    int p = p0 + px;
    bool pv = p < HW;
    #pragma unroll
    for (int k0 = 0; k0 < 32; k0 += 8) {
      U8 th, tl;
      #pragma unroll
      for (int j = 0; j < 8; ++j) {
        int ci = cig*32 + k0 + j;
        float v = pv ? Ab[(size_t)ci*HW + p]*scl[ci] + shf[ci] : 0.f;
        __hip_bfloat16 h = __float2bfloat16(v);
        th.u[j] = *(unsigned short*)&h;
        tl.u[j] = f2bf(v - __bfloat162float(h));
      }
      int oo = cig*4 + (k0 >> 3);
      *(short8*)&xh[(oo*64 + px)*8] = th.v;
      *(short8*)&xl[(oo*64 + px)*8] = tl.v;
    }
  }
  __syncthreads();
  int w = t >> 6, l = t & 63, g = l >> 4, n = l & 15;
  const short8* whp = (const short8*)Whi;
  const short8* wlp = (const short8*)Wlo;
  short8 ah[4][2], al[4][2];
  #pragma unroll
  for (int cs = 0; cs < 4; ++cs)
    #pragma unroll
    for (int ctl = 0; ctl < 2; ++ctl) {
      ah[cs][ctl] = whp[(cs*8 + w*2 + ctl)*64 + l];
      al[cs][ctl] = wlp[(cs*8 + w*2 + ctl)*64 + l];
    }
  float ls[2][4] = {}, lq[2][4] = {};
  for (int pt = 0; pt < 4; ++pt) {
    int p = p0 + pt*16 + n;
    bool pv = p < HW;
    short8 bh[4], bl[4];
    #pragma unroll
    for (int cs = 0; cs < 4; ++cs) {
      bh[cs] = *(const short8*)&xh[((cs*4 + g)*64 + pt*16 + n)*8];
      bl[cs] = *(const short8*)&xl[((cs*4 + g)*64 + pt*16 + n)*8];
    }
    f32x4 acc[2] = {};
    #pragma unroll
    for (int cs = 0; cs < 4; ++cs)
      #pragma unroll
      for (int ctl = 0; ctl < 2; ++ctl) {
        acc[ctl] = __builtin_amdgcn_mfma_f32_16x16x32_bf16(ah[cs][ctl], bh[cs], acc[ctl], 0, 0, 0);
        acc[ctl] = __builtin_amdgcn_mfma_f32_16x16x32_bf16(ah[cs][ctl], bl[cs], acc[ctl], 0, 0, 0);
        acc[ctl] = __builtin_amdgcn_mfma_f32_16x16x32_bf16(al[cs][ctl], bh[cs], acc[ctl], 0, 0, 0);
      }
    #pragma unroll
    for (int ctl = 0; ctl < 2; ++ctl)
      #pragma unroll
      for (int r = 0; r < 4; ++r) {
        int co = (w*2 + ctl)*16 + g*4 + r;
        float y = acc[ctl][r];
        y = (y >= 0.f) ? y : 0.01f*y;
        if (MODE == 1) { y = y*dwl[co] + dbl[co]; y = fmaxf(y, 0.f); }
        if (pv) Ab[(size_t)co*HW + p] = y;
        if (MODE == 1) {
          float vs = pv ? y : 0.f;
          ls[ctl][r] += vs; lq[ctl][r] += vs*vs;
        }
      }
  }
  if (MODE == 1) {
    #pragma unroll
    for (int ctl = 0; ctl < 2; ++ctl)
      #pragma unroll
      for (int r = 0; r < 4; ++r) {
        float s = ls[ctl][r], q = lq[ctl][r];
        #pragma unroll
        for (int m = 1; m < 16; m <<= 1) { s += __shfl_xor(s, m); q += __shfl_xor(q, m); }
        if (n == 0) { pS[(w*2 + ctl)*16 + g*4 + r] = s; pQ[(w*2 + ctl)*16 + g*4 + r] = q; }
      }
    __syncthreads();
    if (t < CC) {
      ps[(size_t)t*NPMAX + blk] = pS[t];
      pq[(size_t)t*NPMAX + blk] = pQ[t];
    }
  }
}

// ---------- depthwise 3x3 pad1 + bias + relu, grid (B, 8 ch-groups) ----------
__global__ __launch_bounds__(256) void k_dw3(float* __restrict__ A, const float* __restrict__ w,
                      const float* __restrict__ db) {
  int b = blockIdx.x, cg = blockIdx.y, t = threadIdx.x;
  __shared__ float xin[16][HW];
  float* Ab = A + ((size_t)b*CC + cg*16)*HW;
  for (int i = t; i < 16*HW; i += 256) xin[i/HW][i%HW] = Ab[i];
  __syncthreads();
  if (t < HW) {
    int y = t/15, x = t - y*15;
    for (int c = 0; c < 16; ++c) {
      int ch = cg*16 + c;
      float acc = db[ch];
      #pragma unroll
      for (int ky = 0; ky < 3; ++ky) {
        int iy = y + ky - 1;
        if (iy < 0 || iy >= 15) continue;
        #pragma unroll
        for (int kx = 0; kx < 3; ++kx) {
          int ix = x + kx - 1;
          if (ix < 0 || ix >= 15) continue;
          acc += w[ch*9 + ky*3 + kx]*xin[c][iy*15 + ix];
        }
      }
      Ab[c*HW + t] = fmaxf(acc, 0.f);
    }
  }
}

// ---------- attn2 stage 1: center Q projection ----------
__global__ __launch_bounds__(128) void k_cent(const float* __restrict__ A,
        const float* __restrict__ Wq, float* __restrict__ cent) {
  int b = blockIdx.x, t = threadIdx.x;
  __shared__ float xc[CC];
  const float* Ab = A + (size_t)b*CC*HW;
  xc[t] = bf2f(f2bf(Ab[(size_t)t*HW + 112]));
  __syncthreads();
  const float* wq = Wq + (size_t)t*CC;
  float acc = 0.f;
  for (int ci = 0; ci < CC; ++ci) acc += wq[ci]*xc[ci];
  cent[(size_t)b*CC + t] = acc;
}

// ---------- attn2 stage 2: K-proj + e2 logits, octet-major LDS ----------
__global__ __launch_bounds__(256) void k_attn2a(const float* __restrict__ A,
        const float* __restrict__ cent, const unsigned short* __restrict__ Wk,
        float* __restrict__ sim) {
  int blk = blockIdx.x;
  int b = blk >> 2, tile = blk & 3, p0 = tile*64;
  int t = threadIdx.x;
  __shared__ __align__(16) unsigned short xh[16*64*8];
  __shared__ float cl[CC];
  const float* Ab = A + (size_t)b*CC*HW;
  if (t < CC) cl[t] = cent[(size_t)b*CC + t];
  {
    int px = t & 63, cig = t >> 6;
    int p = p0 + px;
    bool pv = p < HW;
    #pragma unroll
    for (int k0 = 0; k0 < 32; k0 += 8) {
      U8 th;
      #pragma unroll
      for (int j = 0; j < 8; ++j) {
        int ci = cig*32 + k0 + j;
        th.u[j] = pv ? f2bf(Ab[(size_t)ci*HW + p]) : 0;
      }
      *(short8*)&xh[((cig*4 + (k0>>3))*64 + px)*8] = th.v;
    }
  }
  __syncthreads();
  int w = t >> 6, l = t & 63, g = l >> 4, n = l & 15;
  int p = p0 + w*16 + n;
  bool pv = p < HW;
  const short8* wkp = (const short8*)Wk;
  short8 bf[4];
  #pragma unroll
  for (int cs = 0; cs < 4; ++cs)
    bf[cs] = *(const short8*)&xh[((cs*4 + g)*64 + w*16 + n)*8];
  float e2p = 0.f;
  #pragma unroll
  for (int ct = 0; ct < 8; ++ct) {
    f32x4 k = {};
    #pragma unroll
    for (int cs = 0; cs < 4; ++cs)
      k = __builtin_amdgcn_mfma_f32_16x16x32_bf16(wkp[(cs*8 + ct)*64 + l], bf[cs], k, 0, 0, 0);
    #pragma unroll
    for (int r = 0; r < 4; ++r) { float d = cl[ct*16 + g*4 + r] - k[r]; e2p += d*d; }
  }
  e2p += __shfl_xor(e2p, 16);
  e2p += __shfl_xor(e2p, 32);
  if (g == 0 && pv) sim[(size_t)b*HW + p] = 1.f/(1.f + sqrtf(e2p));
}

// ---------- attn2 stage 3: per-image softmax ----------
__global__ __launch_bounds__(256) void k_soft(float* __restrict__ sim) {
  int b = blockIdx.x, t = threadIdx.x;
  __shared__ float red[256];
  float val = (t < HW) ? sim[(size_t)b*HW + t] : -1e30f;
  float m = br_max<256>(val, red, t);
  float e = (t < HW) ? expf(val - m) : 0.f;
  float s = br_sum<256>(e, red, t);
  if (t < HW) sim[(size_t)b*HW + t] = e/s;
}

// ---------- attn2 stage 4: V-proj + residual + fused bn3 stats ----------
__global__ __launch_bounds__(256) void k_attn2b(float* __restrict__ A,
        const float* __restrict__ att, const unsigned short* __restrict__ Wv,
        float* __restrict__ ps, float* __restrict__ pq) {
  int blk = blockIdx.x;
  int b = blk >> 2, tile = blk & 3, p0 = tile*64;
  int t = threadIdx.x;
  __shared__ __align__(16) unsigned short xh[16*64*8];
  __shared__ float pS[4][CC], pQ[4][CC];
  float* Ab = A + (size_t)b*CC*HW;
  {
    int px = t & 63, cig = t >> 6;
    int p = p0 + px;
    bool pv = p < HW;
    #pragma unroll
    for (int k0 = 0; k0 < 32; k0 += 8) {
      U8 th;
      #pragma unroll
      for (int j = 0; j < 8; ++j) {
        int ci = cig*32 + k0 + j;
        th.u[j] = pv ? f2bf(Ab[(size_t)ci*HW + p]) : 0;
      }
      *(short8*)&xh[((cig*4 + (k0>>3))*64 + px)*8] = th.v;
    }
  }
  __syncthreads();
  int w = t >> 6, l = t & 63, g = l >> 4, n = l & 15;
  int p = p0 + w*16 + n;
  bool pv = p < HW;
  float ap = pv ? att[(size_t)b*HW + p] : 0.f;
  const short8* wvp = (const short8*)Wv;
  short8 bf[4];
  #pragma unroll
  for (int cs = 0; cs < 4; ++cs)
    bf[cs] = *(const short8*)&xh[((cs*4 + g)*64 + w*16 + n)*8];
  #pragma unroll
  for (int ct = 0; ct < 8; ++ct) {
    f32x4 v = {};
    #pragma unroll
    for (int cs = 0; cs < 4; ++cs)
      v = __builtin_amdgcn_mfma_f32_16x16x32_bf16(wvp[(cs*8 + ct)*64 + l], bf[cs], v, 0, 0, 0);
    #pragma unroll
    for (int r = 0; r < 4; ++r) {
      int co = ct*16 + g*4 + r;
      float val = 0.f;
      if (pv) {
        val = ap*v[r] + Ab[(size_t)co*HW + p];
        Ab[(size_t)co*HW + p] = val;
      }
      float s = val, q = val*val;
      #pragma unroll
      for (int m = 1; m < 16; m <<= 1) { s += __shfl_xor(s, m); q += __shfl_xor(q, m); }
      if (n == 0) { pS[w][co] = s; pQ[w][co] = q; }
    }
  }
  __syncthreads();
  if (t < CC) {
    ps[(size_t)t*NPMAX + blk] = pS[0][t]+pS[1][t]+pS[2][t]+pS[3][t];
    pq[(size_t)t*NPMAX + blk] = pQ[0][t]+pQ[1][t]+pQ[2][t]+pQ[3][t];
  }
}

// ---------- BN3 + channel-attention gate; writes D (+ bf16 D2) ----------
__global__ __launch_bounds__(256) void k_chatt_v3(const float* __restrict__ A, float* __restrict__ D,
        unsigned short* __restrict__ D2,
        const float* __restrict__ sc, const float* __restrict__ sh,
        const unsigned short* __restrict__ Wc1, const float* __restrict__ b1,
        const unsigned short* __restrict__ Wc2, const float* __restrict__ b2) {
  int blk = blockIdx.x;
  int b = blk >> 2, tile = blk & 3, p0 = tile*64;
  int t = threadIdx.x;
  __shared__ __align__(16) unsigned short xh[16*64*8];
  __shared__ __align__(16) unsigned short hb[64*CIPH];
  __shared__ float scl[CC], shl[CC], b2l[CC], b1l[32];
  const float* Ab = A + (size_t)b*CC*HW;
  float* Db = D + (size_t)b*CC*HW;
  if (t < CC) { scl[t] = sc[t]; shl[t] = sh[t]; b2l[t] = b2[t]; }
  if (t < 32) b1l[t] = b1[t];
  __syncthreads();
  {
    int px = t & 63, cig = t >> 6;
    int p = p0 + px;
    bool pv = p < HW;
    #pragma unroll
    for (int k0 = 0; k0 < 32; k0 += 8) {
      U8 th;
      #pragma unroll
      for (int j = 0; j < 8; ++j) {
        int ci = cig*32 + k0 + j;
        th.u[j] = pv ? f2bf(Ab[(size_t)ci*HW + p]*scl[ci] + shl[ci]) : 0;
      }
      *(short8*)&xh[((cig*4 + (k0>>3))*64 + px)*8] = th.v;
    }
  }
  __syncthreads();
  int w = t >> 6, l = t & 63, g = l >> 4, n = l & 15;
  int p = p0 + w*16 + n;
  bool pv = p < HW;
  const short8* w1p = (const short8*)Wc1;
  const short8* w2p = (const short8*)Wc2;
  short8 bf[4];
  #pragma unroll
  for (int cs = 0; cs < 4; ++cs)
    bf[cs] = *(const short8*)&xh[((cs*4 + g)*64 + w*16 + n)*8];
  #pragma unroll
  for (int ct = 0; ct < 2; ++ct) {
    f32x4 a = {};
    #pragma unroll
    for (int cs = 0; cs < 4; ++cs)
      a = __builtin_amdgcn_mfma_f32_16x16x32_bf16(w1p[(cs*2 + ct)*64 + l], bf[cs], a, 0, 0, 0);
    us4 hv;
    #pragma unroll
    for (int r = 0; r < 4; ++r) hv[r] = f2bf(fmaxf(a[r] + b1l[ct*16 + g*4 + r], 0.f));
    *(us4*)&hb[(w*16+n)*CIPH + ct*16 + g*4] = hv;
  }
  __syncthreads();
  short8 hf = *(const short8*)&hb[(w*16+n)*CIPH + g*8];
  #pragma unroll
  for (int ct = 0; ct < 8; ++ct) {
    f32x4 a = __builtin_amdgcn_mfma_f32_16x16x32_bf16(w2p[ct*64 + l], hf, f32x4{}, 0, 0, 0);
    if (pv) {
      us4 dv;
      #pragma unroll
      for (int r = 0; r < 4; ++r) {
        int co = ct*16 + g*4 + r;
        float s = a[r] + b2l[co];
        float gt = 1.f/(1.f + expf(-s));
        float xin = Ab[(size_t)co*HW + p]*scl[co] + shl[co];
        float o = xin*gt;
        Db[(size_t)co*HW + p] = o;
        dv[r] = f2bf(o);
      }
      if (D2) *(us4*)&D2[((size_t)b*HW + p)*CIP + ct*16 + g*4] = dv;
    }
  }
}

// ---------- 7x7 conv 128->32: full-image block, wave=(ct,rowhalf), 8-row acc,
//            4-ck serial staging with register prefetch (+ bn4 stats) ----------
template<int USED2>
__global__ __launch_bounds__(256) void k_conv7a_mfma(const float* __restrict__ D,
        const unsigned short* __restrict__ D2,
        const unsigned short* __restrict__ Wa, float* __restrict__ S,
        float* __restrict__ ps, float* __restrict__ pq) {
  int b = blockIdx.x, t = threadIdx.x;
  __shared__ __align__(16) unsigned short xb[4*21*22*8];   // 29,568 B  [oct][row 0..20][x 0..21][8]
  __shared__ float pS[2][32], pQ[2][32];
  unsigned int* xw = (unsigned int*)xb;
  for (int i = t; i < 4*21*22*8/2; i += 256) xw[i] = 0u;
  int w = t >> 6, l = t & 63, g = l >> 4, x = l & 15;
  int ct = w & 1, rh = w >> 1;
  int base = rh*8;
  f32x4 acc[8] = {};
  const short8* wp = (const short8*)Wa;
  int pr = 0;
  if (t < HW) { int py = t/15, px = t - (t/15)*15; pr = (py+3)*22 + (px+3); }
  short8 stg[4];
  // prefetch ck=0
  if (t < HW) {
    if (USED2) {
      const unsigned short* src = &D2[((size_t)b*HW + t)*CIP];
      #pragma unroll
      for (int g0 = 0; g0 < 4; ++g0) stg[g0] = *(const short8*)&src[g0*8];
    } else {
      const float* Dbp = D + (size_t)b*CC*HW;
      #pragma unroll
      for (int g0 = 0; g0 < 4; ++g0) {
        U8 tb;
        #pragma unroll
        for (int k = 0; k < 8; ++k) tb.u[k] = f2bf(Dbp[(g0*8+k)*HW + t]);
        stg[g0] = tb.v;
      }
    }
  }
  for (int ck = 0; ck < 4; ++ck) {
    __syncthreads();
    if (t < HW) {
      #pragma unroll
      for (int g0 = 0; g0 < 4; ++g0)
        *(short8*)&xb[(g0*21*22 + pr)*8] = stg[g0];
    }
    __syncthreads();
    if (ck < 3) {
      if (t < HW) {
        if (USED2) {
          const unsigned short* src = &D2[((size_t)b*HW + t)*CIP + (ck+1)*32];
          #pragma unroll
          for (int g0 = 0; g0 < 4; ++g0) stg[g0] = *(const short8*)&src[g0*8];
        } else {
          const float* Dbp = D + ((size_t)b*CC + (ck+1)*32)*HW;
          #pragma unroll
          for (int g0 = 0; g0 < 4; ++g0) {
            U8 tb;
            #pragma unroll
            for (int k = 0; k < 8; ++k) tb.u[k] = f2bf(Dbp[(g0*8+k)*HW + t]);
            stg[g0] = tb.v;
          }
        }
      }
    }
    for (int dx = 0; dx < 7; ++dx) {
      short8 aw[7];
      #pragma unroll
      for (int dy = 0; dy < 7; ++dy)
        aw[dy] = wp[(((dy*7 + dx)*4 + ck)*2 + ct)*64 + l];
      #pragma unroll
      for (int rs = 0; rs < 14; ++rs) {
        if (base + rs < 21) {
          short8 bf = *(const short8*)&xb[((g*21 + base + rs)*22 + x + dx)*8];
          #pragma unroll
          for (int r = 0; r < 8; ++r) {
            int dy = rs - r;
            if (dy >= 0 && dy <= 6)
              acc[r] = __builtin_amdgcn_mfma_f32_16x16x32_bf16(aw[dy], bf, acc[r], 0, 0, 0);
          }
        }
      }
    }
  }
  float ls[4] = {}, lq[4] = {};
  #pragma unroll
  for (int r = 0; r < 8; ++r) {
    int nt = base + r;
    bool valid = (x < 15) && (nt < 15);
    if (valid) {
      float* out = S + ((size_t)b*32 + ct*16 + g*4)*HW + nt*15 + x;
      #pragma unroll
      for (int q = 0; q < 4; ++q) out[q*HW] = acc[r][q];
    }
    #pragma unroll
    for (int q = 0; q < 4; ++q) {
      float v = valid ? acc[r][q] : 0.f;
      ls[q] += v; lq[q] += v*v;
    }
  }
  #pragma unroll
  for (int q = 0; q < 4; ++q) {
    float s = ls[q], qq = lq[q];
    #pragma unroll
    for (int m = 1; m < 16; m <<= 1) { s += __shfl_xor(s, m); qq += __shfl_xor(qq, m); }
    if (x == 0) { pS[rh][ct*16 + g*4 + q] = s; pQ[rh][ct*16 + g*4 + q] = qq; }
  }
  __syncthreads();
  if (t < 32) {
    ps[(size_t)t*NPMAX + b] = pS[0][t]+pS[1][t];
    pq[(size_t)t*NPMAX + b] = pQ[0][t]+pQ[1][t];
  }
}

// ---------- 7x7 conv 32->128: full-image block, 512 thr = 8 waves (1 ct each),
//            acc[15], BN+relu at staging (+ bn5 stats) ----------
__global__ __launch_bounds__(512) void k_conv7b_mfma(const float* __restrict__ S,
        const float* __restrict__ sc, const float* __restrict__ sh,
        const unsigned short* __restrict__ Wb, float* __restrict__ O,
        float* __restrict__ ps, float* __restrict__ pq) {
  int b = blockIdx.x, t = threadIdx.x;
  __shared__ __align__(16) unsigned short xb[4*21*22*8];   // 29,568 B
  __shared__ float scl[32], shl[32];
  __shared__ float pS[CC], pQ[CC];
  unsigned int* xw = (unsigned int*)xb;
  for (int i = t; i < 4*21*22*8/2; i += 512) xw[i] = 0u;
  if (t < 32) { scl[t] = sc[t]; shl[t] = sh[t]; }
  __syncthreads();
  const float* Sb = S + (size_t)b*32*HW;
  if (t < HW) {
    int py = t/15, px = t - (t/15)*15;
    int pr = (py+3)*22 + (px+3);
    #pragma unroll
    for (int g0 = 0; g0 < 4; ++g0) {
      U8 tb;
      #pragma unroll
      for (int k = 0; k < 8; ++k)
        tb.u[k] = f2bf(fmaxf(Sb[(g0*8+k)*HW + t]*scl[g0*8+k] + shl[g0*8+k], 0.f));
      *(short8*)&xb[(g0*21*22 + pr)*8] = tb.v;
    }
  }
  __syncthreads();
  int w = t >> 6, l = t & 63, g = l >> 4, x = l & 15;
  int ct = w;
  f32x4 acc[15] = {};
  const short8* wp = (const short8*)Wb;
  for (int dx = 0; dx < 7; ++dx) {
    short8 aw[7];
    #pragma unroll
    for (int dy = 0; dy < 7; ++dy)
      aw[dy] = wp[((dy*7 + dx)*8 + ct)*64 + l];
    #pragma unroll
    for (int rs = 0; rs < 21; ++rs) {
      short8 bf = *(const short8*)&xb[((g*21 + rs)*22 + x + dx)*8];
      #pragma unroll
      for (int r = 0; r < 15; ++r) {
        int dy = rs - r;
        if (dy >= 0 && dy <= 6)
          acc[r] = __builtin_amdgcn_mfma_f32_16x16x32_bf16(aw[dy], bf, acc[r], 0, 0, 0);
      }
    }
  }
  float ls[4] = {}, lq[4] = {};
  #pragma unroll
  for (int r = 0; r < 15; ++r) {
    bool valid = (x < 15);
    if (valid) {
      float* out = O + ((size_t)b*CC + ct*16 + g*4)*HW + r*15 + x;
      #pragma unroll
      for (int q = 0; q < 4; ++q) out[q*HW] = acc[r][q];
    }
    #pragma unroll
    for (int q = 0; q < 4; ++q) {
      float v = valid ? acc[r][q] : 0.f;
      ls[q] += v; lq[q] += v*v;
    }
  }
  #pragma unroll
  for (int q = 0; q < 4; ++q) {
    float s = ls[q], qq = lq[q];
    #pragma unroll
    for (int m = 1; m < 16; m <<= 1) { s += __shfl_xor(s, m); qq += __shfl_xor(qq, m); }
    if (x == 0) { pS[ct*16 + g*4 + q] = s; pQ[ct*16 + g*4 + q] = qq; }
  }
  __syncthreads();
  if (t < CC) {
    ps[(size_t)t*NPMAX + b] = pS[t];
    pq[(size_t)t*NPMAX + b] = pQ[t];
  }
}

// ---------- final: D *= sigmoid(bn5(A)), float4 ----------
__global__ __launch_bounds__(256) void k_final4(f32x4* __restrict__ D, const f32x4* __restrict__ A,
                        const float* __restrict__ sc, const float* __restrict__ sh) {
  size_t i = (size_t)blockIdx.x*256 + threadIdx.x;
  f32x4 a = A[i], d = D[i];
  size_t e = i*4;
  #pragma unroll
  for (int k = 0; k < 4; ++k) {
    int c = (int)(((e + k) / HW) % CC);
    float s = a[k]*sc[c] + sh[c];
    d[k] *= 1.f/(1.f + expf(-s));
  }
  D[i] = d;
}

extern "C" void kernel_launch(void* const* d_in, const int* in_sizes, int n_in,
                              void* d_out, int out_size, void* d_ws, size_t ws_size,
                              hipStream_t stream) {
  (void)in_sizes; (void)n_in; (void)out_size;
  const float* x1    = (const float*)d_in[0];
  const float* x2    = (const float*)d_in[1];
  const float* lam   = (const float*)d_in[2];
  const float* bn1_g = (const float*)d_in[3];
  const float* bn1_b = (const float*)d_in[4];
  const float* pW1   = (const float*)d_in[5];
  const float* dW1   = (const float*)d_in[6];
  const float* db1   = (const float*)d_in[7];
  const float* bn2_g = (const float*)d_in[8];
  const float* bn2_b = (const float*)d_in[9];
  const float* pW2   = (const float*)d_in[10];
  const float* dW2   = (const float*)d_in[11];
  const float* db2   = (const float*)d_in[12];
  const float* qkvW  = (const float*)d_in[13];
  const float* bn3_g = (const float*)d_in[14];
  const float* bn3_b = (const float*)d_in[15];
  const float* ca_w1 = (const float*)d_in[16];
  const float* ca_b1 = (const float*)d_in[17];
  const float* ca_w2 = (const float*)d_in[18];
  const float* ca_b2 = (const float*)d_in[19];
  const float* sa_w1 = (const float*)d_in[20];
  const float* sbn1_g= (const float*)d_in[22];
  const float* sbn1_b= (const float*)d_in[23];
  const float* sa_w2 = (const float*)d_in[24];
  const float* sbn2_g= (const float*)d_in[26];
  const float* sbn2_b= (const float*)d_in[27];

  float* D = (float*)d_out;
  float* A = (float*)d_ws;                          // (512,128,225) f32
  float* S = A + (size_t)BB*CC*HW;                  // (512,32,225)  f32
  float* part = S + (size_t)BB*32*HW;               // 512*4*3*256 f32
  float* st = part + (size_t)BB*4*3*256;            // 1280 f32 stats
  float *sc1 = st,      *sh1 = st+128,  *sc2 = st+256, *sh2 = st+384,
        *sc3 = st+512,  *sh3 = st+640,  *sc4 = st+768, *sh4 = st+800,
        *sc5 = st+832,  *sh5 = st+960;
  float* ps = st + 1280;                            // 128*NPMAX
  float* pq = ps + (size_t)CC*NPMAX;                // 128*NPMAX
  float* cent = pq + (size_t)CC*NPMAX;              // 512*128
  float* sim  = cent + (size_t)BB*CC;               // 512*225
  float* am   = sim + (size_t)BB*HW;                // 512*225
  unsigned short* Wa  = (unsigned short*)(am + (size_t)BB*HW);
  unsigned short* Wb  = Wa + 49*4096;
  unsigned short* W1h = Wb + 49*4096;
  unsigned short* W1l = W1h + 16384;
  unsigned short* W2h = W1l + 16384;
  unsigned short* W2l = W2h + 16384;
  unsigned short* Wk  = W2l + 16384;
  unsigned short* Wv  = Wk  + 16384;
  unsigned short* Wc1 = Wv  + 16384;
  unsigned short* Wc2 = Wc1 + 4096;
  unsigned short* D2  = Wc2 + 4096;                 // (512,225,136) bf16, optional
  size_t need = (size_t)((char*)(D2 + (size_t)BB*HW*CIP) - (char*)d_ws);
  bool useD2 = ws_size >= need;

  const int NB4 = BB*4;

  k_prep_all<<<1792, 256, 0, stream>>>(sa_w1, sa_w2, pW1, pW2, qkvW, ca_w1, ca_w2,
                                       Wa, Wb, W1h, W1l, W2h, W2l, Wk, Wv, Wc1, Wc2);

  k_at1a <<<dim3(BB,4), 256, 0, stream>>>(x1, x2, part);
  k_at1b <<<BB, 256, 0, stream>>>(x1, x2, part, lam, am);
  k_at1c <<<dim3(BB,4), 256, 0, stream>>>(x1, x2, am, A, ps, pq);
  k_bnfin2<<<CC, 256, 0, stream>>>(ps, pq, BB, bn1_g, bn1_b, sc1, sh1);
  k_pw_v3<1><<<NB4, 256, 0, stream>>>(A, W1h, W1l, sc1, sh1, dW1, db1, ps, pq);
  k_bnfin2<<<CC, 256, 0, stream>>>(ps, pq, NB4, bn2_g, bn2_b, sc2, sh2);
  k_pw_v3<2><<<NB4, 256, 0, stream>>>(A, W2h, W2l, sc2, sh2, nullptr, nullptr, nullptr, nullptr);
  k_dw3   <<<dim3(BB,8), 256, 0, stream>>>(A, dW2, db2);
  k_cent  <<<BB, 128, 0, stream>>>(A, qkvW, cent);
  k_attn2a<<<NB4, 256, 0, stream>>>(A, cent, Wk, sim);
  k_soft  <<<BB, 256, 0, stream>>>(sim);
  k_attn2b<<<NB4, 256, 0, stream>>>(A, sim, Wv, ps, pq);
  k_bnfin2<<<CC, 256, 0, stream>>>(ps, pq, NB4, bn3_g, bn3_b, sc3, sh3);
  k_chatt_v3<<<NB4, 256, 0, stream>>>(A, D, useD2 ? D2 : nullptr, sc3, sh3, Wc1, ca_b1, Wc2, ca_b2);
  if (useD2) k_conv7a_mfma<1><<<BB, 256, 0, stream>>>(D, D2, Wa, S, ps, pq);
  else       k_conv7a_mfma<0><<<BB, 256, 0, stream>>>(D, nullptr, Wa, S, ps, pq);
  k_bnfin2<<<32, 256, 0, stream>>>(ps, pq, BB, sbn1_g, sbn1_b, sc4, sh4);
  k_conv7b_mfma<<<BB, 512, 0, stream>>>(S, sc4, sh4, Wb, A, ps, pq);
  k_bnfin2<<<CC, 256, 0, stream>>>(ps, pq, BB, sbn2_g, sbn2_b, sc5, sh5);
  k_final4<<<(BB*CC*HW)/1024, 256, 0, stream>>>((f32x4*)D, (const f32x4*)A, sc5, sh5);
}

// Round 13
// 515.529 us; speedup vs baseline: 1.4849x; 1.4849x over previous
//
#include <hip/hip_runtime.h>
#include <hip/hip_bf16.h>
#include <cmath>

#define BB 512
#define CC 128
#define HW 225
#define CIP 136     // ushort stride of D2 [px][ci] rows (272 B)
#define CIPH 40     // ushort stride for 32-ch hidden rows
#define NPMAX 2048  // max partial-stat blocks
#define NRW 14      // padded-row window for row-split convs

typedef __attribute__((ext_vector_type(8))) short short8;
typedef __attribute__((ext_vector_type(4))) float f32x4;
typedef __attribute__((ext_vector_type(4))) unsigned short us4;

union U8 { unsigned short u[8]; short8 v; };

__device__ __forceinline__ unsigned short f2bf(float v) {
  __hip_bfloat16 h = __float2bfloat16(v);
  return *(unsigned short*)&h;
}
__device__ __forceinline__ float bf2f(unsigned short u) {
  __hip_bfloat16 h = *(__hip_bfloat16*)&u;
  return __bfloat162float(h);
}

template<int NT>
__device__ __forceinline__ float br_max(float v, float* red, int t) {
  red[t] = v; __syncthreads();
  for (int st = NT/2; st > 0; st >>= 1) { if (t < st) red[t] = fmaxf(red[t], red[t+st]); __syncthreads(); }
  float r = red[0]; __syncthreads();
  return r;
}
template<int NT>
__device__ __forceinline__ float br_sum(float v, float* red, int t) {
  red[t] = v; __syncthreads();
  for (int st = NT/2; st > 0; st >>= 1) { if (t < st) red[t] += red[t+st]; __syncthreads(); }
  float r = red[0]; __syncthreads();
  return r;
}

// finalize fused per-block partials ps/pq[c][NPMAX], np valid slots
__global__ __launch_bounds__(256) void k_bnfin2(const float* __restrict__ ps, const float* __restrict__ pq,
                         int np,
                         const float* __restrict__ g, const float* __restrict__ bt,
                         float* __restrict__ scale, float* __restrict__ shift) {
  int c = blockIdx.x, t = threadIdx.x;
  __shared__ float rs[256], rq[256];
  float s = 0.f, q = 0.f;
  for (int i = t; i < np; i += 256) { s += ps[(size_t)c*NPMAX + i]; q += pq[(size_t)c*NPMAX + i]; }
  rs[t] = s; rq[t] = q; __syncthreads();
  for (int st = 128; st > 0; st >>= 1) { if (t < st) { rs[t]+=rs[t+st]; rq[t]+=rq[t+st]; } __syncthreads(); }
  if (t == 0) {
    const float N = (float)BB*HW;
    float mean = rs[0]/N, var = rq[0]/N - mean*mean;
    float sc = g[c]*rsqrtf(var + 1e-5f);
    scale[c] = sc; shift[c] = bt[c] - mean*sc;
  }
}

// ---------- attn1 stage A: per (image, ch-group) pixel partials ----------
__global__ __launch_bounds__(256) void k_at1a(const float* __restrict__ x1, const float* __restrict__ x2,
                       float* __restrict__ part) {
  int b = blockIdx.x, cg = blockIdx.y, t = threadIdx.x;
  __shared__ float cent[32];
  const float* xb1 = x1 + (size_t)b*64*HW;
  const float* xb2 = x2 + (size_t)b*64*HW;
  if (t < 32) { int c = cg*32 + t; cent[t] = (c < 64) ? xb1[c*HW + 112] : xb2[(c-64)*HW + 112]; }
  __syncthreads();
  if (t < HW) {
    float e2 = 0.f, dot = 0.f, qn2 = 0.f;
    for (int k = 0; k < 32; ++k) {
      int c = cg*32 + k;
      float xv = (c < 64) ? xb1[c*HW + t] : xb2[(c-64)*HW + t];
      float ce = cent[k];
      float d = xv - ce;
      e2 += d*d; dot += xv*ce; qn2 += xv*xv;
    }
    size_t base = ((size_t)(b*4 + cg)*3)*256;
    part[base + t] = e2; part[base + 256 + t] = dot; part[base + 512 + t] = qn2;
  }
}

// ---------- attn1 stage B: combine + dual softmax -> am[b][p] ----------
__global__ __launch_bounds__(256) void k_at1b(const float* __restrict__ x1, const float* __restrict__ x2,
                       const float* __restrict__ part, const float* __restrict__ lam,
                       float* __restrict__ am) {
  int b = blockIdx.x, t = threadIdx.x;
  __shared__ float red[256];
  float cv = 0.f;
  if (t < CC) {
    float ce = (t < 64) ? x1[(size_t)b*64*HW + t*HW + 112] : x2[(size_t)b*64*HW + (t-64)*HW + 112];
    cv = ce*ce;
  }
  float cn2 = br_sum<256>(cv, red, t);
  float e2 = 0.f, dot = 0.f, qn2 = 0.f;
  if (t < HW) {
    #pragma unroll
    for (int cg = 0; cg < 4; ++cg) {
      size_t base = ((size_t)(b*4 + cg)*3)*256;
      e2 += part[base + t]; dot += part[base + 256 + t]; qn2 += part[base + 512 + t];
    }
  }
  float sim_e = 0.f, sim_c = 0.f;
  if (t < HW) {
    sim_e = 1.f/(1.f + sqrtf(e2));
    float qn = sqrtf(qn2), cn = sqrtf(cn2);
    sim_c = dot / (fmaxf(cn, 1e-8f) * fmaxf(qn, 1e-8f));
  }
  float m1 = br_max<256>((t<HW)? sim_e : -1e30f, red, t);
  float e1v = (t<HW)? expf(sim_e - m1) : 0.f;
  float s1 = br_sum<256>(e1v, red, t);
  float m2 = br_max<256>((t<HW)? sim_c : -1e30f, red, t);
  float e2v = (t<HW)? expf(sim_c - m2) : 0.f;
  float s2 = br_sum<256>(e2v, red, t);
  float lmd = 1.f/(1.f + expf(-lam[0]));
  if (t < HW) am[(size_t)b*HW + t] = 1.f + lmd*e1v/s1 + (1.f - lmd)*e2v/s2;
}

// ---------- attn1 stage C: A = x*am (+ fused bn1 partials per 32-ch group) ----------
__global__ __launch_bounds__(256) void k_at1c(const float* __restrict__ x1, const float* __restrict__ x2,
                       const float* __restrict__ am, float* __restrict__ A,
                       float* __restrict__ ps, float* __restrict__ pq) {
  int b = blockIdx.x, cg = blockIdx.y, t = threadIdx.x;
  __shared__ float pS[4][32], pQ[4][32];
  const float* xb1 = x1 + (size_t)b*64*HW;
  const float* xb2 = x2 + (size_t)b*64*HW;
  float* Ab = A + (size_t)b*CC*HW;
  float amv = (t < HW) ? am[(size_t)b*HW + t] : 0.f;
  int w = t >> 6, lane = t & 63;
  for (int k = 0; k < 32; ++k) {
    int c = cg*32 + k;
    float xv = 0.f;
    if (t < HW) xv = (c < 64) ? xb1[c*HW + t] : xb2[(c-64)*HW + t];
    float val = xv*amv;
    if (t < HW) Ab[(size_t)c*HW + t] = val;
    float s = val, q = val*val;
    #pragma unroll
    for (int m = 1; m < 64; m <<= 1) { s += __shfl_xor(s, m); q += __shfl_xor(q, m); }
    if (lane == 0) { pS[w][k] = s; pQ[w][k] = q; }
  }
  __syncthreads();
  if (t < 32) {
    int c = cg*32 + t;
    ps[(size_t)c*NPMAX + b] = pS[0][t]+pS[1][t]+pS[2][t]+pS[3][t];
    pq[(size_t)c*NPMAX + b] = pQ[0][t]+pQ[1][t]+pQ[2][t]+pQ[3][t];
  }
}

// ---------- merged weight pre-pack ----------
// Wa: [ck(4)][dx(7)][dy(7)][ct(2)][lane64][j8]  (contiguous dy streams)
// Wb: [dx(7)][dy(7)][ct(8)][lane64][j8]
__global__ __launch_bounds__(256) void k_prep_all(
    const float* __restrict__ sa_w1, const float* __restrict__ sa_w2,
    const float* __restrict__ pW1, const float* __restrict__ pW2,
    const float* __restrict__ qkvW, const float* __restrict__ ca_w1, const float* __restrict__ ca_w2,
    unsigned short* __restrict__ Wa, unsigned short* __restrict__ Wb,
    unsigned short* __restrict__ W1h, unsigned short* __restrict__ W1l,
    unsigned short* __restrict__ W2h, unsigned short* __restrict__ W2l,
    unsigned short* __restrict__ Wk, unsigned short* __restrict__ Wv,
    unsigned short* __restrict__ Wc1, unsigned short* __restrict__ Wc2) {
  int id = blockIdx.x*256 + threadIdx.x;
  const int NA = 49*4096;
  if (id < NA) {                                  // conv7a weights
    int j = id & 7, l = (id >> 3) & 63, ct = (id >> 9) & 1;
    int r = id >> 10;                             // ((ck*7+dx)*7+dy)
    int dy = r % 7; r /= 7;
    int dx = r % 7; int ck = r / 7;
    int co = ct*16 + (l & 15);
    int ci = ck*32 + ((l >> 4) << 3) + j;
    Wa[id] = f2bf(sa_w1[(co*128 + ci)*49 + dy*7 + dx]);
    return;
  }
  id -= NA;
  if (id < NA) {                                  // conv7b weights
    int j = id & 7, l = (id >> 3) & 63, ct = (id >> 9) & 7;
    int r = id >> 12;                             // dx*7+dy
    int dy = r % 7, dx = r / 7;
    int co = ct*16 + (l & 15);
    int ci = ((l >> 4) << 3) + j;
    Wb[id] = f2bf(sa_w2[(co*32 + ci)*49 + dy*7 + dx]);
    return;
  }
  id -= NA;
  if (id < 16384) {
    int j = id & 7, l = (id >> 3) & 63, ct = (id >> 9) & 7, cs = id >> 12;
    int co = ct*16 + (l & 15);
    int ci = cs*32 + ((l >> 4) << 3) + j;
    float v = pW1[co*128 + ci];
    __hip_bfloat16 h = __float2bfloat16(v);
    W1h[id] = *(unsigned short*)&h;
    W1l[id] = f2bf(v - __bfloat162float(h));
    return;
  }
  id -= 16384;
  if (id < 16384) {
    int j = id & 7, l = (id >> 3) & 63, ct = (id >> 9) & 7, cs = id >> 12;
    int co = ct*16 + (l & 15);
    int ci = cs*32 + ((l >> 4) << 3) + j;
    float v = pW2[co*128 + ci];
    __hip_bfloat16 h = __float2bfloat16(v);
    W2h[id] = *(unsigned short*)&h;
    W2l[id] = f2bf(v - __bfloat162float(h));
    return;
  }
  id -= 16384;
  if (id < 16384) {
    int j = id & 7, l = (id >> 3) & 63, ct = (id >> 9) & 7, cs = id >> 12;
    int co = ct*16 + (l & 15);
    int ci = cs*32 + ((l >> 4) << 3) + j;
    Wk[id] = f2bf(qkvW[(size_t)(128 + co)*128 + ci]);
    Wv[id] = f2bf(qkvW[(size_t)(256 + co)*128 + ci]);
    return;
  }
  id -= 16384;
  if (id < 4096) {
    int j = id & 7, l = (id >> 3) & 63, ct = (id >> 9) & 1, cs = (id >> 10) & 3;
    int co = ct*16 + (l & 15);
    int ci = cs*32 + ((l >> 4) << 3) + j;
    Wc1[id] = f2bf(ca_w1[co*128 + ci]);
    return;
  }
  id -= 4096;
  {
    int j = id & 7, l = (id >> 3) & 63, ct = (id >> 9) & 7;
    int co = ct*16 + (l & 15);
    int ci = ((l >> 4) << 3) + j;
    Wc2[id] = f2bf(ca_w2[co*32 + ci]);
  }
}

// ---------- fused BN + 1x1 conv, pixel-tile GEMM, ct-split waves, in-place ----------
template<int MODE>
__global__ __launch_bounds__(256) void k_pw_v3(float* __restrict__ A,
        const unsigned short* __restrict__ Whi, const unsigned short* __restrict__ Wlo,
        const float* __restrict__ scale, const float* __restrict__ shift,
        const float* __restrict__ dw, const float* __restrict__ db,
        float* __restrict__ ps, float* __restrict__ pq) {
  int blk = blockIdx.x;
  int b = blk >> 2, tile = blk & 3, p0 = tile*64;
  int t = threadIdx.x;
  __shared__ __align__(16) unsigned short xh[16*64*8];   // [oct][px][8] 16 KB
  __shared__ __align__(16) unsigned short xl[16*64*8];
  __shared__ float scl[CC], shf[CC], dwl[CC], dbl[CC];
  __shared__ float pS[CC], pQ[CC];
  if (t < CC) {
    scl[t] = scale[t]; shf[t] = shift[t];
    if (MODE == 1) { dwl[t] = dw[t]; dbl[t] = db[t]; }
  }
  __syncthreads();
  float* Ab = A + (size_t)b*CC*HW;
  {
    int px = t & 63, cig = t >> 6;
    int p = p0 + px;
    bool pv = p < HW;
    #pragma unroll
    for (int k0 = 0; k0 < 32; k0 += 8) {
      U8 th, tl;
      #pragma unroll
      for (int j = 0; j < 8; ++j) {
        int ci = cig*32 + k0 + j;
        float v = pv ? Ab[(size_t)ci*HW + p]*scl[ci] + shf[ci] : 0.f;
        __hip_bfloat16 h = __float2bfloat16(v);
        th.u[j] = *(unsigned short*)&h;
        tl.u[j] = f2bf(v - __bfloat162float(h));
      }
      int oo = cig*4 + (k0 >> 3);
      *(short8*)&xh[(oo*64 + px)*8] = th.v;
      *(short8*)&xl[(oo*64 + px)*8] = tl.v;
    }
  }
  __syncthreads();
  int w = t >> 6, l = t & 63, g = l >> 4, n = l & 15;
  const short8* whp = (const short8*)Whi;
  const short8* wlp = (const short8*)Wlo;
  short8 ah[4][2], al[4][2];
  #pragma unroll
  for (int cs = 0; cs < 4; ++cs)
    #pragma unroll
    for (int ctl = 0; ctl < 2; ++ctl) {
      ah[cs][ctl] = whp[(cs*8 + w*2 + ctl)*64 + l];
      al[cs][ctl] = wlp[(cs*8 + w*2 + ctl)*64 + l];
    }
  float ls[2][4] = {}, lq[2][4] = {};
  for (int pt = 0; pt < 4; ++pt) {
    int p = p0 + pt*16 + n;
    bool pv = p < HW;
    short8 bh[4], bl[4];
    #pragma unroll
    for (int cs = 0; cs < 4; ++cs) {
      bh[cs] = *(const short8*)&xh[((cs*4 + g)*64 + pt*16 + n)*8];
      bl[cs] = *(const short8*)&xl[((cs*4 + g)*64 + pt*16 + n)*8];
    }
    f32x4 acc[2] = {};
    #pragma unroll
    for (int cs = 0; cs < 4; ++cs)
      #pragma unroll
      for (int ctl = 0; ctl < 2; ++ctl) {
        acc[ctl] = __builtin_amdgcn_mfma_f32_16x16x32_bf16(ah[cs][ctl], bh[cs], acc[ctl], 0, 0, 0);
        acc[ctl] = __builtin_amdgcn_mfma_f32_16x16x32_bf16(ah[cs][ctl], bl[cs], acc[ctl], 0, 0, 0);
        acc[ctl] = __builtin_amdgcn_mfma_f32_16x16x32_bf16(al[cs][ctl], bh[cs], acc[ctl], 0, 0, 0);
      }
    #pragma unroll
    for (int ctl = 0; ctl < 2; ++ctl)
      #pragma unroll
      for (int r = 0; r < 4; ++r) {
        int co = (w*2 + ctl)*16 + g*4 + r;
        float y = acc[ctl][r];
        y = (y >= 0.f) ? y : 0.01f*y;
        if (MODE == 1) { y = y*dwl[co] + dbl[co]; y = fmaxf(y, 0.f); }
        if (pv) Ab[(size_t)co*HW + p] = y;
        if (MODE == 1) {
          float vs = pv ? y : 0.f;
          ls[ctl][r] += vs; lq[ctl][r] += vs*vs;
        }
      }
  }
  if (MODE == 1) {
    #pragma unroll
    for (int ctl = 0; ctl < 2; ++ctl)
      #pragma unroll
      for (int r = 0; r < 4; ++r) {
        float s = ls[ctl][r], q = lq[ctl][r];
        #pragma unroll
        for (int m = 1; m < 16; m <<= 1) { s += __shfl_xor(s, m); q += __shfl_xor(q, m); }
        if (n == 0) { pS[(w*2 + ctl)*16 + g*4 + r] = s; pQ[(w*2 + ctl)*16 + g*4 + r] = q; }
      }
    __syncthreads();
    if (t < CC) {
      ps[(size_t)t*NPMAX + blk] = pS[t];
      pq[(size_t)t*NPMAX + blk] = pQ[t];
    }
  }
}

// ---------- depthwise 3x3 pad1 + bias + relu, grid (B, 8 ch-groups) ----------
__global__ __launch_bounds__(256) void k_dw3(float* __restrict__ A, const float* __restrict__ w,
                      const float* __restrict__ db) {
  int b = blockIdx.x, cg = blockIdx.y, t = threadIdx.x;
  __shared__ float xin[16][HW];
  float* Ab = A + ((size_t)b*CC + cg*16)*HW;
  for (int i = t; i < 16*HW; i += 256) xin[i/HW][i%HW] = Ab[i];
  __syncthreads();
  if (t < HW) {
    int y = t/15, x = t - y*15;
    for (int c = 0; c < 16; ++c) {
      int ch = cg*16 + c;
      float acc = db[ch];
      #pragma unroll
      for (int ky = 0; ky < 3; ++ky) {
        int iy = y + ky - 1;
        if (iy < 0 || iy >= 15) continue;
        #pragma unroll
        for (int kx = 0; kx < 3; ++kx) {
          int ix = x + kx - 1;
          if (ix < 0 || ix >= 15) continue;
          acc += w[ch*9 + ky*3 + kx]*xin[c][iy*15 + ix];
        }
      }
      Ab[c*HW + t] = fmaxf(acc, 0.f);
    }
  }
}

// ---------- attn2 stage 1: center Q projection ----------
__global__ __launch_bounds__(128) void k_cent(const float* __restrict__ A,
        const float* __restrict__ Wq, float* __restrict__ cent) {
  int b = blockIdx.x, t = threadIdx.x;
  __shared__ float xc[CC];
  const float* Ab = A + (size_t)b*CC*HW;
  xc[t] = bf2f(f2bf(Ab[(size_t)t*HW + 112]));
  __syncthreads();
  const float* wq = Wq + (size_t)t*CC;
  float acc = 0.f;
  for (int ci = 0; ci < CC; ++ci) acc += wq[ci]*xc[ci];
  cent[(size_t)b*CC + t] = acc;
}

// ---------- attn2 stage 2: K-proj + e2 logits, octet-major LDS ----------
__global__ __launch_bounds__(256) void k_attn2a(const float* __restrict__ A,
        const float* __restrict__ cent, const unsigned short* __restrict__ Wk,
        float* __restrict__ sim) {
  int blk = blockIdx.x;
  int b = blk >> 2, tile = blk & 3, p0 = tile*64;
  int t = threadIdx.x;
  __shared__ __align__(16) unsigned short xh[16*64*8];
  __shared__ float cl[CC];
  const float* Ab = A + (size_t)b*CC*HW;
  if (t < CC) cl[t] = cent[(size_t)b*CC + t];
  {
    int px = t & 63, cig = t >> 6;
    int p = p0 + px;
    bool pv = p < HW;
    #pragma unroll
    for (int k0 = 0; k0 < 32; k0 += 8) {
      U8 th;
      #pragma unroll
      for (int j = 0; j < 8; ++j) {
        int ci = cig*32 + k0 + j;
        th.u[j] = pv ? f2bf(Ab[(size_t)ci*HW + p]) : 0;
      }
      *(short8*)&xh[((cig*4 + (k0>>3))*64 + px)*8] = th.v;
    }
  }
  __syncthreads();
  int w = t >> 6, l = t & 63, g = l >> 4, n = l & 15;
  int p = p0 + w*16 + n;
  bool pv = p < HW;
  const short8* wkp = (const short8*)Wk;
  short8 bf[4];
  #pragma unroll
  for (int cs = 0; cs < 4; ++cs)
    bf[cs] = *(const short8*)&xh[((cs*4 + g)*64 + w*16 + n)*8];
  float e2p = 0.f;
  #pragma unroll
  for (int ct = 0; ct < 8; ++ct) {
    f32x4 k = {};
    #pragma unroll
    for (int cs = 0; cs < 4; ++cs)
      k = __builtin_amdgcn_mfma_f32_16x16x32_bf16(wkp[(cs*8 + ct)*64 + l], bf[cs], k, 0, 0, 0);
    #pragma unroll
    for (int r = 0; r < 4; ++r) { float d = cl[ct*16 + g*4 + r] - k[r]; e2p += d*d; }
  }
  e2p += __shfl_xor(e2p, 16);
  e2p += __shfl_xor(e2p, 32);
  if (g == 0 && pv) sim[(size_t)b*HW + p] = 1.f/(1.f + sqrtf(e2p));
}

// ---------- attn2 stage 3: per-image softmax ----------
__global__ __launch_bounds__(256) void k_soft(float* __restrict__ sim) {
  int b = blockIdx.x, t = threadIdx.x;
  __shared__ float red[256];
  float val = (t < HW) ? sim[(size_t)b*HW + t] : -1e30f;
  float m = br_max<256>(val, red, t);
  float e = (t < HW) ? expf(val - m) : 0.f;
  float s = br_sum<256>(e, red, t);
  if (t < HW) sim[(size_t)b*HW + t] = e/s;
}

// ---------- attn2 stage 4: V-proj + residual + fused bn3 stats ----------
__global__ __launch_bounds__(256) void k_attn2b(float* __restrict__ A,
        const float* __restrict__ att, const unsigned short* __restrict__ Wv,
        float* __restrict__ ps, float* __restrict__ pq) {
  int blk = blockIdx.x;
  int b = blk >> 2, tile = blk & 3, p0 = tile*64;
  int t = threadIdx.x;
  __shared__ __align__(16) unsigned short xh[16*64*8];
  __shared__ float pS[4][CC], pQ[4][CC];
  float* Ab = A + (size_t)b*CC*HW;
  {
    int px = t & 63, cig = t >> 6;
    int p = p0 + px;
    bool pv = p < HW;
    #pragma unroll
    for (int k0 = 0; k0 < 32; k0 += 8) {
      U8 th;
      #pragma unroll
      for (int j = 0; j < 8; ++j) {
        int ci = cig*32 + k0 + j;
        th.u[j] = pv ? f2bf(Ab[(size_t)ci*HW + p]) : 0;
      }
      *(short8*)&xh[((cig*4 + (k0>>3))*64 + px)*8] = th.v;
    }
  }
  __syncthreads();
  int w = t >> 6, l = t & 63, g = l >> 4, n = l & 15;
  int p = p0 + w*16 + n;
  bool pv = p < HW;
  float ap = pv ? att[(size_t)b*HW + p] : 0.f;
  const short8* wvp = (const short8*)Wv;
  short8 bf[4];
  #pragma unroll
  for (int cs = 0; cs < 4; ++cs)
    bf[cs] = *(const short8*)&xh[((cs*4 + g)*64 + w*16 + n)*8];
  #pragma unroll
  for (int ct = 0; ct < 8; ++ct) {
    f32x4 v = {};
    #pragma unroll
    for (int cs = 0; cs < 4; ++cs)
      v = __builtin_amdgcn_mfma_f32_16x16x32_bf16(wvp[(cs*8 + ct)*64 + l], bf[cs], v, 0, 0, 0);
    #pragma unroll
    for (int r = 0; r < 4; ++r) {
      int co = ct*16 + g*4 + r;
      float val = 0.f;
      if (pv) {
        val = ap*v[r] + Ab[(size_t)co*HW + p];
        Ab[(size_t)co*HW + p] = val;
      }
      float s = val, q = val*val;
      #pragma unroll
      for (int m = 1; m < 16; m <<= 1) { s += __shfl_xor(s, m); q += __shfl_xor(q, m); }
      if (n == 0) { pS[w][co] = s; pQ[w][co] = q; }
    }
  }
  __syncthreads();
  if (t < CC) {
    ps[(size_t)t*NPMAX + blk] = pS[0][t]+pS[1][t]+pS[2][t]+pS[3][t];
    pq[(size_t)t*NPMAX + blk] = pQ[0][t]+pQ[1][t]+pQ[2][t]+pQ[3][t];
  }
}

// ---------- BN3 + channel-attention gate; writes D (+ bf16 D2) ----------
__global__ __launch_bounds__(256) void k_chatt_v3(const float* __restrict__ A, float* __restrict__ D,
        unsigned short* __restrict__ D2,
        const float* __restrict__ sc, const float* __restrict__ sh,
        const unsigned short* __restrict__ Wc1, const float* __restrict__ b1,
        const unsigned short* __restrict__ Wc2, const float* __restrict__ b2) {
  int blk = blockIdx.x;
  int b = blk >> 2, tile = blk & 3, p0 = tile*64;
  int t = threadIdx.x;
  __shared__ __align__(16) unsigned short xh[16*64*8];
  __shared__ __align__(16) unsigned short hb[64*CIPH];
  __shared__ float scl[CC], shl[CC], b2l[CC], b1l[32];
  const float* Ab = A + (size_t)b*CC*HW;
  float* Db = D + (size_t)b*CC*HW;
  if (t < CC) { scl[t] = sc[t]; shl[t] = sh[t]; b2l[t] = b2[t]; }
  if (t < 32) b1l[t] = b1[t];
  __syncthreads();
  {
    int px = t & 63, cig = t >> 6;
    int p = p0 + px;
    bool pv = p < HW;
    #pragma unroll
    for (int k0 = 0; k0 < 32; k0 += 8) {
      U8 th;
      #pragma unroll
      for (int j = 0; j < 8; ++j) {
        int ci = cig*32 + k0 + j;
        th.u[j] = pv ? f2bf(Ab[(size_t)ci*HW + p]*scl[ci] + shl[ci]) : 0;
      }
      *(short8*)&xh[((cig*4 + (k0>>3))*64 + px)*8] = th.v;
    }
  }
  __syncthreads();
  int w = t >> 6, l = t & 63, g = l >> 4, n = l & 15;
  int p = p0 + w*16 + n;
  bool pv = p < HW;
  const short8* w1p = (const short8*)Wc1;
  const short8* w2p = (const short8*)Wc2;
  short8 bf[4];
  #pragma unroll
  for (int cs = 0; cs < 4; ++cs)
    bf[cs] = *(const short8*)&xh[((cs*4 + g)*64 + w*16 + n)*8];
  #pragma unroll
  for (int ct = 0; ct < 2; ++ct) {
    f32x4 a = {};
    #pragma unroll
    for (int cs = 0; cs < 4; ++cs)
      a = __builtin_amdgcn_mfma_f32_16x16x32_bf16(w1p[(cs*2 + ct)*64 + l], bf[cs], a, 0, 0, 0);
    us4 hv;
    #pragma unroll
    for (int r = 0; r < 4; ++r) hv[r] = f2bf(fmaxf(a[r] + b1l[ct*16 + g*4 + r], 0.f));
    *(us4*)&hb[(w*16+n)*CIPH + ct*16 + g*4] = hv;
  }
  __syncthreads();
  short8 hf = *(const short8*)&hb[(w*16+n)*CIPH + g*8];
  #pragma unroll
  for (int ct = 0; ct < 8; ++ct) {
    f32x4 a = __builtin_amdgcn_mfma_f32_16x16x32_bf16(w2p[ct*64 + l], hf, f32x4{}, 0, 0, 0);
    if (pv) {
      us4 dv;
      #pragma unroll
      for (int r = 0; r < 4; ++r) {
        int co = ct*16 + g*4 + r;
        float s = a[r] + b2l[co];
        float gt = 1.f/(1.f + expf(-s));
        float xin = Ab[(size_t)co*HW + p]*scl[co] + shl[co];
        float o = xin*gt;
        Db[(size_t)co*HW + p] = o;
        dv[r] = f2bf(o);
      }
      if (D2) *(us4*)&D2[((size_t)b*HW + p)*CIP + ct*16 + g*4] = dv;
    }
  }
}

// ---------- 7x7 conv 128->32, row-split, ct/rh-split waves, dy-reuse rs-loop (+ bn4 stats) ----------
template<int USED2>
__global__ __launch_bounds__(256) void k_conv7a_mfma(const float* __restrict__ D,
        const unsigned short* __restrict__ D2,
        const unsigned short* __restrict__ Wa, float* __restrict__ S,
        float* __restrict__ ps, float* __restrict__ pq) {
  int b = blockIdx.x, half = blockIdx.y, t = threadIdx.x;
  __shared__ __align__(16) unsigned short xb[4*NRW*22*8];   // 19,712 B, [oct][row][x][8]
  __shared__ float pS[2][32], pQ[2][32];
  unsigned int* xw = (unsigned int*)xb;
  for (int i = t; i < 4*NRW*22*8/2; i += 256) xw[i] = 0u;
  int w = t >> 6, l = t & 63, g = l >> 4, x = l & 15;
  int ct = w & 1, rh = w >> 1;
  int row0 = half*8;
  f32x4 acc[4] = {};
  const short8* wp = (const short8*)Wa;
  bool prow = false; int rr = 0, xp = 0;
  if (t < HW) {
    int py = t/15, px = t - (t/15)*15;
    int gp = py + 3;
    prow = (gp >= row0) && (gp < row0 + NRW);
    rr = gp - row0; xp = px + 3;
  }
  for (int ck = 0; ck < 4; ++ck) {
    __syncthreads();
    if (prow) {
      if (USED2) {
        const unsigned short* src = &D2[((size_t)b*HW + t)*CIP + ck*32];
        #pragma unroll
        for (int g0 = 0; g0 < 4; ++g0)
          *(short8*)&xb[((g0*NRW + rr)*22 + xp)*8] = *(const short8*)&src[g0*8];
      } else {
        const float* Dbp = D + ((size_t)b*CC + ck*32)*HW;
        #pragma unroll
        for (int g0 = 0; g0 < 4; ++g0) {
          U8 tb;
          #pragma unroll
          for (int k = 0; k < 8; ++k) tb.u[k] = f2bf(Dbp[(g0*8+k)*HW + t]);
          *(short8*)&xb[((g0*NRW + rr)*22 + xp)*8] = tb.v;
        }
      }
    }
    __syncthreads();
    for (int dx = 0; dx < 7; ++dx) {
      short8 aw[7];
      #pragma unroll
      for (int dy = 0; dy < 7; ++dy)
        aw[dy] = wp[(((ck*7 + dx)*7 + dy)*2 + ct)*64 + l];
      #pragma unroll
      for (int rs = 0; rs < 10; ++rs) {
        short8 bf = *(const short8*)&xb[((g*NRW + rh*4 + rs)*22 + x + dx)*8];
        #pragma unroll
        for (int r = 0; r < 4; ++r) {
          int dy = rs - r;
          if (dy >= 0 && dy <= 6)
            acc[r] = __builtin_amdgcn_mfma_f32_16x16x32_bf16(aw[dy], bf, acc[r], 0, 0, 0);
        }
      }
    }
  }
  float ls[4] = {}, lq[4] = {};
  #pragma unroll
  for (int r = 0; r < 4; ++r) {
    int nt = row0 + rh*4 + r;
    bool valid = (x < 15) && (nt < 15);
    if (valid) {
      float* out = S + ((size_t)b*32 + ct*16 + g*4)*HW + nt*15 + x;
      #pragma unroll
      for (int q = 0; q < 4; ++q) out[q*HW] = acc[r][q];
    }
    #pragma unroll
    for (int q = 0; q < 4; ++q) {
      float v = valid ? acc[r][q] : 0.f;
      ls[q] += v; lq[q] += v*v;
    }
  }
  #pragma unroll
  for (int q = 0; q < 4; ++q) {
    float s = ls[q], qq = lq[q];
    #pragma unroll
    for (int m = 1; m < 16; m <<= 1) { s += __shfl_xor(s, m); qq += __shfl_xor(qq, m); }
    if (x == 0) { pS[rh][ct*16 + g*4 + q] = s; pQ[rh][ct*16 + g*4 + q] = qq; }
  }
  __syncthreads();
  if (t < 32) {
    ps[(size_t)t*NPMAX + b*2 + half] = pS[0][t]+pS[1][t];
    pq[(size_t)t*NPMAX + b*2 + half] = pQ[0][t]+pQ[1][t];
  }
}

// ---------- 7x7 conv 32->128, row-split, ct-pair waves, dy-reuse rs-loop (+ bn5 stats) ----------
__global__ __launch_bounds__(256) void k_conv7b_mfma(const float* __restrict__ S,
        const float* __restrict__ sc, const float* __restrict__ sh,
        const unsigned short* __restrict__ Wb, float* __restrict__ O,
        float* __restrict__ ps, float* __restrict__ pq) {
  int b = blockIdx.x, half = blockIdx.y, t = threadIdx.x;
  __shared__ __align__(16) unsigned short xb[4*NRW*22*8];   // 19,712 B
  __shared__ float scl[32], shl[32];
  __shared__ float pS[CC], pQ[CC];
  unsigned int* xw = (unsigned int*)xb;
  for (int i = t; i < 4*NRW*22*8/2; i += 256) xw[i] = 0u;
  if (t < 32) { scl[t] = sc[t]; shl[t] = sh[t]; }
  __syncthreads();
  int row0 = half*8;
  const float* Sb = S + (size_t)b*32*HW;
  if (t < HW) {
    int py = t/15, px = t - (t/15)*15;
    int gp = py + 3;
    if (gp >= row0 && gp < row0 + NRW) {
      int rr = gp - row0, xp = px + 3;
      #pragma unroll
      for (int g0 = 0; g0 < 4; ++g0) {
        U8 tb;
        #pragma unroll
        for (int k = 0; k < 8; ++k)
          tb.u[k] = f2bf(fmaxf(Sb[(g0*8+k)*HW + t]*scl[g0*8+k] + shl[g0*8+k], 0.f));
        *(short8*)&xb[((g0*NRW + rr)*22 + xp)*8] = tb.v;
      }
    }
  }
  __syncthreads();
  int w = t >> 6, l = t & 63, g = l >> 4, x = l & 15;
  int ct0 = w*2;
  f32x4 acc[2][8] = {};
  const short8* wp = (const short8*)Wb;
  for (int dx = 0; dx < 7; ++dx) {
    short8 a0[7], a1[7];
    #pragma unroll
    for (int dy = 0; dy < 7; ++dy) {
      a0[dy] = wp[((dx*7 + dy)*8 + ct0)*64 + l];
      a1[dy] = wp[((dx*7 + dy)*8 + ct0 + 1)*64 + l];
    }
    #pragma unroll
    for (int rs = 0; rs < 14; ++rs) {
      short8 bf = *(const short8*)&xb[((g*NRW + rs)*22 + x + dx)*8];
      #pragma unroll
      for (int r = 0; r < 8; ++r) {
        int dy = rs - r;
        if (dy >= 0 && dy <= 6) {
          acc[0][r] = __builtin_amdgcn_mfma_f32_16x16x32_bf16(a0[dy], bf, acc[0][r], 0, 0, 0);
          acc[1][r] = __builtin_amdgcn_mfma_f32_16x16x32_bf16(a1[dy], bf, acc[1][r], 0, 0, 0);
        }
      }
    }
  }
  float ls[2][4] = {}, lq[2][4] = {};
  #pragma unroll
  for (int ctl = 0; ctl < 2; ++ctl)
    #pragma unroll
    for (int r = 0; r < 8; ++r) {
      int nt = row0 + r;
      bool valid = (x < 15) && (nt < 15);
      if (valid) {
        float* out = O + ((size_t)b*CC + (ct0+ctl)*16 + g*4)*HW + nt*15 + x;
        #pragma unroll
        for (int q = 0; q < 4; ++q) out[q*HW] = acc[ctl][r][q];
      }
      #pragma unroll
      for (int q = 0; q < 4; ++q) {
        float v = valid ? acc[ctl][r][q] : 0.f;
        ls[ctl][q] += v; lq[ctl][q] += v*v;
      }
    }
  #pragma unroll
  for (int ctl = 0; ctl < 2; ++ctl)
    #pragma unroll
    for (int q = 0; q < 4; ++q) {
      float s = ls[ctl][q], qq = lq[ctl][q];
      #pragma unroll
      for (int m = 1; m < 16; m <<= 1) { s += __shfl_xor(s, m); qq += __shfl_xor(qq, m); }
      if (x == 0) { pS[(ct0+ctl)*16 + g*4 + q] = s; pQ[(ct0+ctl)*16 + g*4 + q] = qq; }
    }
  __syncthreads();
  if (t < CC) {
    ps[(size_t)t*NPMAX + b*2 + half] = pS[t];
    pq[(size_t)t*NPMAX + b*2 + half] = pQ[t];
  }
}

// ---------- final: D *= sigmoid(bn5(A)), float4 ----------
__global__ __launch_bounds__(256) void k_final4(f32x4* __restrict__ D, const f32x4* __restrict__ A,
                        const float* __restrict__ sc, const float* __restrict__ sh) {
  size_t i = (size_t)blockIdx.x*256 + threadIdx.x;
  f32x4 a = A[i], d = D[i];
  size_t e = i*4;
  #pragma unroll
  for (int k = 0; k < 4; ++k) {
    int c = (int)(((e + k) / HW) % CC);
    float s = a[k]*sc[c] + sh[c];
    d[k] *= 1.f/(1.f + expf(-s));
  }
  D[i] = d;
}

extern "C" void kernel_launch(void* const* d_in, const int* in_sizes, int n_in,
                              void* d_out, int out_size, void* d_ws, size_t ws_size,
                              hipStream_t stream) {
  (void)in_sizes; (void)n_in; (void)out_size;
  const float* x1    = (const float*)d_in[0];
  const float* x2    = (const float*)d_in[1];
  const float* lam   = (const float*)d_in[2];
  const float* bn1_g = (const float*)d_in[3];
  const float* bn1_b = (const float*)d_in[4];
  const float* pW1   = (const float*)d_in[5];
  const float* dW1   = (const float*)d_in[6];
  const float* db1   = (const float*)d_in[7];
  const float* bn2_g = (const float*)d_in[8];
  const float* bn2_b = (const float*)d_in[9];
  const float* pW2   = (const float*)d_in[10];
  const float* dW2   = (const float*)d_in[11];
  const float* db2   = (const float*)d_in[12];
  const float* qkvW  = (const float*)d_in[13];
  const float* bn3_g = (const float*)d_in[14];
  const float* bn3_b = (const float*)d_in[15];
  const float* ca_w1 = (const float*)d_in[16];
  const float* ca_b1 = (const float*)d_in[17];
  const float* ca_w2 = (const float*)d_in[18];
  const float* ca_b2 = (const float*)d_in[19];
  const float* sa_w1 = (const float*)d_in[20];
  const float* sbn1_g= (const float*)d_in[22];
  const float* sbn1_b= (const float*)d_in[23];
  const float* sa_w2 = (const float*)d_in[24];
  const float* sbn2_g= (const float*)d_in[26];
  const float* sbn2_b= (const float*)d_in[27];

  float* D = (float*)d_out;
  float* A = (float*)d_ws;                          // (512,128,225) f32
  float* S = A + (size_t)BB*CC*HW;                  // (512,32,225)  f32
  float* part = S + (size_t)BB*32*HW;               // 512*4*3*256 f32
  float* st = part + (size_t)BB*4*3*256;            // 1280 f32 stats
  float *sc1 = st,      *sh1 = st+128,  *sc2 = st+256, *sh2 = st+384,
        *sc3 = st+512,  *sh3 = st+640,  *sc4 = st+768, *sh4 = st+800,
        *sc5 = st+832,  *sh5 = st+960;
  float* ps = st + 1280;                            // 128*NPMAX
  float* pq = ps + (size_t)CC*NPMAX;                // 128*NPMAX
  float* cent = pq + (size_t)CC*NPMAX;              // 512*128
  float* sim  = cent + (size_t)BB*CC;               // 512*225
  float* am   = sim + (size_t)BB*HW;                // 512*225
  unsigned short* Wa  = (unsigned short*)(am + (size_t)BB*HW);
  unsigned short* Wb  = Wa + 49*4096;
  unsigned short* W1h = Wb + 49*4096;
  unsigned short* W1l = W1h + 16384;
  unsigned short* W2h = W1l + 16384;
  unsigned short* W2l = W2h + 16384;
  unsigned short* Wk  = W2l + 16384;
  unsigned short* Wv  = Wk  + 16384;
  unsigned short* Wc1 = Wv  + 16384;
  unsigned short* Wc2 = Wc1 + 4096;
  unsigned short* D2  = Wc2 + 4096;                 // (512,225,136) bf16, optional
  size_t need = (size_t)((char*)(D2 + (size_t)BB*HW*CIP) - (char*)d_ws);
  bool useD2 = ws_size >= need;

  const int NB4 = BB*4;

  k_prep_all<<<1792, 256, 0, stream>>>(sa_w1, sa_w2, pW1, pW2, qkvW, ca_w1, ca_w2,
                                       Wa, Wb, W1h, W1l, W2h, W2l, Wk, Wv, Wc1, Wc2);

  k_at1a <<<dim3(BB,4), 256, 0, stream>>>(x1, x2, part);
  k_at1b <<<BB, 256, 0, stream>>>(x1, x2, part, lam, am);
  k_at1c <<<dim3(BB,4), 256, 0, stream>>>(x1, x2, am, A, ps, pq);
  k_bnfin2<<<CC, 256, 0, stream>>>(ps, pq, BB, bn1_g, bn1_b, sc1, sh1);
  k_pw_v3<1><<<NB4, 256, 0, stream>>>(A, W1h, W1l, sc1, sh1, dW1, db1, ps, pq);
  k_bnfin2<<<CC, 256, 0, stream>>>(ps, pq, NB4, bn2_g, bn2_b, sc2, sh2);
  k_pw_v3<2><<<NB4, 256, 0, stream>>>(A, W2h, W2l, sc2, sh2, nullptr, nullptr, nullptr, nullptr);
  k_dw3   <<<dim3(BB,8), 256, 0, stream>>>(A, dW2, db2);
  k_cent  <<<BB, 128, 0, stream>>>(A, qkvW, cent);
  k_attn2a<<<NB4, 256, 0, stream>>>(A, cent, Wk, sim);
  k_soft  <<<BB, 256, 0, stream>>>(sim);
  k_attn2b<<<NB4, 256, 0, stream>>>(A, sim, Wv, ps, pq);
  k_bnfin2<<<CC, 256, 0, stream>>>(ps, pq, NB4, bn3_g, bn3_b, sc3, sh3);
  k_chatt_v3<<<NB4, 256, 0, stream>>>(A, D, useD2 ? D2 : nullptr, sc3, sh3, Wc1, ca_b1, Wc2, ca_b2);
  if (useD2) k_conv7a_mfma<1><<<dim3(BB,2), 256, 0, stream>>>(D, D2, Wa, S, ps, pq);
  else       k_conv7a_mfma<0><<<dim3(BB,2), 256, 0, stream>>>(D, nullptr, Wa, S, ps, pq);
  k_bnfin2<<<32, 256, 0, stream>>>(ps, pq, BB*2, sbn1_g, sbn1_b, sc4, sh4);
  k_conv7b_mfma<<<dim3(BB,2), 256, 0, stream>>>(S, sc4, sh4, Wb, A, ps, pq);
  k_bnfin2<<<CC, 256, 0, stream>>>(ps, pq, BB*2, sbn2_g, sbn2_b, sc5, sh5);
  k_final4<<<(BB*CC*HW)/1024, 256, 0, stream>>>((f32x4*)D, (const f32x4*)A, sc5, sh5);
}

// Round 14
// 501.560 us; speedup vs baseline: 1.5263x; 1.0279x over previous
//
#include <hip/hip_runtime.h>
#include <hip/hip_bf16.h>
#include <cmath>

#define BB 512
#define CC 128
#define HW 225
#define CIP 136     // ushort stride of D2 [px][ci] rows (272 B)
#define CIPH 40     // ushort stride for 32-ch hidden rows
#define NPMAX 2048  // max partial-stat blocks
#define NRW 14      // padded-row window for row-split convs

typedef __attribute__((ext_vector_type(8))) short short8;
typedef __attribute__((ext_vector_type(4))) float f32x4;
typedef __attribute__((ext_vector_type(4))) unsigned short us4;

union U8 { unsigned short u[8]; short8 v; };

__device__ __forceinline__ unsigned short f2bf(float v) {
  __hip_bfloat16 h = __float2bfloat16(v);
  return *(unsigned short*)&h;
}
__device__ __forceinline__ float bf2f(unsigned short u) {
  __hip_bfloat16 h = *(__hip_bfloat16*)&u;
  return __bfloat162float(h);
}

template<int NT>
__device__ __forceinline__ float br_max(float v, float* red, int t) {
  red[t] = v; __syncthreads();
  for (int st = NT/2; st > 0; st >>= 1) { if (t < st) red[t] = fmaxf(red[t], red[t+st]); __syncthreads(); }
  float r = red[0]; __syncthreads();
  return r;
}
template<int NT>
__device__ __forceinline__ float br_sum(float v, float* red, int t) {
  red[t] = v; __syncthreads();
  for (int st = NT/2; st > 0; st >>= 1) { if (t < st) red[t] += red[t+st]; __syncthreads(); }
  float r = red[0]; __syncthreads();
  return r;
}

// finalize fused per-block partials ps/pq[c][NPMAX], np valid slots
__global__ __launch_bounds__(256) void k_bnfin2(const float* __restrict__ ps, const float* __restrict__ pq,
                         int np,
                         const float* __restrict__ g, const float* __restrict__ bt,
                         float* __restrict__ scale, float* __restrict__ shift) {
  int c = blockIdx.x, t = threadIdx.x;
  __shared__ float rs[256], rq[256];
  float s = 0.f, q = 0.f;
  for (int i = t; i < np; i += 256) { s += ps[(size_t)c*NPMAX + i]; q += pq[(size_t)c*NPMAX + i]; }
  rs[t] = s; rq[t] = q; __syncthreads();
  for (int st = 128; st > 0; st >>= 1) { if (t < st) { rs[t]+=rs[t+st]; rq[t]+=rq[t+st]; } __syncthreads(); }
  if (t == 0) {
    const float N = (float)BB*HW;
    float mean = rs[0]/N, var = rq[0]/N - mean*mean;
    float sc = g[c]*rsqrtf(var + 1e-5f);
    scale[c] = sc; shift[c] = bt[c] - mean*sc;
  }
}

// ---------- attn1 stage A: per (image, ch-group) pixel partials ----------
__global__ __launch_bounds__(256) void k_at1a(const float* __restrict__ x1, const float* __restrict__ x2,
                       float* __restrict__ part) {
  int b = blockIdx.x, cg = blockIdx.y, t = threadIdx.x;
  __shared__ float cent[32];
  const float* xb1 = x1 + (size_t)b*64*HW;
  const float* xb2 = x2 + (size_t)b*64*HW;
  if (t < 32) { int c = cg*32 + t; cent[t] = (c < 64) ? xb1[c*HW + 112] : xb2[(c-64)*HW + 112]; }
  __syncthreads();
  if (t < HW) {
    float e2 = 0.f, dot = 0.f, qn2 = 0.f;
    for (int k = 0; k < 32; ++k) {
      int c = cg*32 + k;
      float xv = (c < 64) ? xb1[c*HW + t] : xb2[(c-64)*HW + t];
      float ce = cent[k];
      float d = xv - ce;
      e2 += d*d; dot += xv*ce; qn2 += xv*xv;
    }
    size_t base = ((size_t)(b*4 + cg)*3)*256;
    part[base + t] = e2; part[base + 256 + t] = dot; part[base + 512 + t] = qn2;
  }
}

// ---------- attn1 stage B: combine + dual softmax -> am[b][p] ----------
__global__ __launch_bounds__(256) void k_at1b(const float* __restrict__ x1, const float* __restrict__ x2,
                       const float* __restrict__ part, const float* __restrict__ lam,
                       float* __restrict__ am) {
  int b = blockIdx.x, t = threadIdx.x;
  __shared__ float red[256];
  float cv = 0.f;
  if (t < CC) {
    float ce = (t < 64) ? x1[(size_t)b*64*HW + t*HW + 112] : x2[(size_t)b*64*HW + (t-64)*HW + 112];
    cv = ce*ce;
  }
  float cn2 = br_sum<256>(cv, red, t);
  float e2 = 0.f, dot = 0.f, qn2 = 0.f;
  if (t < HW) {
    #pragma unroll
    for (int cg = 0; cg < 4; ++cg) {
      size_t base = ((size_t)(b*4 + cg)*3)*256;
      e2 += part[base + t]; dot += part[base + 256 + t]; qn2 += part[base + 512 + t];
    }
  }
  float sim_e = 0.f, sim_c = 0.f;
  if (t < HW) {
    sim_e = 1.f/(1.f + sqrtf(e2));
    float qn = sqrtf(qn2), cn = sqrtf(cn2);
    sim_c = dot / (fmaxf(cn, 1e-8f) * fmaxf(qn, 1e-8f));
  }
  float m1 = br_max<256>((t<HW)? sim_e : -1e30f, red, t);
  float e1v = (t<HW)? expf(sim_e - m1) : 0.f;
  float s1 = br_sum<256>(e1v, red, t);
  float m2 = br_max<256>((t<HW)? sim_c : -1e30f, red, t);
  float e2v = (t<HW)? expf(sim_c - m2) : 0.f;
  float s2 = br_sum<256>(e2v, red, t);
  float lmd = 1.f/(1.f + expf(-lam[0]));
  if (t < HW) am[(size_t)b*HW + t] = 1.f + lmd*e1v/s1 + (1.f - lmd)*e2v/s2;
}

// ---------- attn1 stage C: A = x*am (+ fused bn1 partials per 32-ch group) ----------
__global__ __launch_bounds__(256) void k_at1c(const float* __restrict__ x1, const float* __restrict__ x2,
                       const float* __restrict__ am, float* __restrict__ A,
                       float* __restrict__ ps, float* __restrict__ pq) {
  int b = blockIdx.x, cg = blockIdx.y, t = threadIdx.x;
  __shared__ float pS[4][32], pQ[4][32];
  const float* xb1 = x1 + (size_t)b*64*HW;
  const float* xb2 = x2 + (size_t)b*64*HW;
  float* Ab = A + (size_t)b*CC*HW;
  float amv = (t < HW) ? am[(size_t)b*HW + t] : 0.f;
  int w = t >> 6, lane = t & 63;
  for (int k = 0; k < 32; ++k) {
    int c = cg*32 + k;
    float xv = 0.f;
    if (t < HW) xv = (c < 64) ? xb1[c*HW + t] : xb2[(c-64)*HW + t];
    float val = xv*amv;
    if (t < HW) Ab[(size_t)c*HW + t] = val;
    float s = val, q = val*val;
    #pragma unroll
    for (int m = 1; m < 64; m <<= 1) { s += __shfl_xor(s, m); q += __shfl_xor(q, m); }
    if (lane == 0) { pS[w][k] = s; pQ[w][k] = q; }
  }
  __syncthreads();
  if (t < 32) {
    int c = cg*32 + t;
    ps[(size_t)c*NPMAX + b] = pS[0][t]+pS[1][t]+pS[2][t]+pS[3][t];
    pq[(size_t)c*NPMAX + b] = pQ[0][t]+pQ[1][t]+pQ[2][t]+pQ[3][t];
  }
}

// ---------- merged weight pre-pack ----------
// Wa: [ck(4)][dx(7)][dy(7)][ct(2)][lane64][j8]  (contiguous dy streams)
// Wb: [dx(7)][dy(7)][ct(8)][lane64][j8]
__global__ __launch_bounds__(256) void k_prep_all(
    const float* __restrict__ sa_w1, const float* __restrict__ sa_w2,
    const float* __restrict__ pW1, const float* __restrict__ pW2,
    const float* __restrict__ qkvW, const float* __restrict__ ca_w1, const float* __restrict__ ca_w2,
    unsigned short* __restrict__ Wa, unsigned short* __restrict__ Wb,
    unsigned short* __restrict__ W1h, unsigned short* __restrict__ W1l,
    unsigned short* __restrict__ W2h, unsigned short* __restrict__ W2l,
    unsigned short* __restrict__ Wk, unsigned short* __restrict__ Wv,
    unsigned short* __restrict__ Wc1, unsigned short* __restrict__ Wc2) {
  int id = blockIdx.x*256 + threadIdx.x;
  const int NA = 49*4096;
  if (id < NA) {                                  // conv7a weights
    int j = id & 7, l = (id >> 3) & 63, ct = (id >> 9) & 1;
    int r = id >> 10;                             // ((ck*7+dx)*7+dy)
    int dy = r % 7; r /= 7;
    int dx = r % 7; int ck = r / 7;
    int co = ct*16 + (l & 15);
    int ci = ck*32 + ((l >> 4) << 3) + j;
    Wa[id] = f2bf(sa_w1[(co*128 + ci)*49 + dy*7 + dx]);
    return;
  }
  id -= NA;
  if (id < NA) {                                  // conv7b weights
    int j = id & 7, l = (id >> 3) & 63, ct = (id >> 9) & 7;
    int r = id >> 12;                             // dx*7+dy
    int dy = r % 7, dx = r / 7;
    int co = ct*16 + (l & 15);
    int ci = ((l >> 4) << 3) + j;
    Wb[id] = f2bf(sa_w2[(co*32 + ci)*49 + dy*7 + dx]);
    return;
  }
  id -= NA;
  if (id < 16384) {
    int j = id & 7, l = (id >> 3) & 63, ct = (id >> 9) & 7, cs = id >> 12;
    int co = ct*16 + (l & 15);
    int ci = cs*32 + ((l >> 4) << 3) + j;
    float v = pW1[co*128 + ci];
    __hip_bfloat16 h = __float2bfloat16(v);
    W1h[id] = *(unsigned short*)&h;
    W1l[id] = f2bf(v - __bfloat162float(h));
    return;
  }
  id -= 16384;
  if (id < 16384) {
    int j = id & 7, l = (id >> 3) & 63, ct = (id >> 9) & 7, cs = id >> 12;
    int co = ct*16 + (l & 15);
    int ci = cs*32 + ((l >> 4) << 3) + j;
    float v = pW2[co*128 + ci];
    __hip_bfloat16 h = __float2bfloat16(v);
    W2h[id] = *(unsigned short*)&h;
    W2l[id] = f2bf(v - __bfloat162float(h));
    return;
  }
  id -= 16384;
  if (id < 16384) {
    int j = id & 7, l = (id >> 3) & 63, ct = (id >> 9) & 7, cs = id >> 12;
    int co = ct*16 + (l & 15);
    int ci = cs*32 + ((l >> 4) << 3) + j;
    Wk[id] = f2bf(qkvW[(size_t)(128 + co)*128 + ci]);
    Wv[id] = f2bf(qkvW[(size_t)(256 + co)*128 + ci]);
    return;
  }
  id -= 16384;
  if (id < 4096) {
    int j = id & 7, l = (id >> 3) & 63, ct = (id >> 9) & 1, cs = (id >> 10) & 3;
    int co = ct*16 + (l & 15);
    int ci = cs*32 + ((l >> 4) << 3) + j;
    Wc1[id] = f2bf(ca_w1[co*128 + ci]);
    return;
  }
  id -= 4096;
  {
    int j = id & 7, l = (id >> 3) & 63, ct = (id >> 9) & 7;
    int co = ct*16 + (l & 15);
    int ci = ((l >> 4) << 3) + j;
    Wc2[id] = f2bf(ca_w2[co*32 + ci]);
  }
}

// ---------- fused BN + 1x1 conv, pixel-tile GEMM, ct-split waves, in-place ----------
template<int MODE>
__global__ __launch_bounds__(256) void k_pw_v3(float* __restrict__ A,
        const unsigned short* __restrict__ Whi, const unsigned short* __restrict__ Wlo,
        const float* __restrict__ scale, const float* __restrict__ shift,
        const float* __restrict__ dw, const float* __restrict__ db,
        float* __restrict__ ps, float* __restrict__ pq) {
  int blk = blockIdx.x;
  int b = blk >> 2, tile = blk & 3, p0 = tile*64;
  int t = threadIdx.x;
  __shared__ __align__(16) unsigned short xh[16*64*8];   // [oct][px][8] 16 KB
  __shared__ __align__(16) unsigned short xl[16*64*8];
  __shared__ float scl[CC], shf[CC], dwl[CC], dbl[CC];
  __shared__ float pS[CC], pQ[CC];
  if (t < CC) {
    scl[t] = scale[t]; shf[t] = shift[t];
    if (MODE == 1) { dwl[t] = dw[t]; dbl[t] = db[t]; }
  }
  __syncthreads();
  float* Ab = A + (size_t)b*CC*HW;
  {
    int px = t & 63, cig = t >> 6;
    int p = p0 + px;
    bool pv = p < HW;
    #pragma unroll
    for (int k0 = 0; k0 < 32; k0 += 8) {
      U8 th, tl;
      #pragma unroll
      for (int j = 0; j < 8; ++j) {
        int ci = cig*32 + k0 + j;
        float v = pv ? Ab[(size_t)ci*HW + p]*scl[ci] + shf[ci] : 0.f;
        __hip_bfloat16 h = __float2bfloat16(v);
        th.u[j] = *(unsigned short*)&h;
        tl.u[j] = f2bf(v - __bfloat162float(h));
      }
      int oo = cig*4 + (k0 >> 3);
      *(short8*)&xh[(oo*64 + px)*8] = th.v;
      *(short8*)&xl[(oo*64 + px)*8] = tl.v;
    }
  }
  __syncthreads();
  int w = t >> 6, l = t & 63, g = l >> 4, n = l & 15;
  const short8* whp = (const short8*)Whi;
  const short8* wlp = (const short8*)Wlo;
  short8 ah[4][2], al[4][2];
  #pragma unroll
  for (int cs = 0; cs < 4; ++cs)
    #pragma unroll
    for (int ctl = 0; ctl < 2; ++ctl) {
      ah[cs][ctl] = whp[(cs*8 + w*2 + ctl)*64 + l];
      al[cs][ctl] = wlp[(cs*8 + w*2 + ctl)*64 + l];
    }
  float ls[2][4] = {}, lq[2][4] = {};
  for (int pt = 0; pt < 4; ++pt) {
    int p = p0 + pt*16 + n;
    bool pv = p < HW;
    short8 bh[4], bl[4];
    #pragma unroll
    for (int cs = 0; cs < 4; ++cs) {
      bh[cs] = *(const short8*)&xh[((cs*4 + g)*64 + pt*16 + n)*8];
      bl[cs] = *(const short8*)&xl[((cs*4 + g)*64 + pt*16 + n)*8];
    }
    f32x4 acc[2] = {};
    #pragma unroll
    for (int cs = 0; cs < 4; ++cs)
      #pragma unroll
      for (int ctl = 0; ctl < 2; ++ctl) {
        acc[ctl] = __builtin_amdgcn_mfma_f32_16x16x32_bf16(ah[cs][ctl], bh[cs], acc[ctl], 0, 0, 0);
        acc[ctl] = __builtin_amdgcn_mfma_f32_16x16x32_bf16(ah[cs][ctl], bl[cs], acc[ctl], 0, 0, 0);
        acc[ctl] = __builtin_amdgcn_mfma_f32_16x16x32_bf16(al[cs][ctl], bh[cs], acc[ctl], 0, 0, 0);
      }
    #pragma unroll
    for (int ctl = 0; ctl < 2; ++ctl)
      #pragma unroll
      for (int r = 0; r < 4; ++r) {
        int co = (w*2 + ctl)*16 + g*4 + r;
        float y = acc[ctl][r];
        y = (y >= 0.f) ? y : 0.01f*y;
        if (MODE == 1) { y = y*dwl[co] + dbl[co]; y = fmaxf(y, 0.f); }
        if (pv) Ab[(size_t)co*HW + p] = y;
        if (MODE == 1) {
          float vs = pv ? y : 0.f;
          ls[ctl][r] += vs; lq[ctl][r] += vs*vs;
        }
      }
  }
  if (MODE == 1) {
    #pragma unroll
    for (int ctl = 0; ctl < 2; ++ctl)
      #pragma unroll
      for (int r = 0; r < 4; ++r) {
        float s = ls[ctl][r], q = lq[ctl][r];
        #pragma unroll
        for (int m = 1; m < 16; m <<= 1) { s += __shfl_xor(s, m); q += __shfl_xor(q, m); }
        if (n == 0) { pS[(w*2 + ctl)*16 + g*4 + r] = s; pQ[(w*2 + ctl)*16 + g*4 + r] = q; }
      }
    __syncthreads();
    if (t < CC) {
      ps[(size_t)t*NPMAX + blk] = pS[t];
      pq[(size_t)t*NPMAX + blk] = pQ[t];
    }
  }
}

// ---------- depthwise 3x3 pad1 + bias + relu, grid (B, 8 ch-groups) ----------
__global__ __launch_bounds__(256) void k_dw3(float* __restrict__ A, const float* __restrict__ w,
                      const float* __restrict__ db) {
  int b = blockIdx.x, cg = blockIdx.y, t = threadIdx.x;
  __shared__ float xin[16][HW];
  float* Ab = A + ((size_t)b*CC + cg*16)*HW;
  for (int i = t; i < 16*HW; i += 256) xin[i/HW][i%HW] = Ab[i];
  __syncthreads();
  if (t < HW) {
    int y = t/15, x = t - y*15;
    for (int c = 0; c < 16; ++c) {
      int ch = cg*16 + c;
      float acc = db[ch];
      #pragma unroll
      for (int ky = 0; ky < 3; ++ky) {
        int iy = y + ky - 1;
        if (iy < 0 || iy >= 15) continue;
        #pragma unroll
        for (int kx = 0; kx < 3; ++kx) {
          int ix = x + kx - 1;
          if (ix < 0 || ix >= 15) continue;
          acc += w[ch*9 + ky*3 + kx]*xin[c][iy*15 + ix];
        }
      }
      Ab[c*HW + t] = fmaxf(acc, 0.f);
    }
  }
}

// ---------- attn2 stage 1: center Q projection ----------
__global__ __launch_bounds__(128) void k_cent(const float* __restrict__ A,
        const float* __restrict__ Wq, float* __restrict__ cent) {
  int b = blockIdx.x, t = threadIdx.x;
  __shared__ float xc[CC];
  const float* Ab = A + (size_t)b*CC*HW;
  xc[t] = bf2f(f2bf(Ab[(size_t)t*HW + 112]));
  __syncthreads();
  const float* wq = Wq + (size_t)t*CC;
  float acc = 0.f;
  for (int ci = 0; ci < CC; ++ci) acc += wq[ci]*xc[ci];
  cent[(size_t)b*CC + t] = acc;
}

// ---------- attn2 stage 2: K-proj + e2 logits, octet-major LDS ----------
__global__ __launch_bounds__(256) void k_attn2a(const float* __restrict__ A,
        const float* __restrict__ cent, const unsigned short* __restrict__ Wk,
        float* __restrict__ sim) {
  int blk = blockIdx.x;
  int b = blk >> 2, tile = blk & 3, p0 = tile*64;
  int t = threadIdx.x;
  __shared__ __align__(16) unsigned short xh[16*64*8];
  __shared__ float cl[CC];
  const float* Ab = A + (size_t)b*CC*HW;
  if (t < CC) cl[t] = cent[(size_t)b*CC + t];
  {
    int px = t & 63, cig = t >> 6;
    int p = p0 + px;
    bool pv = p < HW;
    #pragma unroll
    for (int k0 = 0; k0 < 32; k0 += 8) {
      U8 th;
      #pragma unroll
      for (int j = 0; j < 8; ++j) {
        int ci = cig*32 + k0 + j;
        th.u[j] = pv ? f2bf(Ab[(size_t)ci*HW + p]) : 0;
      }
      *(short8*)&xh[((cig*4 + (k0>>3))*64 + px)*8] = th.v;
    }
  }
  __syncthreads();
  int w = t >> 6, l = t & 63, g = l >> 4, n = l & 15;
  int p = p0 + w*16 + n;
  bool pv = p < HW;
  const short8* wkp = (const short8*)Wk;
  short8 bf[4];
  #pragma unroll
  for (int cs = 0; cs < 4; ++cs)
    bf[cs] = *(const short8*)&xh[((cs*4 + g)*64 + w*16 + n)*8];
  float e2p = 0.f;
  #pragma unroll
  for (int ct = 0; ct < 8; ++ct) {
    f32x4 k = {};
    #pragma unroll
    for (int cs = 0; cs < 4; ++cs)
      k = __builtin_amdgcn_mfma_f32_16x16x32_bf16(wkp[(cs*8 + ct)*64 + l], bf[cs], k, 0, 0, 0);
    #pragma unroll
    for (int r = 0; r < 4; ++r) { float d = cl[ct*16 + g*4 + r] - k[r]; e2p += d*d; }
  }
  e2p += __shfl_xor(e2p, 16);
  e2p += __shfl_xor(e2p, 32);
  if (g == 0 && pv) sim[(size_t)b*HW + p] = 1.f/(1.f + sqrtf(e2p));
}

// ---------- attn2 stage 3: per-image softmax ----------
__global__ __launch_bounds__(256) void k_soft(float* __restrict__ sim) {
  int b = blockIdx.x, t = threadIdx.x;
  __shared__ float red[256];
  float val = (t < HW) ? sim[(size_t)b*HW + t] : -1e30f;
  float m = br_max<256>(val, red, t);
  float e = (t < HW) ? expf(val - m) : 0.f;
  float s = br_sum<256>(e, red, t);
  if (t < HW) sim[(size_t)b*HW + t] = e/s;
}

// ---------- attn2 stage 4: V-proj + residual + fused bn3 stats ----------
__global__ __launch_bounds__(256) void k_attn2b(float* __restrict__ A,
        const float* __restrict__ att, const unsigned short* __restrict__ Wv,
        float* __restrict__ ps, float* __restrict__ pq) {
  int blk = blockIdx.x;
  int b = blk >> 2, tile = blk & 3, p0 = tile*64;
  int t = threadIdx.x;
  __shared__ __align__(16) unsigned short xh[16*64*8];
  __shared__ float pS[4][CC], pQ[4][CC];
  float* Ab = A + (size_t)b*CC*HW;
  {
    int px = t & 63, cig = t >> 6;
    int p = p0 + px;
    bool pv = p < HW;
    #pragma unroll
    for (int k0 = 0; k0 < 32; k0 += 8) {
      U8 th;
      #pragma unroll
      for (int j = 0; j < 8; ++j) {
        int ci = cig*32 + k0 + j;
        th.u[j] = pv ? f2bf(Ab[(size_t)ci*HW + p]) : 0;
      }
      *(short8*)&xh[((cig*4 + (k0>>3))*64 + px)*8] = th.v;
    }
  }
  __syncthreads();
  int w = t >> 6, l = t & 63, g = l >> 4, n = l & 15;
  int p = p0 + w*16 + n;
  bool pv = p < HW;
  float ap = pv ? att[(size_t)b*HW + p] : 0.f;
  const short8* wvp = (const short8*)Wv;
  short8 bf[4];
  #pragma unroll
  for (int cs = 0; cs < 4; ++cs)
    bf[cs] = *(const short8*)&xh[((cs*4 + g)*64 + w*16 + n)*8];
  #pragma unroll
  for (int ct = 0; ct < 8; ++ct) {
    f32x4 v = {};
    #pragma unroll
    for (int cs = 0; cs < 4; ++cs)
      v = __builtin_amdgcn_mfma_f32_16x16x32_bf16(wvp[(cs*8 + ct)*64 + l], bf[cs], v, 0, 0, 0);
    #pragma unroll
    for (int r = 0; r < 4; ++r) {
      int co = ct*16 + g*4 + r;
      float val = 0.f;
      if (pv) {
        val = ap*v[r] + Ab[(size_t)co*HW + p];
        Ab[(size_t)co*HW + p] = val;
      }
      float s = val, q = val*val;
      #pragma unroll
      for (int m = 1; m < 16; m <<= 1) { s += __shfl_xor(s, m); q += __shfl_xor(q, m); }
      if (n == 0) { pS[w][co] = s; pQ[w][co] = q; }
    }
  }
  __syncthreads();
  if (t < CC) {
    ps[(size_t)t*NPMAX + blk] = pS[0][t]+pS[1][t]+pS[2][t]+pS[3][t];
    pq[(size_t)t*NPMAX + blk] = pQ[0][t]+pQ[1][t]+pQ[2][t]+pQ[3][t];
  }
}

// ---------- BN3 + channel-attention gate; writes D (+ bf16 D2) ----------
// gate-phase xin now read from LDS xh (bf16 of BN3(x)) instead of global A
__global__ __launch_bounds__(256) void k_chatt_v3(const float* __restrict__ A, float* __restrict__ D,
        unsigned short* __restrict__ D2,
        const float* __restrict__ sc, const float* __restrict__ sh,
        const unsigned short* __restrict__ Wc1, const float* __restrict__ b1,
        const unsigned short* __restrict__ Wc2, const float* __restrict__ b2) {
  int blk = blockIdx.x;
  int b = blk >> 2, tile = blk & 3, p0 = tile*64;
  int t = threadIdx.x;
  __shared__ __align__(16) unsigned short xh[16*64*8];
  __shared__ __align__(16) unsigned short hb[64*CIPH];
  __shared__ float scl[CC], shl[CC], b2l[CC], b1l[32];
  const float* Ab = A + (size_t)b*CC*HW;
  float* Db = D + (size_t)b*CC*HW;
  if (t < CC) { scl[t] = sc[t]; shl[t] = sh[t]; b2l[t] = b2[t]; }
  if (t < 32) b1l[t] = b1[t];
  __syncthreads();
  {
    int px = t & 63, cig = t >> 6;
    int p = p0 + px;
    bool pv = p < HW;
    #pragma unroll
    for (int k0 = 0; k0 < 32; k0 += 8) {
      U8 th;
      #pragma unroll
      for (int j = 0; j < 8; ++j) {
        int ci = cig*32 + k0 + j;
        th.u[j] = pv ? f2bf(Ab[(size_t)ci*HW + p]*scl[ci] + shl[ci]) : 0;
      }
      *(short8*)&xh[((cig*4 + (k0>>3))*64 + px)*8] = th.v;
    }
  }
  __syncthreads();
  int w = t >> 6, l = t & 63, g = l >> 4, n = l & 15;
  int p = p0 + w*16 + n;
  bool pv = p < HW;
  const short8* w1p = (const short8*)Wc1;
  const short8* w2p = (const short8*)Wc2;
  short8 bf[4];
  #pragma unroll
  for (int cs = 0; cs < 4; ++cs)
    bf[cs] = *(const short8*)&xh[((cs*4 + g)*64 + w*16 + n)*8];
  #pragma unroll
  for (int ct = 0; ct < 2; ++ct) {
    f32x4 a = {};
    #pragma unroll
    for (int cs = 0; cs < 4; ++cs)
      a = __builtin_amdgcn_mfma_f32_16x16x32_bf16(w1p[(cs*2 + ct)*64 + l], bf[cs], a, 0, 0, 0);
    us4 hv;
    #pragma unroll
    for (int r = 0; r < 4; ++r) hv[r] = f2bf(fmaxf(a[r] + b1l[ct*16 + g*4 + r], 0.f));
    *(us4*)&hb[(w*16+n)*CIPH + ct*16 + g*4] = hv;
  }
  __syncthreads();
  short8 hf = *(const short8*)&hb[(w*16+n)*CIPH + g*8];
  #pragma unroll
  for (int ct = 0; ct < 8; ++ct) {
    f32x4 a = __builtin_amdgcn_mfma_f32_16x16x32_bf16(w2p[ct*64 + l], hf, f32x4{}, 0, 0, 0);
    if (pv) {
      us4 dv;
      #pragma unroll
      for (int r = 0; r < 4; ++r) {
        int co = ct*16 + g*4 + r;
        float s = a[r] + b2l[co];
        float gt = 1.f/(1.f + expf(-s));
        float xin = bf2f(xh[((co >> 3)*64 + w*16 + n)*8 + (co & 7)]);
        float o = xin*gt;
        Db[(size_t)co*HW + p] = o;
        dv[r] = f2bf(o);
      }
      if (D2) *(us4*)&D2[((size_t)b*HW + p)*CIP + ct*16 + g*4] = dv;
    }
  }
}

// ---------- 7x7 conv 128->32, row-split, ct/rh-split waves, dy-reuse rs-loop (+ bn4 stats) ----------
template<int USED2>
__global__ __launch_bounds__(256) void k_conv7a_mfma(const float* __restrict__ D,
        const unsigned short* __restrict__ D2,
        const unsigned short* __restrict__ Wa, float* __restrict__ S,
        float* __restrict__ ps, float* __restrict__ pq) {
  int b = blockIdx.x, half = blockIdx.y, t = threadIdx.x;
  __shared__ __align__(16) unsigned short xb[4*NRW*22*8];   // 19,712 B, [oct][row][x][8]
  __shared__ float pS[2][32], pQ[2][32];
  unsigned int* xw = (unsigned int*)xb;
  for (int i = t; i < 4*NRW*22*8/2; i += 256) xw[i] = 0u;
  int w = t >> 6, l = t & 63, g = l >> 4, x = l & 15;
  int ct = w & 1, rh = w >> 1;
  int row0 = half*8;
  f32x4 acc[4] = {};
  const short8* wp = (const short8*)Wa;
  bool prow = false; int rr = 0, xp = 0;
  if (t < HW) {
    int py = t/15, px = t - (t/15)*15;
    int gp = py + 3;
    prow = (gp >= row0) && (gp < row0 + NRW);
    rr = gp - row0; xp = px + 3;
  }
  for (int ck = 0; ck < 4; ++ck) {
    __syncthreads();
    if (prow) {
      if (USED2) {
        const unsigned short* src = &D2[((size_t)b*HW + t)*CIP + ck*32];
        #pragma unroll
        for (int g0 = 0; g0 < 4; ++g0)
          *(short8*)&xb[((g0*NRW + rr)*22 + xp)*8] = *(const short8*)&src[g0*8];
      } else {
        const float* Dbp = D + ((size_t)b*CC + ck*32)*HW;
        #pragma unroll
        for (int g0 = 0; g0 < 4; ++g0) {
          U8 tb;
          #pragma unroll
          for (int k = 0; k < 8; ++k) tb.u[k] = f2bf(Dbp[(g0*8+k)*HW + t]);
          *(short8*)&xb[((g0*NRW + rr)*22 + xp)*8] = tb.v;
        }
      }
    }
    __syncthreads();
    for (int dx = 0; dx < 7; ++dx) {
      short8 aw[7];
      #pragma unroll
      for (int dy = 0; dy < 7; ++dy)
        aw[dy] = wp[(((ck*7 + dx)*7 + dy)*2 + ct)*64 + l];
      #pragma unroll
      for (int rs = 0; rs < 10; ++rs) {
        short8 bf = *(const short8*)&xb[((g*NRW + rh*4 + rs)*22 + x + dx)*8];
        #pragma unroll
        for (int r = 0; r < 4; ++r) {
          int dy = rs - r;
          if (dy >= 0 && dy <= 6)
            acc[r] = __builtin_amdgcn_mfma_f32_16x16x32_bf16(aw[dy], bf, acc[r], 0, 0, 0);
        }
      }
    }
  }
  float ls[4] = {}, lq[4] = {};
  #pragma unroll
  for (int r = 0; r < 4; ++r) {
    int nt = row0 + rh*4 + r;
    bool valid = (x < 15) && (nt < 15);
    if (valid) {
      float* out = S + ((size_t)b*32 + ct*16 + g*4)*HW + nt*15 + x;
      #pragma unroll
      for (int q = 0; q < 4; ++q) out[q*HW] = acc[r][q];
    }
    #pragma unroll
    for (int q = 0; q < 4; ++q) {
      float v = valid ? acc[r][q] : 0.f;
      ls[q] += v; lq[q] += v*v;
    }
  }
  #pragma unroll
  for (int q = 0; q < 4; ++q) {
    float s = ls[q], qq = lq[q];
    #pragma unroll
    for (int m = 1; m < 16; m <<= 1) { s += __shfl_xor(s, m); qq += __shfl_xor(qq, m); }
    if (x == 0) { pS[rh][ct*16 + g*4 + q] = s; pQ[rh][ct*16 + g*4 + q] = qq; }
  }
  __syncthreads();
  if (t < 32) {
    ps[(size_t)t*NPMAX + b*2 + half] = pS[0][t]+pS[1][t];
    pq[(size_t)t*NPMAX + b*2 + half] = pQ[0][t]+pQ[1][t];
  }
}

// ---------- 7x7 conv 32->128, row-split, ct-pair waves, dy-reuse rs-loop (+ bn5 stats) ----------
__global__ __launch_bounds__(256) void k_conv7b_mfma(const float* __restrict__ S,
        const float* __restrict__ sc, const float* __restrict__ sh,
        const unsigned short* __restrict__ Wb, float* __restrict__ O,
        float* __restrict__ ps, float* __restrict__ pq) {
  int b = blockIdx.x, half = blockIdx.y, t = threadIdx.x;
  __shared__ __align__(16) unsigned short xb[4*NRW*22*8];   // 19,712 B
  __shared__ float scl[32], shl[32];
  __shared__ float pS[CC], pQ[CC];
  unsigned int* xw = (unsigned int*)xb;
  for (int i = t; i < 4*NRW*22*8/2; i += 256) xw[i] = 0u;
  if (t < 32) { scl[t] = sc[t]; shl[t] = sh[t]; }
  __syncthreads();
  int row0 = half*8;
  const float* Sb = S + (size_t)b*32*HW;
  if (t < HW) {
    int py = t/15, px = t - (t/15)*15;
    int gp = py + 3;
    if (gp >= row0 && gp < row0 + NRW) {
      int rr = gp - row0, xp = px + 3;
      #pragma unroll
      for (int g0 = 0; g0 < 4; ++g0) {
        U8 tb;
        #pragma unroll
        for (int k = 0; k < 8; ++k)
          tb.u[k] = f2bf(fmaxf(Sb[(g0*8+k)*HW + t]*scl[g0*8+k] + shl[g0*8+k], 0.f));
        *(short8*)&xb[((g0*NRW + rr)*22 + xp)*8] = tb.v;
      }
    }
  }
  __syncthreads();
  int w = t >> 6, l = t & 63, g = l >> 4, x = l & 15;
  int ct0 = w*2;
  f32x4 acc[2][8] = {};
  const short8* wp = (const short8*)Wb;
  for (int dx = 0; dx < 7; ++dx) {
    short8 a0[7], a1[7];
    #pragma unroll
    for (int dy = 0; dy < 7; ++dy) {
      a0[dy] = wp[((dx*7 + dy)*8 + ct0)*64 + l];
      a1[dy] = wp[((dx*7 + dy)*8 + ct0 + 1)*64 + l];
    }
    #pragma unroll
    for (int rs = 0; rs < 14; ++rs) {
      short8 bf = *(const short8*)&xb[((g*NRW + rs)*22 + x + dx)*8];
      #pragma unroll
      for (int r = 0; r < 8; ++r) {
        int dy = rs - r;
        if (dy >= 0 && dy <= 6) {
          acc[0][r] = __builtin_amdgcn_mfma_f32_16x16x32_bf16(a0[dy], bf, acc[0][r], 0, 0, 0);
          acc[1][r] = __builtin_amdgcn_mfma_f32_16x16x32_bf16(a1[dy], bf, acc[1][r], 0, 0, 0);
        }
      }
    }
  }
  float ls[2][4] = {}, lq[2][4] = {};
  #pragma unroll
  for (int ctl = 0; ctl < 2; ++ctl)
    #pragma unroll
    for (int r = 0; r < 8; ++r) {
      int nt = row0 + r;
      bool valid = (x < 15) && (nt < 15);
      if (valid) {
        float* out = O + ((size_t)b*CC + (ct0+ctl)*16 + g*4)*HW + nt*15 + x;
        #pragma unroll
        for (int q = 0; q < 4; ++q) out[q*HW] = acc[ctl][r][q];
      }
      #pragma unroll
      for (int q = 0; q < 4; ++q) {
        float v = valid ? acc[ctl][r][q] : 0.f;
        ls[ctl][q] += v; lq[ctl][q] += v*v;
      }
    }
  #pragma unroll
  for (int ctl = 0; ctl < 2; ++ctl)
    #pragma unroll
    for (int q = 0; q < 4; ++q) {
      float s = ls[ctl][q], qq = lq[ctl][q];
      #pragma unroll
      for (int m = 1; m < 16; m <<= 1) { s += __shfl_xor(s, m); qq += __shfl_xor(qq, m); }
      if (x == 0) { pS[(ct0+ctl)*16 + g*4 + q] = s; pQ[(ct0+ctl)*16 + g*4 + q] = qq; }
    }
  __syncthreads();
  if (t < CC) {
    ps[(size_t)t*NPMAX + b*2 + half] = pS[t];
    pq[(size_t)t*NPMAX + b*2 + half] = pQ[t];
  }
}

// ---------- final: D *= sigmoid(bn5(A)), float4 ----------
__global__ __launch_bounds__(256) void k_final4(f32x4* __restrict__ D, const f32x4* __restrict__ A,
                        const float* __restrict__ sc, const float* __restrict__ sh) {
  size_t i = (size_t)blockIdx.x*256 + threadIdx.x;
  f32x4 a = A[i], d = D[i];
  size_t e = i*4;
  #pragma unroll
  for (int k = 0; k < 4; ++k) {
    int c = (int)(((e + k) / HW) % CC);
    float s = a[k]*sc[c] + sh[c];
    d[k] *= 1.f/(1.f + expf(-s));
  }
  D[i] = d;
}

extern "C" void kernel_launch(void* const* d_in, const int* in_sizes, int n_in,
                              void* d_out, int out_size, void* d_ws, size_t ws_size,
                              hipStream_t stream) {
  (void)in_sizes; (void)n_in; (void)out_size;
  const float* x1    = (const float*)d_in[0];
  const float* x2    = (const float*)d_in[1];
  const float* lam   = (const float*)d_in[2];
  const float* bn1_g = (const float*)d_in[3];
  const float* bn1_b = (const float*)d_in[4];
  const float* pW1   = (const float*)d_in[5];
  const float* dW1   = (const float*)d_in[6];
  const float* db1   = (const float*)d_in[7];
  const float* bn2_g = (const float*)d_in[8];
  const float* bn2_b = (const float*)d_in[9];
  const float* pW2   = (const float*)d_in[10];
  const float* dW2   = (const float*)d_in[11];
  const float* db2   = (const float*)d_in[12];
  const float* qkvW  = (const float*)d_in[13];
  const float* bn3_g = (const float*)d_in[14];
  const float* bn3_b = (const float*)d_in[15];
  const float* ca_w1 = (const float*)d_in[16];
  const float* ca_b1 = (const float*)d_in[17];
  const float* ca_w2 = (const float*)d_in[18];
  const float* ca_b2 = (const float*)d_in[19];
  const float* sa_w1 = (const float*)d_in[20];
  const float* sbn1_g= (const float*)d_in[22];
  const float* sbn1_b= (const float*)d_in[23];
  const float* sa_w2 = (const float*)d_in[24];
  const float* sbn2_g= (const float*)d_in[26];
  const float* sbn2_b= (const float*)d_in[27];

  float* D = (float*)d_out;
  float* A = (float*)d_ws;                          // (512,128,225) f32
  float* S = A + (size_t)BB*CC*HW;                  // (512,32,225)  f32
  float* part = S + (size_t)BB*32*HW;               // 512*4*3*256 f32
  float* st = part + (size_t)BB*4*3*256;            // 1280 f32 stats
  float *sc1 = st,      *sh1 = st+128,  *sc2 = st+256, *sh2 = st+384,
        *sc3 = st+512,  *sh3 = st+640,  *sc4 = st+768, *sh4 = st+800,
        *sc5 = st+832,  *sh5 = st+960;
  float* ps = st + 1280;                            // 128*NPMAX
  float* pq = ps + (size_t)CC*NPMAX;                // 128*NPMAX
  float* cent = pq + (size_t)CC*NPMAX;              // 512*128
  float* sim  = cent + (size_t)BB*CC;               // 512*225
  float* am   = sim + (size_t)BB*HW;                // 512*225
  unsigned short* Wa  = (unsigned short*)(am + (size_t)BB*HW);
  unsigned short* Wb  = Wa + 49*4096;
  unsigned short* W1h = Wb + 49*4096;
  unsigned short* W1l = W1h + 16384;
  unsigned short* W2h = W1l + 16384;
  unsigned short* W2l = W2h + 16384;
  unsigned short* Wk  = W2l + 16384;
  unsigned short* Wv  = Wk  + 16384;
  unsigned short* Wc1 = Wv  + 16384;
  unsigned short* Wc2 = Wc1 + 4096;
  unsigned short* D2  = Wc2 + 4096;                 // (512,225,136) bf16, optional
  size_t need = (size_t)((char*)(D2 + (size_t)BB*HW*CIP) - (char*)d_ws);
  bool useD2 = ws_size >= need;

  const int NB4 = BB*4;

  k_prep_all<<<1792, 256, 0, stream>>>(sa_w1, sa_w2, pW1, pW2, qkvW, ca_w1, ca_w2,
                                       Wa, Wb, W1h, W1l, W2h, W2l, Wk, Wv, Wc1, Wc2);

  k_at1a <<<dim3(BB,4), 256, 0, stream>>>(x1, x2, part);
  k_at1b <<<BB, 256, 0, stream>>>(x1, x2, part, lam, am);
  k_at1c <<<dim3(BB,4), 256, 0, stream>>>(x1, x2, am, A, ps, pq);
  k_bnfin2<<<CC, 256, 0, stream>>>(ps, pq, BB, bn1_g, bn1_b, sc1, sh1);
  k_pw_v3<1><<<NB4, 256, 0, stream>>>(A, W1h, W1l, sc1, sh1, dW1, db1, ps, pq);
  k_bnfin2<<<CC, 256, 0, stream>>>(ps, pq, NB4, bn2_g, bn2_b, sc2, sh2);
  k_pw_v3<2><<<NB4, 256, 0, stream>>>(A, W2h, W2l, sc2, sh2, nullptr, nullptr, nullptr, nullptr);
  k_dw3   <<<dim3(BB,8), 256, 0, stream>>>(A, dW2, db2);
  k_cent  <<<BB, 128, 0, stream>>>(A, qkvW, cent);
  k_attn2a<<<NB4, 256, 0, stream>>>(A, cent, Wk, sim);
  k_soft  <<<BB, 256, 0, stream>>>(sim);
  k_attn2b<<<NB4, 256, 0, stream>>>(A, sim, Wv, ps, pq);
  k_bnfin2<<<CC, 256, 0, stream>>>(ps, pq, NB4, bn3_g, bn3_b, sc3, sh3);
  k_chatt_v3<<<NB4, 256, 0, stream>>>(A, D, useD2 ? D2 : nullptr, sc3, sh3, Wc1, ca_b1, Wc2, ca_b2);
  if (useD2) k_conv7a_mfma<1><<<dim3(BB,2), 256, 0, stream>>>(D, D2, Wa, S, ps, pq);
  else       k_conv7a_mfma<0><<<dim3(BB,2), 256, 0, stream>>>(D, nullptr, Wa, S, ps, pq);
  k_bnfin2<<<32, 256, 0, stream>>>(ps, pq, BB*2, sbn1_g, sbn1_b, sc4, sh4);
  k_conv7b_mfma<<<dim3(BB,2), 256, 0, stream>>>(S, sc4, sh4, Wb, A, ps, pq);
  k_bnfin2<<<CC, 256, 0, stream>>>(ps, pq, BB*2, sbn2_g, sbn2_b, sc5, sh5);
  k_final4<<<(BB*CC*HW)/1024, 256, 0, stream>>>((f32x4*)D, (const f32x4*)A, sc5, sh5);
}

// Round 15
// 496.344 us; speedup vs baseline: 1.5423x; 1.0105x over previous
//
#include <hip/hip_runtime.h>
#include <hip/hip_bf16.h>
#include <cmath>

#define BB 512
#define CC 128
#define HW 225
#define CIP 136     // ushort stride of D2 [px][ci] rows (272 B)
#define CIPH 40     // ushort stride for 32-ch hidden rows
#define NPMAX 2048  // max partial-stat blocks
#define NRW 14      // padded-row window for row-split convs

typedef __attribute__((ext_vector_type(8))) short short8;
typedef __attribute__((ext_vector_type(4))) float f32x4;
typedef __attribute__((ext_vector_type(4))) unsigned short us4;

union U8 { unsigned short u[8]; short8 v; };

__device__ __forceinline__ unsigned short f2bf(float v) {
  __hip_bfloat16 h = __float2bfloat16(v);
  return *(unsigned short*)&h;
}
__device__ __forceinline__ float bf2f(unsigned short u) {
  __hip_bfloat16 h = *(__hip_bfloat16*)&u;
  return __bfloat162float(h);
}

template<int NT>
__device__ __forceinline__ float br_max(float v, float* red, int t) {
  red[t] = v; __syncthreads();
  for (int st = NT/2; st > 0; st >>= 1) { if (t < st) red[t] = fmaxf(red[t], red[t+st]); __syncthreads(); }
  float r = red[0]; __syncthreads();
  return r;
}
template<int NT>
__device__ __forceinline__ float br_sum(float v, float* red, int t) {
  red[t] = v; __syncthreads();
  for (int st = NT/2; st > 0; st >>= 1) { if (t < st) red[t] += red[t+st]; __syncthreads(); }
  float r = red[0]; __syncthreads();
  return r;
}

// finalize fused per-block partials ps/pq[c][NPMAX], np valid slots
__global__ __launch_bounds__(256) void k_bnfin2(const float* __restrict__ ps, const float* __restrict__ pq,
                         int np,
                         const float* __restrict__ g, const float* __restrict__ bt,
                         float* __restrict__ scale, float* __restrict__ shift) {
  int c = blockIdx.x, t = threadIdx.x;
  __shared__ float rs[256], rq[256];
  float s = 0.f, q = 0.f;
  for (int i = t; i < np; i += 256) { s += ps[(size_t)c*NPMAX + i]; q += pq[(size_t)c*NPMAX + i]; }
  rs[t] = s; rq[t] = q; __syncthreads();
  for (int st = 128; st > 0; st >>= 1) { if (t < st) { rs[t]+=rs[t+st]; rq[t]+=rq[t+st]; } __syncthreads(); }
  if (t == 0) {
    const float N = (float)BB*HW;
    float mean = rs[0]/N, var = rq[0]/N - mean*mean;
    float sc = g[c]*rsqrtf(var + 1e-5f);
    scale[c] = sc; shift[c] = bt[c] - mean*sc;
  }
}

// ---------- attn1 stage A ----------
__global__ __launch_bounds__(256) void k_at1a(const float* __restrict__ x1, const float* __restrict__ x2,
                       float* __restrict__ part) {
  int b = blockIdx.x, cg = blockIdx.y, t = threadIdx.x;
  __shared__ float cent[32];
  const float* xb1 = x1 + (size_t)b*64*HW;
  const float* xb2 = x2 + (size_t)b*64*HW;
  if (t < 32) { int c = cg*32 + t; cent[t] = (c < 64) ? xb1[c*HW + 112] : xb2[(c-64)*HW + 112]; }
  __syncthreads();
  if (t < HW) {
    float e2 = 0.f, dot = 0.f, qn2 = 0.f;
    for (int k = 0; k < 32; ++k) {
      int c = cg*32 + k;
      float xv = (c < 64) ? xb1[c*HW + t] : xb2[(c-64)*HW + t];
      float ce = cent[k];
      float d = xv - ce;
      e2 += d*d; dot += xv*ce; qn2 += xv*xv;
    }
    size_t base = ((size_t)(b*4 + cg)*3)*256;
    part[base + t] = e2; part[base + 256 + t] = dot; part[base + 512 + t] = qn2;
  }
}

// ---------- attn1 stage B ----------
__global__ __launch_bounds__(256) void k_at1b(const float* __restrict__ x1, const float* __restrict__ x2,
                       const float* __restrict__ part, const float* __restrict__ lam,
                       float* __restrict__ am) {
  int b = blockIdx.x, t = threadIdx.x;
  __shared__ float red[256];
  float cv = 0.f;
  if (t < CC) {
    float ce = (t < 64) ? x1[(size_t)b*64*HW + t*HW + 112] : x2[(size_t)b*64*HW + (t-64)*HW + 112];
    cv = ce*ce;
  }
  float cn2 = br_sum<256>(cv, red, t);
  float e2 = 0.f, dot = 0.f, qn2 = 0.f;
  if (t < HW) {
    #pragma unroll
    for (int cg = 0; cg < 4; ++cg) {
      size_t base = ((size_t)(b*4 + cg)*3)*256;
      e2 += part[base + t]; dot += part[base + 256 + t]; qn2 += part[base + 512 + t];
    }
  }
  float sim_e = 0.f, sim_c = 0.f;
  if (t < HW) {
    sim_e = 1.f/(1.f + sqrtf(e2));
    float qn = sqrtf(qn2), cn = sqrtf(cn2);
    sim_c = dot / (fmaxf(cn, 1e-8f) * fmaxf(qn, 1e-8f));
  }
  float m1 = br_max<256>((t<HW)? sim_e : -1e30f, red, t);
  float e1v = (t<HW)? expf(sim_e - m1) : 0.f;
  float s1 = br_sum<256>(e1v, red, t);
  float m2 = br_max<256>((t<HW)? sim_c : -1e30f, red, t);
  float e2v = (t<HW)? expf(sim_c - m2) : 0.f;
  float s2 = br_sum<256>(e2v, red, t);
  float lmd = 1.f/(1.f + expf(-lam[0]));
  if (t < HW) am[(size_t)b*HW + t] = 1.f + lmd*e1v/s1 + (1.f - lmd)*e2v/s2;
}

// ---------- attn1 stage C ----------
__global__ __launch_bounds__(256) void k_at1c(const float* __restrict__ x1, const float* __restrict__ x2,
                       const float* __restrict__ am, float* __restrict__ A,
                       float* __restrict__ ps, float* __restrict__ pq) {
  int b = blockIdx.x, cg = blockIdx.y, t = threadIdx.x;
  __shared__ float pS[4][32], pQ[4][32];
  const float* xb1 = x1 + (size_t)b*64*HW;
  const float* xb2 = x2 + (size_t)b*64*HW;
  float* Ab = A + (size_t)b*CC*HW;
  float amv = (t < HW) ? am[(size_t)b*HW + t] : 0.f;
  int w = t >> 6, lane = t & 63;
  for (int k = 0; k < 32; ++k) {
    int c = cg*32 + k;
    float xv = 0.f;
    if (t < HW) xv = (c < 64) ? xb1[c*HW + t] : xb2[(c-64)*HW + t];
    float val = xv*amv;
    if (t < HW) Ab[(size_t)c*HW + t] = val;
    float s = val, q = val*val;
    #pragma unroll
    for (int m = 1; m < 64; m <<= 1) { s += __shfl_xor(s, m); q += __shfl_xor(q, m); }
    if (lane == 0) { pS[w][k] = s; pQ[w][k] = q; }
  }
  __syncthreads();
  if (t < 32) {
    int c = cg*32 + t;
    ps[(size_t)c*NPMAX + b] = pS[0][t]+pS[1][t]+pS[2][t]+pS[3][t];
    pq[(size_t)c*NPMAX + b] = pQ[0][t]+pQ[1][t]+pQ[2][t]+pQ[3][t];
  }
}

// ---------- merged weight pre-pack ----------
// Wa: [ck(4)][dx(7)][dy(7)][ct(2)][lane64][j8]
// Wb: [dx(7)][dy(7)][ct(8)][lane64][j8]
__global__ __launch_bounds__(256) void k_prep_all(
    const float* __restrict__ sa_w1, const float* __restrict__ sa_w2,
    const float* __restrict__ pW1, const float* __restrict__ pW2,
    const float* __restrict__ qkvW, const float* __restrict__ ca_w1, const float* __restrict__ ca_w2,
    unsigned short* __restrict__ Wa, unsigned short* __restrict__ Wb,
    unsigned short* __restrict__ W1h, unsigned short* __restrict__ W1l,
    unsigned short* __restrict__ W2h, unsigned short* __restrict__ W2l,
    unsigned short* __restrict__ Wk, unsigned short* __restrict__ Wv,
    unsigned short* __restrict__ Wc1, unsigned short* __restrict__ Wc2) {
  int id = blockIdx.x*256 + threadIdx.x;
  const int NA = 49*4096;
  if (id < NA) {
    int j = id & 7, l = (id >> 3) & 63, ct = (id >> 9) & 1;
    int r = id >> 10;
    int dy = r % 7; r /= 7;
    int dx = r % 7; int ck = r / 7;
    int co = ct*16 + (l & 15);
    int ci = ck*32 + ((l >> 4) << 3) + j;
    Wa[id] = f2bf(sa_w1[(co*128 + ci)*49 + dy*7 + dx]);
    return;
  }
  id -= NA;
  if (id < NA) {
    int j = id & 7, l = (id >> 3) & 63, ct = (id >> 9) & 7;
    int r = id >> 12;
    int dy = r % 7, dx = r / 7;
    int co = ct*16 + (l & 15);
    int ci = ((l >> 4) << 3) + j;
    Wb[id] = f2bf(sa_w2[(co*32 + ci)*49 + dy*7 + dx]);
    return;
  }
  id -= NA;
  if (id < 16384) {
    int j = id & 7, l = (id >> 3) & 63, ct = (id >> 9) & 7, cs = id >> 12;
    int co = ct*16 + (l & 15);
    int ci = cs*32 + ((l >> 4) << 3) + j;
    float v = pW1[co*128 + ci];
    __hip_bfloat16 h = __float2bfloat16(v);
    W1h[id] = *(unsigned short*)&h;
    W1l[id] = f2bf(v - __bfloat162float(h));
    return;
  }
  id -= 16384;
  if (id < 16384) {
    int j = id & 7, l = (id >> 3) & 63, ct = (id >> 9) & 7, cs = id >> 12;
    int co = ct*16 + (l & 15);
    int ci = cs*32 + ((l >> 4) << 3) + j;
    float v = pW2[co*128 + ci];
    __hip_bfloat16 h = __float2bfloat16(v);
    W2h[id] = *(unsigned short*)&h;
    W2l[id] = f2bf(v - __bfloat162float(h));
    return;
  }
  id -= 16384;
  if (id < 16384) {
    int j = id & 7, l = (id >> 3) & 63, ct = (id >> 9) & 7, cs = id >> 12;
    int co = ct*16 + (l & 15);
    int ci = cs*32 + ((l >> 4) << 3) + j;
    Wk[id] = f2bf(qkvW[(size_t)(128 + co)*128 + ci]);
    Wv[id] = f2bf(qkvW[(size_t)(256 + co)*128 + ci]);
    return;
  }
  id -= 16384;
  if (id < 4096) {
    int j = id & 7, l = (id >> 3) & 63, ct = (id >> 9) & 1, cs = (id >> 10) & 3;
    int co = ct*16 + (l & 15);
    int ci = cs*32 + ((l >> 4) << 3) + j;
    Wc1[id] = f2bf(ca_w1[co*128 + ci]);
    return;
  }
  id -= 4096;
  {
    int j = id & 7, l = (id >> 3) & 63, ct = (id >> 9) & 7;
    int co = ct*16 + (l & 15);
    int ci = ((l >> 4) << 3) + j;
    Wc2[id] = f2bf(ca_w2[co*32 + ci]);
  }
}

// ---------- fused BN + 1x1 conv, pixel-tile GEMM, ct-split waves, in-place ----------
template<int MODE>
__global__ __launch_bounds__(256) void k_pw_v3(float* __restrict__ A,
        const unsigned short* __restrict__ Whi, const unsigned short* __restrict__ Wlo,
        const float* __restrict__ scale, const float* __restrict__ shift,
        const float* __restrict__ dw, const float* __restrict__ db,
        float* __restrict__ ps, float* __restrict__ pq) {
  int blk = blockIdx.x;
  int b = blk >> 2, tile = blk & 3, p0 = tile*64;
  int t = threadIdx.x;
  __shared__ __align__(16) unsigned short xh[16*64*8];
  __shared__ __align__(16) unsigned short xl[16*64*8];
  __shared__ float scl[CC], shf[CC], dwl[CC], dbl[CC];
  __shared__ float pS[CC], pQ[CC];
  if (t < CC) {
    scl[t] = scale[t]; shf[t] = shift[t];
    if (MODE == 1) { dwl[t] = dw[t]; dbl[t] = db[t]; }
  }
  __syncthreads();
  float* Ab = A + (size_t)b*CC*HW;
  {
    int px = t & 63, cig = t >> 6;
    int p = p0 + px;
    bool pv = p < HW;
    #pragma unroll
    for (int k0 = 0; k0 < 32; k0 += 8) {
      U8 th, tl;
      #pragma unroll
      for (int j = 0; j < 8; ++j) {
        int ci = cig*32 + k0 + j;
        float v = pv ? Ab[(size_t)ci*HW + p]*scl[ci] + shf[ci] : 0.f;
        __hip_bfloat16 h = __float2bfloat16(v);
        th.u[j] = *(unsigned short*)&h;
        tl.u[j] = f2bf(v - __bfloat162float(h));
      }
      int oo = cig*4 + (k0 >> 3);
      *(short8*)&xh[(oo*64 + px)*8] = th.v;
      *(short8*)&xl[(oo*64 + px)*8] = tl.v;
    }
  }
  __syncthreads();
  int w = t >> 6, l = t & 63, g = l >> 4, n = l & 15;
  const short8* whp = (const short8*)Whi;
  const short8* wlp = (const short8*)Wlo;
  short8 ah[4][2], al[4][2];
  #pragma unroll
  for (int cs = 0; cs < 4; ++cs)
    #pragma unroll
    for (int ctl = 0; ctl < 2; ++ctl) {
      ah[cs][ctl] = whp[(cs*8 + w*2 + ctl)*64 + l];
      al[cs][ctl] = wlp[(cs*8 + w*2 + ctl)*64 + l];
    }
  float ls[2][4] = {}, lq[2][4] = {};
  for (int pt = 0; pt < 4; ++pt) {
    int p = p0 + pt*16 + n;
    bool pv = p < HW;
    short8 bh[4], bl[4];
    #pragma unroll
    for (int cs = 0; cs < 4; ++cs) {
      bh[cs] = *(const short8*)&xh[((cs*4 + g)*64 + pt*16 + n)*8];
      bl[cs] = *(const short8*)&xl[((cs*4 + g)*64 + pt*16 + n)*8];
    }
    f32x4 acc[2] = {};
    #pragma unroll
    for (int cs = 0; cs < 4; ++cs)
      #pragma unroll
      for (int ctl = 0; ctl < 2; ++ctl) {
        acc[ctl] = __builtin_amdgcn_mfma_f32_16x16x32_bf16(ah[cs][ctl], bh[cs], acc[ctl], 0, 0, 0);
        acc[ctl] = __builtin_amdgcn_mfma_f32_16x16x32_bf16(ah[cs][ctl], bl[cs], acc[ctl], 0, 0, 0);
        acc[ctl] = __builtin_amdgcn_mfma_f32_16x16x32_bf16(al[cs][ctl], bh[cs], acc[ctl], 0, 0, 0);
      }
    #pragma unroll
    for (int ctl = 0; ctl < 2; ++ctl)
      #pragma unroll
      for (int r = 0; r < 4; ++r) {
        int co = (w*2 + ctl)*16 + g*4 + r;
        float y = acc[ctl][r];
        y = (y >= 0.f) ? y : 0.01f*y;
        if (MODE == 1) { y = y*dwl[co] + dbl[co]; y = fmaxf(y, 0.f); }
        if (pv) Ab[(size_t)co*HW + p] = y;
        if (MODE == 1) {
          float vs = pv ? y : 0.f;
          ls[ctl][r] += vs; lq[ctl][r] += vs*vs;
        }
      }
  }
  if (MODE == 1) {
    #pragma unroll
    for (int ctl = 0; ctl < 2; ++ctl)
      #pragma unroll
      for (int r = 0; r < 4; ++r) {
        float s = ls[ctl][r], q = lq[ctl][r];
        #pragma unroll
        for (int m = 1; m < 16; m <<= 1) { s += __shfl_xor(s, m); q += __shfl_xor(q, m); }
        if (n == 0) { pS[(w*2 + ctl)*16 + g*4 + r] = s; pQ[(w*2 + ctl)*16 + g*4 + r] = q; }
      }
    __syncthreads();
    if (t < CC) {
      ps[(size_t)t*NPMAX + blk] = pS[t];
      pq[(size_t)t*NPMAX + blk] = pQ[t];
    }
  }
}

// ---------- depthwise 3x3 pad1 + bias + relu, grid (B, 8 ch-groups); emits bf16 X2 ----------
__global__ __launch_bounds__(256) void k_dw3(float* __restrict__ A, const float* __restrict__ w,
                      const float* __restrict__ db, unsigned short* __restrict__ X2) {
  int b = blockIdx.x, cg = blockIdx.y, t = threadIdx.x;
  __shared__ float xin[16][HW];
  float* Ab = A + ((size_t)b*CC + cg*16)*HW;
  for (int i = t; i < 16*HW; i += 256) xin[i/HW][i%HW] = Ab[i];
  __syncthreads();
  if (t < HW) {
    int y = t/15, x = t - y*15;
    U8 o0, o1;
    for (int c = 0; c < 16; ++c) {
      int ch = cg*16 + c;
      float acc = db[ch];
      #pragma unroll
      for (int ky = 0; ky < 3; ++ky) {
        int iy = y + ky - 1;
        if (iy < 0 || iy >= 15) continue;
        #pragma unroll
        for (int kx = 0; kx < 3; ++kx) {
          int ix = x + kx - 1;
          if (ix < 0 || ix >= 15) continue;
          acc += w[ch*9 + ky*3 + kx]*xin[c][iy*15 + ix];
        }
      }
      float val = fmaxf(acc, 0.f);
      Ab[c*HW + t] = val;
      if (c < 8) o0.u[c] = f2bf(val); else o1.u[c-8] = f2bf(val);
    }
    if (X2) {
      *(short8*)&X2[(((size_t)b*16 + cg*2 + 0)*HW + t)*8] = o0.v;
      *(short8*)&X2[(((size_t)b*16 + cg*2 + 1)*HW + t)*8] = o1.v;
    }
  }
}

// ---------- attn2 stage 1: center Q projection ----------
__global__ __launch_bounds__(128) void k_cent(const float* __restrict__ A,
        const float* __restrict__ Wq, float* __restrict__ cent) {
  int b = blockIdx.x, t = threadIdx.x;
  __shared__ float xc[CC];
  const float* Ab = A + (size_t)b*CC*HW;
  xc[t] = bf2f(f2bf(Ab[(size_t)t*HW + 112]));
  __syncthreads();
  const float* wq = Wq + (size_t)t*CC;
  float acc = 0.f;
  for (int ci = 0; ci < CC; ++ci) acc += wq[ci]*xc[ci];
  cent[(size_t)b*CC + t] = acc;
}

// ---------- attn2 stage 2: K-proj + e2 logits ----------
template<int USEX2>
__global__ __launch_bounds__(256) void k_attn2a(const float* __restrict__ A,
        const unsigned short* __restrict__ X2,
        const float* __restrict__ cent, const unsigned short* __restrict__ Wk,
        float* __restrict__ sim) {
  int blk = blockIdx.x;
  int b = blk >> 2, tile = blk & 3, p0 = tile*64;
  int t = threadIdx.x;
  __shared__ __align__(16) unsigned short xh[16*64*8];
  __shared__ float cl[CC];
  const float* Ab = A + (size_t)b*CC*HW;
  if (t < CC) cl[t] = cent[(size_t)b*CC + t];
  {
    int px = t & 63, cig = t >> 6;
    int p = p0 + px;
    bool pv = p < HW;
    #pragma unroll
    for (int k0 = 0; k0 < 32; k0 += 8) {
      int oo = cig*4 + (k0>>3);
      short8 v;
      if (USEX2) {
        v = pv ? *(const short8*)&X2[(((size_t)b*16 + oo)*HW + p)*8] : short8{};
      } else {
        U8 th;
        #pragma unroll
        for (int j = 0; j < 8; ++j) {
          int ci = cig*32 + k0 + j;
          th.u[j] = pv ? f2bf(Ab[(size_t)ci*HW + p]) : 0;
        }
        v = th.v;
      }
      *(short8*)&xh[(oo*64 + px)*8] = v;
    }
  }
  __syncthreads();
  int w = t >> 6, l = t & 63, g = l >> 4, n = l & 15;
  int p = p0 + w*16 + n;
  bool pv = p < HW;
  const short8* wkp = (const short8*)Wk;
  short8 bf[4];
  #pragma unroll
  for (int cs = 0; cs < 4; ++cs)
    bf[cs] = *(const short8*)&xh[((cs*4 + g)*64 + w*16 + n)*8];
  float e2p = 0.f;
  #pragma unroll
  for (int ct = 0; ct < 8; ++ct) {
    f32x4 k = {};
    #pragma unroll
    for (int cs = 0; cs < 4; ++cs)
      k = __builtin_amdgcn_mfma_f32_16x16x32_bf16(wkp[(cs*8 + ct)*64 + l], bf[cs], k, 0, 0, 0);
    #pragma unroll
    for (int r = 0; r < 4; ++r) { float d = cl[ct*16 + g*4 + r] - k[r]; e2p += d*d; }
  }
  e2p += __shfl_xor(e2p, 16);
  e2p += __shfl_xor(e2p, 32);
  if (g == 0 && pv) sim[(size_t)b*HW + p] = 1.f/(1.f + sqrtf(e2p));
}

// ---------- attn2 stage 3: per-image softmax ----------
__global__ __launch_bounds__(256) void k_soft(float* __restrict__ sim) {
  int b = blockIdx.x, t = threadIdx.x;
  __shared__ float red[256];
  float val = (t < HW) ? sim[(size_t)b*HW + t] : -1e30f;
  float m = br_max<256>(val, red, t);
  float e = (t < HW) ? expf(val - m) : 0.f;
  float s = br_sum<256>(e, red, t);
  if (t < HW) sim[(size_t)b*HW + t] = e/s;
}

// ---------- attn2 stage 4: V-proj + residual + fused bn3 stats ----------
template<int USEX2>
__global__ __launch_bounds__(256) void k_attn2b(float* __restrict__ A,
        const unsigned short* __restrict__ X2,
        const float* __restrict__ att, const unsigned short* __restrict__ Wv,
        float* __restrict__ ps, float* __restrict__ pq) {
  int blk = blockIdx.x;
  int b = blk >> 2, tile = blk & 3, p0 = tile*64;
  int t = threadIdx.x;
  __shared__ __align__(16) unsigned short xh[16*64*8];
  __shared__ float pS[4][CC], pQ[4][CC];
  float* Ab = A + (size_t)b*CC*HW;
  {
    int px = t & 63, cig = t >> 6;
    int p = p0 + px;
    bool pv = p < HW;
    #pragma unroll
    for (int k0 = 0; k0 < 32; k0 += 8) {
      int oo = cig*4 + (k0>>3);
      short8 v;
      if (USEX2) {
        v = pv ? *(const short8*)&X2[(((size_t)b*16 + oo)*HW + p)*8] : short8{};
      } else {
        U8 th;
        #pragma unroll
        for (int j = 0; j < 8; ++j) {
          int ci = cig*32 + k0 + j;
          th.u[j] = pv ? f2bf(Ab[(size_t)ci*HW + p]) : 0;
        }
        v = th.v;
      }
      *(short8*)&xh[(oo*64 + px)*8] = v;
    }
  }
  __syncthreads();
  int w = t >> 6, l = t & 63, g = l >> 4, n = l & 15;
  int p = p0 + w*16 + n;
  bool pv = p < HW;
  float ap = pv ? att[(size_t)b*HW + p] : 0.f;
  const short8* wvp = (const short8*)Wv;
  short8 bf[4];
  #pragma unroll
  for (int cs = 0; cs < 4; ++cs)
    bf[cs] = *(const short8*)&xh[((cs*4 + g)*64 + w*16 + n)*8];
  #pragma unroll
  for (int ct = 0; ct < 8; ++ct) {
    f32x4 v = {};
    #pragma unroll
    for (int cs = 0; cs < 4; ++cs)
      v = __builtin_amdgcn_mfma_f32_16x16x32_bf16(wvp[(cs*8 + ct)*64 + l], bf[cs], v, 0, 0, 0);
    #pragma unroll
    for (int r = 0; r < 4; ++r) {
      int co = ct*16 + g*4 + r;
      float val = 0.f;
      if (pv) {
        val = ap*v[r] + Ab[(size_t)co*HW + p];
        Ab[(size_t)co*HW + p] = val;
      }
      float s = val, q = val*val;
      #pragma unroll
      for (int m = 1; m < 16; m <<= 1) { s += __shfl_xor(s, m); q += __shfl_xor(q, m); }
      if (n == 0) { pS[w][co] = s; pQ[w][co] = q; }
    }
  }
  __syncthreads();
  if (t < CC) {
    ps[(size_t)t*NPMAX + blk] = pS[0][t]+pS[1][t]+pS[2][t]+pS[3][t];
    pq[(size_t)t*NPMAX + blk] = pQ[0][t]+pQ[1][t]+pQ[2][t]+pQ[3][t];
  }
}

// ---------- BN3 + channel-attention gate; writes D (+ bf16 D2) ----------
__global__ __launch_bounds__(256) void k_chatt_v3(const float* __restrict__ A, float* __restrict__ D,
        unsigned short* __restrict__ D2,
        const float* __restrict__ sc, const float* __restrict__ sh,
        const unsigned short* __restrict__ Wc1, const float* __restrict__ b1,
        const unsigned short* __restrict__ Wc2, const float* __restrict__ b2) {
  int blk = blockIdx.x;
  int b = blk >> 2, tile = blk & 3, p0 = tile*64;
  int t = threadIdx.x;
  __shared__ __align__(16) unsigned short xh[16*64*8];
  __shared__ __align__(16) unsigned short hb[64*CIPH];
  __shared__ float scl[CC], shl[CC], b2l[CC], b1l[32];
  const float* Ab = A + (size_t)b*CC*HW;
  float* Db = D + (size_t)b*CC*HW;
  if (t < CC) { scl[t] = sc[t]; shl[t] = sh[t]; b2l[t] = b2[t]; }
  if (t < 32) b1l[t] = b1[t];
  __syncthreads();
  {
    int px = t & 63, cig = t >> 6;
    int p = p0 + px;
    bool pv = p < HW;
    #pragma unroll
    for (int k0 = 0; k0 < 32; k0 += 8) {
      U8 th;
      #pragma unroll
      for (int j = 0; j < 8; ++j) {
        int ci = cig*32 + k0 + j;
        th.u[j] = pv ? f2bf(Ab[(size_t)ci*HW + p]*scl[ci] + shl[ci]) : 0;
      }
      *(short8*)&xh[((cig*4 + (k0>>3))*64 + px)*8] = th.v;
    }
  }
  __syncthreads();
  int w = t >> 6, l = t & 63, g = l >> 4, n = l & 15;
  int p = p0 + w*16 + n;
  bool pv = p < HW;
  const short8* w1p = (const short8*)Wc1;
  const short8* w2p = (const short8*)Wc2;
  short8 bf[4];
  #pragma unroll
  for (int cs = 0; cs < 4; ++cs)
    bf[cs] = *(const short8*)&xh[((cs*4 + g)*64 + w*16 + n)*8];
  #pragma unroll
  for (int ct = 0; ct < 2; ++ct) {
    f32x4 a = {};
    #pragma unroll
    for (int cs = 0; cs < 4; ++cs)
      a = __builtin_amdgcn_mfma_f32_16x16x32_bf16(w1p[(cs*2 + ct)*64 + l], bf[cs], a, 0, 0, 0);
    us4 hv;
    #pragma unroll
    for (int r = 0; r < 4; ++r) hv[r] = f2bf(fmaxf(a[r] + b1l[ct*16 + g*4 + r], 0.f));
    *(us4*)&hb[(w*16+n)*CIPH + ct*16 + g*4] = hv;
  }
  __syncthreads();
  short8 hf = *(const short8*)&hb[(w*16+n)*CIPH + g*8];
  #pragma unroll
  for (int ct = 0; ct < 8; ++ct) {
    f32x4 a = __builtin_amdgcn_mfma_f32_16x16x32_bf16(w2p[ct*64 + l], hf, f32x4{}, 0, 0, 0);
    if (pv) {
      us4 dv;
      #pragma unroll
      for (int r = 0; r < 4; ++r) {
        int co = ct*16 + g*4 + r;
        float s = a[r] + b2l[co];
        float gt = 1.f/(1.f + expf(-s));
        float xin = bf2f(xh[((co >> 3)*64 + w*16 + n)*8 + (co & 7)]);
        float o = xin*gt;
        Db[(size_t)co*HW + p] = o;
        dv[r] = f2bf(o);
      }
      if (D2) *(us4*)&D2[((size_t)b*HW + p)*CIP + ct*16 + g*4] = dv;
    }
  }
}

// ---------- 7x7 conv 128->32, row-split, ct/rh-split waves, dy-reuse rs-loop (+ bn4 stats) ----------
template<int USED2>
__global__ __launch_bounds__(256) void k_conv7a_mfma(const float* __restrict__ D,
        const unsigned short* __restrict__ D2,
        const unsigned short* __restrict__ Wa, float* __restrict__ S,
        float* __restrict__ ps, float* __restrict__ pq) {
  int b = blockIdx.x, half = blockIdx.y, t = threadIdx.x;
  __shared__ __align__(16) unsigned short xb[4*NRW*22*8];
  __shared__ float pS[2][32], pQ[2][32];
  unsigned int* xw = (unsigned int*)xb;
  for (int i = t; i < 4*NRW*22*8/2; i += 256) xw[i] = 0u;
  int w = t >> 6, l = t & 63, g = l >> 4, x = l & 15;
  int ct = w & 1, rh = w >> 1;
  int row0 = half*8;
  f32x4 acc[4] = {};
  const short8* wp = (const short8*)Wa;
  bool prow = false; int rr = 0, xp = 0;
  if (t < HW) {
    int py = t/15, px = t - (t/15)*15;
    int gp = py + 3;
    prow = (gp >= row0) && (gp < row0 + NRW);
    rr = gp - row0; xp = px + 3;
  }
  for (int ck = 0; ck < 4; ++ck) {
    __syncthreads();
    if (prow) {
      if (USED2) {
        const unsigned short* src = &D2[((size_t)b*HW + t)*CIP + ck*32];
        #pragma unroll
        for (int g0 = 0; g0 < 4; ++g0)
          *(short8*)&xb[((g0*NRW + rr)*22 + xp)*8] = *(const short8*)&src[g0*8];
      } else {
        const float* Dbp = D + ((size_t)b*CC + ck*32)*HW;
        #pragma unroll
        for (int g0 = 0; g0 < 4; ++g0) {
          U8 tb;
          #pragma unroll
          for (int k = 0; k < 8; ++k) tb.u[k] = f2bf(Dbp[(g0*8+k)*HW + t]);
          *(short8*)&xb[((g0*NRW + rr)*22 + xp)*8] = tb.v;
        }
      }
    }
    __syncthreads();
    for (int dx = 0; dx < 7; ++dx) {
      short8 aw[7];
      #pragma unroll
      for (int dy = 0; dy < 7; ++dy)
        aw[dy] = wp[(((ck*7 + dx)*7 + dy)*2 + ct)*64 + l];
      #pragma unroll
      for (int rs = 0; rs < 10; ++rs) {
        short8 bf = *(const short8*)&xb[((g*NRW + rh*4 + rs)*22 + x + dx)*8];
        #pragma unroll
        for (int r = 0; r < 4; ++r) {
          int dy = rs - r;
          if (dy >= 0 && dy <= 6)
            acc[r] = __builtin_amdgcn_mfma_f32_16x16x32_bf16(aw[dy], bf, acc[r], 0, 0, 0);
        }
      }
    }
  }
  float ls[4] = {}, lq[4] = {};
  #pragma unroll
  for (int r = 0; r < 4; ++r) {
    int nt = row0 + rh*4 + r;
    bool valid = (x < 15) && (nt < 15);
    if (valid) {
      float* out = S + ((size_t)b*32 + ct*16 + g*4)*HW + nt*15 + x;
      #pragma unroll
      for (int q = 0; q < 4; ++q) out[q*HW] = acc[r][q];
    }
    #pragma unroll
    for (int q = 0; q < 4; ++q) {
      float v = valid ? acc[r][q] : 0.f;
      ls[q] += v; lq[q] += v*v;
    }
  }
  #pragma unroll
  for (int q = 0; q < 4; ++q) {
    float s = ls[q], qq = lq[q];
    #pragma unroll
    for (int m = 1; m < 16; m <<= 1) { s += __shfl_xor(s, m); qq += __shfl_xor(qq, m); }
    if (x == 0) { pS[rh][ct*16 + g*4 + q] = s; pQ[rh][ct*16 + g*4 + q] = qq; }
  }
  __syncthreads();
  if (t < 32) {
    ps[(size_t)t*NPMAX + b*2 + half] = pS[0][t]+pS[1][t];
    pq[(size_t)t*NPMAX + b*2 + half] = pQ[0][t]+pQ[1][t];
  }
}

// ---------- 7x7 conv 32->128, row-split, ct-pair waves, dy-reuse rs-loop (+ bn5 stats) ----------
__global__ __launch_bounds__(256) void k_conv7b_mfma(const float* __restrict__ S,
        const float* __restrict__ sc, const float* __restrict__ sh,
        const unsigned short* __restrict__ Wb, float* __restrict__ O,
        float* __restrict__ ps, float* __restrict__ pq) {
  int b = blockIdx.x, half = blockIdx.y, t = threadIdx.x;
  __shared__ __align__(16) unsigned short xb[4*NRW*22*8];
  __shared__ float scl[32], shl[32];
  __shared__ float pS[CC], pQ[CC];
  unsigned int* xw = (unsigned int*)xb;
  for (int i = t; i < 4*NRW*22*8/2; i += 256) xw[i] = 0u;
  if (t < 32) { scl[t] = sc[t]; shl[t] = sh[t]; }
  __syncthreads();
  int row0 = half*8;
  const float* Sb = S + (size_t)b*32*HW;
  if (t < HW) {
    int py = t/15, px = t - (t/15)*15;
    int gp = py + 3;
    if (gp >= row0 && gp < row0 + NRW) {
      int rr = gp - row0, xp = px + 3;
      #pragma unroll
      for (int g0 = 0; g0 < 4; ++g0) {
        U8 tb;
        #pragma unroll
        for (int k = 0; k < 8; ++k)
          tb.u[k] = f2bf(fmaxf(Sb[(g0*8+k)*HW + t]*scl[g0*8+k] + shl[g0*8+k], 0.f));
        *(short8*)&xb[((g0*NRW + rr)*22 + xp)*8] = tb.v;
      }
    }
  }
  __syncthreads();
  int w = t >> 6, l = t & 63, g = l >> 4, x = l & 15;
  int ct0 = w*2;
  f32x4 acc[2][8] = {};
  const short8* wp = (const short8*)Wb;
  for (int dx = 0; dx < 7; ++dx) {
    short8 a0[7], a1[7];
    #pragma unroll
    for (int dy = 0; dy < 7; ++dy) {
      a0[dy] = wp[((dx*7 + dy)*8 + ct0)*64 + l];
      a1[dy] = wp[((dx*7 + dy)*8 + ct0 + 1)*64 + l];
    }
    #pragma unroll
    for (int rs = 0; rs < 14; ++rs) {
      short8 bf = *(const short8*)&xb[((g*NRW + rs)*22 + x + dx)*8];
      #pragma unroll
      for (int r = 0; r < 8; ++r) {
        int dy = rs - r;
        if (dy >= 0 && dy <= 6) {
          acc[0][r] = __builtin_amdgcn_mfma_f32_16x16x32_bf16(a0[dy], bf, acc[0][r], 0, 0, 0);
          acc[1][r] = __builtin_amdgcn_mfma_f32_16x16x32_bf16(a1[dy], bf, acc[1][r], 0, 0, 0);
        }
      }
    }
  }
  float ls[2][4] = {}, lq[2][4] = {};
  #pragma unroll
  for (int ctl = 0; ctl < 2; ++ctl)
    #pragma unroll
    for (int r = 0; r < 8; ++r) {
      int nt = row0 + r;
      bool valid = (x < 15) && (nt < 15);
      if (valid) {
        float* out = O + ((size_t)b*CC + (ct0+ctl)*16 + g*4)*HW + nt*15 + x;
        #pragma unroll
        for (int q = 0; q < 4; ++q) out[q*HW] = acc[ctl][r][q];
      }
      #pragma unroll
      for (int q = 0; q < 4; ++q) {
        float v = valid ? acc[ctl][r][q] : 0.f;
        ls[ctl][q] += v; lq[ctl][q] += v*v;
      }
    }
  #pragma unroll
  for (int ctl = 0; ctl < 2; ++ctl)
    #pragma unroll
    for (int q = 0; q < 4; ++q) {
      float s = ls[ctl][q], qq = lq[ctl][q];
      #pragma unroll
      for (int m = 1; m < 16; m <<= 1) { s += __shfl_xor(s, m); qq += __shfl_xor(qq, m); }
      if (x == 0) { pS[(ct0+ctl)*16 + g*4 + q] = s; pQ[(ct0+ctl)*16 + g*4 + q] = qq; }
    }
  __syncthreads();
  if (t < CC) {
    ps[(size_t)t*NPMAX + b*2 + half] = pS[t];
    pq[(size_t)t*NPMAX + b*2 + half] = pQ[t];
  }
}

// ---------- final: D *= sigmoid(bn5(A)), float4 ----------
__global__ __launch_bounds__(256) void k_final4(f32x4* __restrict__ D, const f32x4* __restrict__ A,
                        const float* __restrict__ sc, const float* __restrict__ sh) {
  size_t i = (size_t)blockIdx.x*256 + threadIdx.x;
  f32x4 a = A[i], d = D[i];
  size_t e = i*4;
  #pragma unroll
  for (int k = 0; k < 4; ++k) {
    int c = (int)(((e + k) / HW) % CC);
    float s = a[k]*sc[c] + sh[c];
    d[k] *= 1.f/(1.f + expf(-s));
  }
  D[i] = d;
}

extern "C" void kernel_launch(void* const* d_in, const int* in_sizes, int n_in,
                              void* d_out, int out_size, void* d_ws, size_t ws_size,
                              hipStream_t stream) {
  (void)in_sizes; (void)n_in; (void)out_size;
  const float* x1    = (const float*)d_in[0];
  const float* x2    = (const float*)d_in[1];
  const float* lam   = (const float*)d_in[2];
  const float* bn1_g = (const float*)d_in[3];
  const float* bn1_b = (const float*)d_in[4];
  const float* pW1   = (const float*)d_in[5];
  const float* dW1   = (const float*)d_in[6];
  const float* db1   = (const float*)d_in[7];
  const float* bn2_g = (const float*)d_in[8];
  const float* bn2_b = (const float*)d_in[9];
  const float* pW2   = (const float*)d_in[10];
  const float* dW2   = (const float*)d_in[11];
  const float* db2   = (const float*)d_in[12];
  const float* qkvW  = (const float*)d_in[13];
  const float* bn3_g = (const float*)d_in[14];
  const float* bn3_b = (const float*)d_in[15];
  const float* ca_w1 = (const float*)d_in[16];
  const float* ca_b1 = (const float*)d_in[17];
  const float* ca_w2 = (const float*)d_in[18];
  const float* ca_b2 = (const float*)d_in[19];
  const float* sa_w1 = (const float*)d_in[20];
  const float* sbn1_g= (const float*)d_in[22];
  const float* sbn1_b= (const float*)d_in[23];
  const float* sa_w2 = (const float*)d_in[24];
  const float* sbn2_g= (const float*)d_in[26];
  const float* sbn2_b= (const float*)d_in[27];

  float* D = (float*)d_out;
  float* A = (float*)d_ws;                          // (512,128,225) f32
  float* S = A + (size_t)BB*CC*HW;                  // (512,32,225)  f32
  float* part = S + (size_t)BB*32*HW;               // 512*4*3*256 f32
  float* st = part + (size_t)BB*4*3*256;            // 1280 f32 stats
  float *sc1 = st,      *sh1 = st+128,  *sc2 = st+256, *sh2 = st+384,
        *sc3 = st+512,  *sh3 = st+640,  *sc4 = st+768, *sh4 = st+800,
        *sc5 = st+832,  *sh5 = st+960;
  float* ps = st + 1280;                            // 128*NPMAX
  float* pq = ps + (size_t)CC*NPMAX;                // 128*NPMAX
  float* cent = pq + (size_t)CC*NPMAX;              // 512*128
  float* sim  = cent + (size_t)BB*CC;               // 512*225
  float* am   = sim + (size_t)BB*HW;                // 512*225
  unsigned short* Wa  = (unsigned short*)(am + (size_t)BB*HW);
  unsigned short* Wb  = Wa + 49*4096;
  unsigned short* W1h = Wb + 49*4096;
  unsigned short* W1l = W1h + 16384;
  unsigned short* W2h = W1l + 16384;
  unsigned short* W2l = W2h + 16384;
  unsigned short* Wk  = W2l + 16384;
  unsigned short* Wv  = Wk  + 16384;
  unsigned short* Wc1 = Wv  + 16384;
  unsigned short* Wc2 = Wc1 + 4096;
  unsigned short* D2  = Wc2 + 4096;                 // (512,225,136) bf16
  unsigned short* X2  = D2 + (size_t)BB*HW*CIP;     // (512,16,225,8) bf16
  size_t needD2 = (size_t)((char*)(D2 + (size_t)BB*HW*CIP) - (char*)d_ws);
  size_t needX2 = (size_t)((char*)(X2 + (size_t)BB*16*HW*8) - (char*)d_ws);
  bool useD2 = ws_size >= needD2;
  bool useX2 = ws_size >= needX2;

  const int NB4 = BB*4;

  k_prep_all<<<1792, 256, 0, stream>>>(sa_w1, sa_w2, pW1, pW2, qkvW, ca_w1, ca_w2,
                                       Wa, Wb, W1h, W1l, W2h, W2l, Wk, Wv, Wc1, Wc2);

  k_at1a <<<dim3(BB,4), 256, 0, stream>>>(x1, x2, part);
  k_at1b <<<BB, 256, 0, stream>>>(x1, x2, part, lam, am);
  k_at1c <<<dim3(BB,4), 256, 0, stream>>>(x1, x2, am, A, ps, pq);
  k_bnfin2<<<CC, 256, 0, stream>>>(ps, pq, BB, bn1_g, bn1_b, sc1, sh1);
  k_pw_v3<1><<<NB4, 256, 0, stream>>>(A, W1h, W1l, sc1, sh1, dW1, db1, ps, pq);
  k_bnfin2<<<CC, 256, 0, stream>>>(ps, pq, NB4, bn2_g, bn2_b, sc2, sh2);
  k_pw_v3<2><<<NB4, 256, 0, stream>>>(A, W2h, W2l, sc2, sh2, nullptr, nullptr, nullptr, nullptr);
  k_dw3   <<<dim3(BB,8), 256, 0, stream>>>(A, dW2, db2, useX2 ? X2 : nullptr);
  k_cent  <<<BB, 128, 0, stream>>>(A, qkvW, cent);
  if (useX2) k_attn2a<1><<<NB4, 256, 0, stream>>>(A, X2, cent, Wk, sim);
  else       k_attn2a<0><<<NB4, 256, 0, stream>>>(A, nullptr, cent, Wk, sim);
  k_soft  <<<BB, 256, 0, stream>>>(sim);
  if (useX2) k_attn2b<1><<<NB4, 256, 0, stream>>>(A, X2, sim, Wv, ps, pq);
  else       k_attn2b<0><<<NB4, 256, 0, stream>>>(A, nullptr, sim, Wv, ps, pq);
  k_bnfin2<<<CC, 256, 0, stream>>>(ps, pq, NB4, bn3_g, bn3_b, sc3, sh3);
  k_chatt_v3<<<NB4, 256, 0, stream>>>(A, D, useD2 ? D2 : nullptr, sc3, sh3, Wc1, ca_b1, Wc2, ca_b2);
  if (useD2) k_conv7a_mfma<1><<<dim3(BB,2), 256, 0, stream>>>(D, D2, Wa, S, ps, pq);
  else       k_conv7a_mfma<0><<<dim3(BB,2), 256, 0, stream>>>(D, nullptr, Wa, S, ps, pq);
  k_bnfin2<<<32, 256, 0, stream>>>(ps, pq, BB*2, sbn1_g, sbn1_b, sc4, sh4);
  k_conv7b_mfma<<<dim3(BB,2), 256, 0, stream>>>(S, sc4, sh4, Wb, A, ps, pq);
  k_bnfin2<<<CC, 256, 0, stream>>>(ps, pq, BB*2, sbn2_g, sbn2_b, sc5, sh5);
  k_final4<<<(BB*CC*HW)/1024, 256, 0, stream>>>((f32x4*)D, (const f32x4*)A, sc5, sh5);
}

// Round 16
// 477.429 us; speedup vs baseline: 1.6034x; 1.0396x over previous
//
#include <hip/hip_runtime.h>
#include <hip/hip_bf16.h>
#include <cmath>

#define BB 512
#define CC 128
#define HW 225
#define CIP 136     // ushort stride of D2 [px][ci] rows (272 B)
#define CIPH 40     // ushort stride for 32-ch hidden rows
#define NPMAX 2048  // max partial-stat blocks
#define NRW 14      // padded-row window for row-split convs

typedef __attribute__((ext_vector_type(8))) short short8;
typedef __attribute__((ext_vector_type(4))) float f32x4;
typedef __attribute__((ext_vector_type(4))) unsigned short us4;

union U8 { unsigned short u[8]; short8 v; };

__device__ __forceinline__ unsigned short f2bf(float v) {
  __hip_bfloat16 h = __float2bfloat16(v);
  return *(unsigned short*)&h;
}
__device__ __forceinline__ float bf2f(unsigned short u) {
  __hip_bfloat16 h = *(__hip_bfloat16*)&u;
  return __bfloat162float(h);
}

template<int NT>
__device__ __forceinline__ float br_max(float v, float* red, int t) {
  red[t] = v; __syncthreads();
  for (int st = NT/2; st > 0; st >>= 1) { if (t < st) red[t] = fmaxf(red[t], red[t+st]); __syncthreads(); }
  float r = red[0]; __syncthreads();
  return r;
}
template<int NT>
__device__ __forceinline__ float br_sum(float v, float* red, int t) {
  red[t] = v; __syncthreads();
  for (int st = NT/2; st > 0; st >>= 1) { if (t < st) red[t] += red[t+st]; __syncthreads(); }
  float r = red[0]; __syncthreads();
  return r;
}

// finalize fused per-block partials ps/pq[c][NPMAX], np valid slots
__global__ __launch_bounds__(256) void k_bnfin2(const float* __restrict__ ps, const float* __restrict__ pq,
                         int np,
                         const float* __restrict__ g, const float* __restrict__ bt,
                         float* __restrict__ scale, float* __restrict__ shift) {
  int c = blockIdx.x, t = threadIdx.x;
  __shared__ float rs[256], rq[256];
  float s = 0.f, q = 0.f;
  for (int i = t; i < np; i += 256) { s += ps[(size_t)c*NPMAX + i]; q += pq[(size_t)c*NPMAX + i]; }
  rs[t] = s; rq[t] = q; __syncthreads();
  for (int st = 128; st > 0; st >>= 1) { if (t < st) { rs[t]+=rs[t+st]; rq[t]+=rq[t+st]; } __syncthreads(); }
  if (t == 0) {
    const float N = (float)BB*HW;
    float mean = rs[0]/N, var = rq[0]/N - mean*mean;
    float sc = g[c]*rsqrtf(var + 1e-5f);
    scale[c] = sc; shift[c] = bt[c] - mean*sc;
  }
}

// ---------- attn1 stage A ----------
__global__ __launch_bounds__(256) void k_at1a(const float* __restrict__ x1, const float* __restrict__ x2,
                       float* __restrict__ part) {
  int b = blockIdx.x, cg = blockIdx.y, t = threadIdx.x;
  __shared__ float cent[32];
  const float* xb1 = x1 + (size_t)b*64*HW;
  const float* xb2 = x2 + (size_t)b*64*HW;
  if (t < 32) { int c = cg*32 + t; cent[t] = (c < 64) ? xb1[c*HW + 112] : xb2[(c-64)*HW + 112]; }
  __syncthreads();
  if (t < HW) {
    float e2 = 0.f, dot = 0.f, qn2 = 0.f;
    for (int k = 0; k < 32; ++k) {
      int c = cg*32 + k;
      float xv = (c < 64) ? xb1[c*HW + t] : xb2[(c-64)*HW + t];
      float ce = cent[k];
      float d = xv - ce;
      e2 += d*d; dot += xv*ce; qn2 += xv*xv;
    }
    size_t base = ((size_t)(b*4 + cg)*3)*256;
    part[base + t] = e2; part[base + 256 + t] = dot; part[base + 512 + t] = qn2;
  }
}

// ---------- attn1 stage B ----------
__global__ __launch_bounds__(256) void k_at1b(const float* __restrict__ x1, const float* __restrict__ x2,
                       const float* __restrict__ part, const float* __restrict__ lam,
                       float* __restrict__ am) {
  int b = blockIdx.x, t = threadIdx.x;
  __shared__ float red[256];
  float cv = 0.f;
  if (t < CC) {
    float ce = (t < 64) ? x1[(size_t)b*64*HW + t*HW + 112] : x2[(size_t)b*64*HW + (t-64)*HW + 112];
    cv = ce*ce;
  }
  float cn2 = br_sum<256>(cv, red, t);
  float e2 = 0.f, dot = 0.f, qn2 = 0.f;
  if (t < HW) {
    #pragma unroll
    for (int cg = 0; cg < 4; ++cg) {
      size_t base = ((size_t)(b*4 + cg)*3)*256;
      e2 += part[base + t]; dot += part[base + 256 + t]; qn2 += part[base + 512 + t];
    }
  }
  float sim_e = 0.f, sim_c = 0.f;
  if (t < HW) {
    sim_e = 1.f/(1.f + sqrtf(e2));
    float qn = sqrtf(qn2), cn = sqrtf(cn2);
    sim_c = dot / (fmaxf(cn, 1e-8f) * fmaxf(qn, 1e-8f));
  }
  float m1 = br_max<256>((t<HW)? sim_e : -1e30f, red, t);
  float e1v = (t<HW)? expf(sim_e - m1) : 0.f;
  float s1 = br_sum<256>(e1v, red, t);
  float m2 = br_max<256>((t<HW)? sim_c : -1e30f, red, t);
  float e2v = (t<HW)? expf(sim_c - m2) : 0.f;
  float s2 = br_sum<256>(e2v, red, t);
  float lmd = 1.f/(1.f + expf(-lam[0]));
  if (t < HW) am[(size_t)b*HW + t] = 1.f + lmd*e1v/s1 + (1.f - lmd)*e2v/s2;
}

// ---------- attn1 stage C ----------
__global__ __launch_bounds__(256) void k_at1c(const float* __restrict__ x1, const float* __restrict__ x2,
                       const float* __restrict__ am, float* __restrict__ A,
                       float* __restrict__ ps, float* __restrict__ pq) {
  int b = blockIdx.x, cg = blockIdx.y, t = threadIdx.x;
  __shared__ float pS[4][32], pQ[4][32];
  const float* xb1 = x1 + (size_t)b*64*HW;
  const float* xb2 = x2 + (size_t)b*64*HW;
  float* Ab = A + (size_t)b*CC*HW;
  float amv = (t < HW) ? am[(size_t)b*HW + t] : 0.f;
  int w = t >> 6, lane = t & 63;
  for (int k = 0; k < 32; ++k) {
    int c = cg*32 + k;
    float xv = 0.f;
    if (t < HW) xv = (c < 64) ? xb1[c*HW + t] : xb2[(c-64)*HW + t];
    float val = xv*amv;
    if (t < HW) Ab[(size_t)c*HW + t] = val;
    float s = val, q = val*val;
    #pragma unroll
    for (int m = 1; m < 64; m <<= 1) { s += __shfl_xor(s, m); q += __shfl_xor(q, m); }
    if (lane == 0) { pS[w][k] = s; pQ[w][k] = q; }
  }
  __syncthreads();
  if (t < 32) {
    int c = cg*32 + t;
    ps[(size_t)c*NPMAX + b] = pS[0][t]+pS[1][t]+pS[2][t]+pS[3][t];
    pq[(size_t)c*NPMAX + b] = pQ[0][t]+pQ[1][t]+pQ[2][t]+pQ[3][t];
  }
}

// ---------- merged weight pre-pack ----------
// Wa: [ck(4)][dx(7)][dy(7)][ct(2)][lane64][j8]
// Wb: [dx(7)][dy(7)][ct(8)][lane64][j8]
__global__ __launch_bounds__(256) void k_prep_all(
    const float* __restrict__ sa_w1, const float* __restrict__ sa_w2,
    const float* __restrict__ pW1, const float* __restrict__ pW2,
    const float* __restrict__ qkvW, const float* __restrict__ ca_w1, const float* __restrict__ ca_w2,
    unsigned short* __restrict__ Wa, unsigned short* __restrict__ Wb,
    unsigned short* __restrict__ W1h, unsigned short* __restrict__ W1l,
    unsigned short* __restrict__ W2h, unsigned short* __restrict__ W2l,
    unsigned short* __restrict__ Wk, unsigned short* __restrict__ Wv,
    unsigned short* __restrict__ Wc1, unsigned short* __restrict__ Wc2) {
  int id = blockIdx.x*256 + threadIdx.x;
  const int NA = 49*4096;
  if (id < NA) {
    int j = id & 7, l = (id >> 3) & 63, ct = (id >> 9) & 1;
    int r = id >> 10;
    int dy = r % 7; r /= 7;
    int dx = r % 7; int ck = r / 7;
    int co = ct*16 + (l & 15);
    int ci = ck*32 + ((l >> 4) << 3) + j;
    Wa[id] = f2bf(sa_w1[(co*128 + ci)*49 + dy*7 + dx]);
    return;
  }
  id -= NA;
  if (id < NA) {
    int j = id & 7, l = (id >> 3) & 63, ct = (id >> 9) & 7;
    int r = id >> 12;
    int dy = r % 7, dx = r / 7;
    int co = ct*16 + (l & 15);
    int ci = ((l >> 4) << 3) + j;
    Wb[id] = f2bf(sa_w2[(co*32 + ci)*49 + dy*7 + dx]);
    return;
  }
  id -= NA;
  if (id < 16384) {
    int j = id & 7, l = (id >> 3) & 63, ct = (id >> 9) & 7, cs = id >> 12;
    int co = ct*16 + (l & 15);
    int ci = cs*32 + ((l >> 4) << 3) + j;
    float v = pW1[co*128 + ci];
    __hip_bfloat16 h = __float2bfloat16(v);
    W1h[id] = *(unsigned short*)&h;
    W1l[id] = f2bf(v - __bfloat162float(h));
    return;
  }
  id -= 16384;
  if (id < 16384) {
    int j = id & 7, l = (id >> 3) & 63, ct = (id >> 9) & 7, cs = id >> 12;
    int co = ct*16 + (l & 15);
    int ci = cs*32 + ((l >> 4) << 3) + j;
    float v = pW2[co*128 + ci];
    __hip_bfloat16 h = __float2bfloat16(v);
    W2h[id] = *(unsigned short*)&h;
    W2l[id] = f2bf(v - __bfloat162float(h));
    return;
  }
  id -= 16384;
  if (id < 16384) {
    int j = id & 7, l = (id >> 3) & 63, ct = (id >> 9) & 7, cs = id >> 12;
    int co = ct*16 + (l & 15);
    int ci = cs*32 + ((l >> 4) << 3) + j;
    Wk[id] = f2bf(qkvW[(size_t)(128 + co)*128 + ci]);
    Wv[id] = f2bf(qkvW[(size_t)(256 + co)*128 + ci]);
    return;
  }
  id -= 16384;
  if (id < 4096) {
    int j = id & 7, l = (id >> 3) & 63, ct = (id >> 9) & 1, cs = (id >> 10) & 3;
    int co = ct*16 + (l & 15);
    int ci = cs*32 + ((l >> 4) << 3) + j;
    Wc1[id] = f2bf(ca_w1[co*128 + ci]);
    return;
  }
  id -= 4096;
  {
    int j = id & 7, l = (id >> 3) & 63, ct = (id >> 9) & 7;
    int co = ct*16 + (l & 15);
    int ci = ((l >> 4) << 3) + j;
    Wc2[id] = f2bf(ca_w2[co*32 + ci]);
  }
}

// ---------- fused BN + 1x1 conv, pixel-tile GEMM, ct-split waves, in-place ----------
template<int MODE>
__global__ __launch_bounds__(256) void k_pw_v3(float* __restrict__ A,
        const unsigned short* __restrict__ Whi, const unsigned short* __restrict__ Wlo,
        const float* __restrict__ scale, const float* __restrict__ shift,
        const float* __restrict__ dw, const float* __restrict__ db,
        float* __restrict__ ps, float* __restrict__ pq) {
  int blk = blockIdx.x;
  int b = blk >> 2, tile = blk & 3, p0 = tile*64;
  int t = threadIdx.x;
  __shared__ __align__(16) unsigned short xh[16*64*8];
  __shared__ __align__(16) unsigned short xl[16*64*8];
  __shared__ float scl[CC], shf[CC], dwl[CC], dbl[CC];
  __shared__ float pS[CC], pQ[CC];
  if (t < CC) {
    scl[t] = scale[t]; shf[t] = shift[t];
    if (MODE == 1) { dwl[t] = dw[t]; dbl[t] = db[t]; }
  }
  __syncthreads();
  float* Ab = A + (size_t)b*CC*HW;
  {
    int px = t & 63, cig = t >> 6;
    int p = p0 + px;
    bool pv = p < HW;
    #pragma unroll
    for (int k0 = 0; k0 < 32; k0 += 8) {
      U8 th, tl;
      #pragma unroll
      for (int j = 0; j < 8; ++j) {
        int ci = cig*32 + k0 + j;
        float v = pv ? Ab[(size_t)ci*HW + p]*scl[ci] + shf[ci] : 0.f;
        __hip_bfloat16 h = __float2bfloat16(v);
        th.u[j] = *(unsigned short*)&h;
        tl.u[j] = f2bf(v - __bfloat162float(h));
      }
      int oo = cig*4 + (k0 >> 3);
      *(short8*)&xh[(oo*64 + px)*8] = th.v;
      *(short8*)&xl[(oo*64 + px)*8] = tl.v;
    }
  }
  __syncthreads();
  int w = t >> 6, l = t & 63, g = l >> 4, n = l & 15;
  const short8* whp = (const short8*)Whi;
  const short8* wlp = (const short8*)Wlo;
  short8 ah[4][2], al[4][2];
  #pragma unroll
  for (int cs = 0; cs < 4; ++cs)
    #pragma unroll
    for (int ctl = 0; ctl < 2; ++ctl) {
      ah[cs][ctl] = whp[(cs*8 + w*2 + ctl)*64 + l];
      al[cs][ctl] = wlp[(cs*8 + w*2 + ctl)*64 + l];
    }
  float ls[2][4] = {}, lq[2][4] = {};
  for (int pt = 0; pt < 4; ++pt) {
    int p = p0 + pt*16 + n;
    bool pv = p < HW;
    short8 bh[4], bl[4];
    #pragma unroll
    for (int cs = 0; cs < 4; ++cs) {
      bh[cs] = *(const short8*)&xh[((cs*4 + g)*64 + pt*16 + n)*8];
      bl[cs] = *(const short8*)&xl[((cs*4 + g)*64 + pt*16 + n)*8];
    }
    f32x4 acc[2] = {};
    #pragma unroll
    for (int cs = 0; cs < 4; ++cs)
      #pragma unroll
      for (int ctl = 0; ctl < 2; ++ctl) {
        acc[ctl] = __builtin_amdgcn_mfma_f32_16x16x32_bf16(ah[cs][ctl], bh[cs], acc[ctl], 0, 0, 0);
        acc[ctl] = __builtin_amdgcn_mfma_f32_16x16x32_bf16(ah[cs][ctl], bl[cs], acc[ctl], 0, 0, 0);
        acc[ctl] = __builtin_amdgcn_mfma_f32_16x16x32_bf16(al[cs][ctl], bh[cs], acc[ctl], 0, 0, 0);
      }
    #pragma unroll
    for (int ctl = 0; ctl < 2; ++ctl)
      #pragma unroll
      for (int r = 0; r < 4; ++r) {
        int co = (w*2 + ctl)*16 + g*4 + r;
        float y = acc[ctl][r];
        y = (y >= 0.f) ? y : 0.01f*y;
        if (MODE == 1) { y = y*dwl[co] + dbl[co]; y = fmaxf(y, 0.f); }
        if (pv) Ab[(size_t)co*HW + p] = y;
        if (MODE == 1) {
          float vs = pv ? y : 0.f;
          ls[ctl][r] += vs; lq[ctl][r] += vs*vs;
        }
      }
  }
  if (MODE == 1) {
    #pragma unroll
    for (int ctl = 0; ctl < 2; ++ctl)
      #pragma unroll
      for (int r = 0; r < 4; ++r) {
        float s = ls[ctl][r], q = lq[ctl][r];
        #pragma unroll
        for (int m = 1; m < 16; m <<= 1) { s += __shfl_xor(s, m); q += __shfl_xor(q, m); }
        if (n == 0) { pS[(w*2 + ctl)*16 + g*4 + r] = s; pQ[(w*2 + ctl)*16 + g*4 + r] = q; }
      }
    __syncthreads();
    if (t < CC) {
      ps[(size_t)t*NPMAX + blk] = pS[t];
      pq[(size_t)t*NPMAX + blk] = pQ[t];
    }
  }
}

// ---------- depthwise 3x3 pad1 + bias + relu, grid (B, 8 ch-groups); emits bf16 X2 ----------
__global__ __launch_bounds__(256) void k_dw3(float* __restrict__ A, const float* __restrict__ w,
                      const float* __restrict__ db, unsigned short* __restrict__ X2) {
  int b = blockIdx.x, cg = blockIdx.y, t = threadIdx.x;
  __shared__ float xin[16][HW];
  float* Ab = A + ((size_t)b*CC + cg*16)*HW;
  for (int i = t; i < 16*HW; i += 256) xin[i/HW][i%HW] = Ab[i];
  __syncthreads();
  if (t < HW) {
    int y = t/15, x = t - y*15;
    U8 o0, o1;
    for (int c = 0; c < 16; ++c) {
      int ch = cg*16 + c;
      float acc = db[ch];
      #pragma unroll
      for (int ky = 0; ky < 3; ++ky) {
        int iy = y + ky - 1;
        if (iy < 0 || iy >= 15) continue;
        #pragma unroll
        for (int kx = 0; kx < 3; ++kx) {
          int ix = x + kx - 1;
          if (ix < 0 || ix >= 15) continue;
          acc += w[ch*9 + ky*3 + kx]*xin[c][iy*15 + ix];
        }
      }
      float val = fmaxf(acc, 0.f);
      Ab[c*HW + t] = val;
      if (c < 8) o0.u[c] = f2bf(val); else o1.u[c-8] = f2bf(val);
    }
    if (X2) {
      *(short8*)&X2[(((size_t)b*16 + cg*2 + 0)*HW + t)*8] = o0.v;
      *(short8*)&X2[(((size_t)b*16 + cg*2 + 1)*HW + t)*8] = o1.v;
    }
  }
}

// ---------- attn2 stage 1: center Q projection ----------
__global__ __launch_bounds__(128) void k_cent(const float* __restrict__ A,
        const float* __restrict__ Wq, float* __restrict__ cent) {
  int b = blockIdx.x, t = threadIdx.x;
  __shared__ float xc[CC];
  const float* Ab = A + (size_t)b*CC*HW;
  xc[t] = bf2f(f2bf(Ab[(size_t)t*HW + 112]));
  __syncthreads();
  const float* wq = Wq + (size_t)t*CC;
  float acc = 0.f;
  for (int ci = 0; ci < CC; ++ci) acc += wq[ci]*xc[ci];
  cent[(size_t)b*CC + t] = acc;
}

// ---------- attn2 stage 2: K-proj + e2 logits ----------
template<int USEX2>
__global__ __launch_bounds__(256) void k_attn2a(const float* __restrict__ A,
        const unsigned short* __restrict__ X2,
        const float* __restrict__ cent, const unsigned short* __restrict__ Wk,
        float* __restrict__ sim) {
  int blk = blockIdx.x;
  int b = blk >> 2, tile = blk & 3, p0 = tile*64;
  int t = threadIdx.x;
  __shared__ __align__(16) unsigned short xh[16*64*8];
  __shared__ float cl[CC];
  const float* Ab = A + (size_t)b*CC*HW;
  if (t < CC) cl[t] = cent[(size_t)b*CC + t];
  {
    int px = t & 63, cig = t >> 6;
    int p = p0 + px;
    bool pv = p < HW;
    #pragma unroll
    for (int k0 = 0; k0 < 32; k0 += 8) {
      int oo = cig*4 + (k0>>3);
      short8 v;
      if (USEX2) {
        v = pv ? *(const short8*)&X2[(((size_t)b*16 + oo)*HW + p)*8] : short8{};
      } else {
        U8 th;
        #pragma unroll
        for (int j = 0; j < 8; ++j) {
          int ci = cig*32 + k0 + j;
          th.u[j] = pv ? f2bf(Ab[(size_t)ci*HW + p]) : 0;
        }
        v = th.v;
      }
      *(short8*)&xh[(oo*64 + px)*8] = v;
    }
  }
  __syncthreads();
  int w = t >> 6, l = t & 63, g = l >> 4, n = l & 15;
  int p = p0 + w*16 + n;
  bool pv = p < HW;
  const short8* wkp = (const short8*)Wk;
  short8 bf[4];
  #pragma unroll
  for (int cs = 0; cs < 4; ++cs)
    bf[cs] = *(const short8*)&xh[((cs*4 + g)*64 + w*16 + n)*8];
  float e2p = 0.f;
  #pragma unroll
  for (int ct = 0; ct < 8; ++ct) {
    f32x4 k = {};
    #pragma unroll
    for (int cs = 0; cs < 4; ++cs)
      k = __builtin_amdgcn_mfma_f32_16x16x32_bf16(wkp[(cs*8 + ct)*64 + l], bf[cs], k, 0, 0, 0);
    #pragma unroll
    for (int r = 0; r < 4; ++r) { float d = cl[ct*16 + g*4 + r] - k[r]; e2p += d*d; }
  }
  e2p += __shfl_xor(e2p, 16);
  e2p += __shfl_xor(e2p, 32);
  if (g == 0 && pv) sim[(size_t)b*HW + p] = 1.f/(1.f + sqrtf(e2p));
}

// ---------- attn2 stage 3: per-image softmax ----------
__global__ __launch_bounds__(256) void k_soft(float* __restrict__ sim) {
  int b = blockIdx.x, t = threadIdx.x;
  __shared__ float red[256];
  float val = (t < HW) ? sim[(size_t)b*HW + t] : -1e30f;
  float m = br_max<256>(val, red, t);
  float e = (t < HW) ? expf(val - m) : 0.f;
  float s = br_sum<256>(e, red, t);
  if (t < HW) sim[(size_t)b*HW + t] = e/s;
}

// ---------- attn2 stage 4: V-proj + residual + fused bn3 stats ----------
template<int USEX2>
__global__ __launch_bounds__(256) void k_attn2b(float* __restrict__ A,
        const unsigned short* __restrict__ X2,
        const float* __restrict__ att, const unsigned short* __restrict__ Wv,
        float* __restrict__ ps, float* __restrict__ pq) {
  int blk = blockIdx.x;
  int b = blk >> 2, tile = blk & 3, p0 = tile*64;
  int t = threadIdx.x;
  __shared__ __align__(16) unsigned short xh[16*64*8];
  __shared__ float pS[4][CC], pQ[4][CC];
  float* Ab = A + (size_t)b*CC*HW;
  {
    int px = t & 63, cig = t >> 6;
    int p = p0 + px;
    bool pv = p < HW;
    #pragma unroll
    for (int k0 = 0; k0 < 32; k0 += 8) {
      int oo = cig*4 + (k0>>3);
      short8 v;
      if (USEX2) {
        v = pv ? *(const short8*)&X2[(((size_t)b*16 + oo)*HW + p)*8] : short8{};
      } else {
        U8 th;
        #pragma unroll
        for (int j = 0; j < 8; ++j) {
          int ci = cig*32 + k0 + j;
          th.u[j] = pv ? f2bf(Ab[(size_t)ci*HW + p]) : 0;
        }
        v = th.v;
      }
      *(short8*)&xh[(oo*64 + px)*8] = v;
    }
  }
  __syncthreads();
  int w = t >> 6, l = t & 63, g = l >> 4, n = l & 15;
  int p = p0 + w*16 + n;
  bool pv = p < HW;
  float ap = pv ? att[(size_t)b*HW + p] : 0.f;
  const short8* wvp = (const short8*)Wv;
  short8 bf[4];
  #pragma unroll
  for (int cs = 0; cs < 4; ++cs)
    bf[cs] = *(const short8*)&xh[((cs*4 + g)*64 + w*16 + n)*8];
  #pragma unroll
  for (int ct = 0; ct < 8; ++ct) {
    f32x4 v = {};
    #pragma unroll
    for (int cs = 0; cs < 4; ++cs)
      v = __builtin_amdgcn_mfma_f32_16x16x32_bf16(wvp[(cs*8 + ct)*64 + l], bf[cs], v, 0, 0, 0);
    #pragma unroll
    for (int r = 0; r < 4; ++r) {
      int co = ct*16 + g*4 + r;
      float val = 0.f;
      if (pv) {
        val = ap*v[r] + Ab[(size_t)co*HW + p];
        Ab[(size_t)co*HW + p] = val;
      }
      float s = val, q = val*val;
      #pragma unroll
      for (int m = 1; m < 16; m <<= 1) { s += __shfl_xor(s, m); q += __shfl_xor(q, m); }
      if (n == 0) { pS[w][co] = s; pQ[w][co] = q; }
    }
  }
  __syncthreads();
  if (t < CC) {
    ps[(size_t)t*NPMAX + blk] = pS[0][t]+pS[1][t]+pS[2][t]+pS[3][t];
    pq[(size_t)t*NPMAX + blk] = pQ[0][t]+pQ[1][t]+pQ[2][t]+pQ[3][t];
  }
}

// ---------- BN3 + channel-attention gate; writes D (+ bf16 D2) ----------
__global__ __launch_bounds__(256) void k_chatt_v3(const float* __restrict__ A, float* __restrict__ D,
        unsigned short* __restrict__ D2,
        const float* __restrict__ sc, const float* __restrict__ sh,
        const unsigned short* __restrict__ Wc1, const float* __restrict__ b1,
        const unsigned short* __restrict__ Wc2, const float* __restrict__ b2) {
  int blk = blockIdx.x;
  int b = blk >> 2, tile = blk & 3, p0 = tile*64;
  int t = threadIdx.x;
  __shared__ __align__(16) unsigned short xh[16*64*8];
  __shared__ __align__(16) unsigned short hb[64*CIPH];
  __shared__ float scl[CC], shl[CC], b2l[CC], b1l[32];
  const float* Ab = A + (size_t)b*CC*HW;
  float* Db = D + (size_t)b*CC*HW;
  if (t < CC) { scl[t] = sc[t]; shl[t] = sh[t]; b2l[t] = b2[t]; }
  if (t < 32) b1l[t] = b1[t];
  __syncthreads();
  {
    int px = t & 63, cig = t >> 6;
    int p = p0 + px;
    bool pv = p < HW;
    #pragma unroll
    for (int k0 = 0; k0 < 32; k0 += 8) {
      U8 th;
      #pragma unroll
      for (int j = 0; j < 8; ++j) {
        int ci = cig*32 + k0 + j;
        th.u[j] = pv ? f2bf(Ab[(size_t)ci*HW + p]*scl[ci] + shl[ci]) : 0;
      }
      *(short8*)&xh[((cig*4 + (k0>>3))*64 + px)*8] = th.v;
    }
  }
  __syncthreads();
  int w = t >> 6, l = t & 63, g = l >> 4, n = l & 15;
  int p = p0 + w*16 + n;
  bool pv = p < HW;
  const short8* w1p = (const short8*)Wc1;
  const short8* w2p = (const short8*)Wc2;
  short8 bf[4];
  #pragma unroll
  for (int cs = 0; cs < 4; ++cs)
    bf[cs] = *(const short8*)&xh[((cs*4 + g)*64 + w*16 + n)*8];
  #pragma unroll
  for (int ct = 0; ct < 2; ++ct) {
    f32x4 a = {};
    #pragma unroll
    for (int cs = 0; cs < 4; ++cs)
      a = __builtin_amdgcn_mfma_f32_16x16x32_bf16(w1p[(cs*2 + ct)*64 + l], bf[cs], a, 0, 0, 0);
    us4 hv;
    #pragma unroll
    for (int r = 0; r < 4; ++r) hv[r] = f2bf(fmaxf(a[r] + b1l[ct*16 + g*4 + r], 0.f));
    *(us4*)&hb[(w*16+n)*CIPH + ct*16 + g*4] = hv;
  }
  __syncthreads();
  short8 hf = *(const short8*)&hb[(w*16+n)*CIPH + g*8];
  #pragma unroll
  for (int ct = 0; ct < 8; ++ct) {
    f32x4 a = __builtin_amdgcn_mfma_f32_16x16x32_bf16(w2p[ct*64 + l], hf, f32x4{}, 0, 0, 0);
    if (pv) {
      us4 dv;
      #pragma unroll
      for (int r = 0; r < 4; ++r) {
        int co = ct*16 + g*4 + r;
        float s = a[r] + b2l[co];
        float gt = 1.f/(1.f + expf(-s));
        float xin = bf2f(xh[((co >> 3)*64 + w*16 + n)*8 + (co & 7)]);
        float o = xin*gt;
        Db[(size_t)co*HW + p] = o;
        dv[r] = f2bf(o);
      }
      if (D2) *(us4*)&D2[((size_t)b*HW + p)*CIP + ct*16 + g*4] = dv;
    }
  }
}

// ---------- 7x7 conv 128->32, row-split, ct/rh-split waves, dy-reuse rs-loop (+ bn4 stats) ----------
template<int USED2>
__global__ __launch_bounds__(256) void k_conv7a_mfma(const float* __restrict__ D,
        const unsigned short* __restrict__ D2,
        const unsigned short* __restrict__ Wa, float* __restrict__ S,
        float* __restrict__ ps, float* __restrict__ pq) {
  int b = blockIdx.x, half = blockIdx.y, t = threadIdx.x;
  __shared__ __align__(16) unsigned short xb[4*NRW*22*8];
  __shared__ float pS[2][32], pQ[2][32];
  unsigned int* xw = (unsigned int*)xb;
  for (int i = t; i < 4*NRW*22*8/2; i += 256) xw[i] = 0u;
  int w = t >> 6, l = t & 63, g = l >> 4, x = l & 15;
  int ct = w & 1, rh = w >> 1;
  int row0 = half*8;
  f32x4 acc[4] = {};
  const short8* wp = (const short8*)Wa;
  bool prow = false; int rr = 0, xp = 0;
  if (t < HW) {
    int py = t/15, px = t - (t/15)*15;
    int gp = py + 3;
    prow = (gp >= row0) && (gp < row0 + NRW);
    rr = gp - row0; xp = px + 3;
  }
  for (int ck = 0; ck < 4; ++ck) {
    __syncthreads();
    if (prow) {
      if (USED2) {
        const unsigned short* src = &D2[((size_t)b*HW + t)*CIP + ck*32];
        #pragma unroll
        for (int g0 = 0; g0 < 4; ++g0)
          *(short8*)&xb[((g0*NRW + rr)*22 + xp)*8] = *(const short8*)&src[g0*8];
      } else {
        const float* Dbp = D + ((size_t)b*CC + ck*32)*HW;
        #pragma unroll
        for (int g0 = 0; g0 < 4; ++g0) {
          U8 tb;
          #pragma unroll
          for (int k = 0; k < 8; ++k) tb.u[k] = f2bf(Dbp[(g0*8+k)*HW + t]);
          *(short8*)&xb[((g0*NRW + rr)*22 + xp)*8] = tb.v;
        }
      }
    }
    __syncthreads();
    for (int dx = 0; dx < 7; ++dx) {
      short8 aw[7];
      #pragma unroll
      for (int dy = 0; dy < 7; ++dy)
        aw[dy] = wp[(((ck*7 + dx)*7 + dy)*2 + ct)*64 + l];
      #pragma unroll
      for (int rs = 0; rs < 10; ++rs) {
        short8 bf = *(const short8*)&xb[((g*NRW + rh*4 + rs)*22 + x + dx)*8];
        #pragma unroll
        for (int r = 0; r < 4; ++r) {
          int dy = rs - r;
          if (dy >= 0 && dy <= 6)
            acc[r] = __builtin_amdgcn_mfma_f32_16x16x32_bf16(aw[dy], bf, acc[r], 0, 0, 0);
        }
      }
    }
  }
  float ls[4] = {}, lq[4] = {};
  #pragma unroll
  for (int r = 0; r < 4; ++r) {
    int nt = row0 + rh*4 + r;
    bool valid = (x < 15) && (nt < 15);
    if (valid) {
      float* out = S + ((size_t)b*32 + ct*16 + g*4)*HW + nt*15 + x;
      #pragma unroll
      for (int q = 0; q < 4; ++q) out[q*HW] = acc[r][q];
    }
    #pragma unroll
    for (int q = 0; q < 4; ++q) {
      float v = valid ? acc[r][q] : 0.f;
      ls[q] += v; lq[q] += v*v;
    }
  }
  #pragma unroll
  for (int q = 0; q < 4; ++q) {
    float s = ls[q], qq = lq[q];
    #pragma unroll
    for (int m = 1; m < 16; m <<= 1) { s += __shfl_xor(s, m); qq += __shfl_xor(qq, m); }
    if (x == 0) { pS[rh][ct*16 + g*4 + q] = s; pQ[rh][ct*16 + g*4 + q] = qq; }
  }
  __syncthreads();
  if (t < 32) {
    ps[(size_t)t*NPMAX + b*2 + half] = pS[0][t]+pS[1][t];
    pq[(size_t)t*NPMAX + b*2 + half] = pQ[0][t]+pQ[1][t];
  }
}

// ---------- 7x7 conv 32->128, grid (B,2,2): 1 ct per wave, dy-reuse rs-loop (+ bn5 stats) ----------
__global__ __launch_bounds__(256) void k_conv7b_mfma(const float* __restrict__ S,
        const float* __restrict__ sc, const float* __restrict__ sh,
        const unsigned short* __restrict__ Wb, float* __restrict__ O,
        float* __restrict__ ps, float* __restrict__ pq) {
  int b = blockIdx.x, half = blockIdx.y, cg = blockIdx.z, t = threadIdx.x;
  __shared__ __align__(16) unsigned short xb[4*NRW*22*8];
  __shared__ float scl[32], shl[32];
  __shared__ float pS[64], pQ[64];
  unsigned int* xw = (unsigned int*)xb;
  for (int i = t; i < 4*NRW*22*8/2; i += 256) xw[i] = 0u;
  if (t < 32) { scl[t] = sc[t]; shl[t] = sh[t]; }
  __syncthreads();
  int row0 = half*8;
  const float* Sb = S + (size_t)b*32*HW;
  if (t < HW) {
    int py = t/15, px = t - (t/15)*15;
    int gp = py + 3;
    if (gp >= row0 && gp < row0 + NRW) {
      int rr = gp - row0, xp = px + 3;
      #pragma unroll
      for (int g0 = 0; g0 < 4; ++g0) {
        U8 tb;
        #pragma unroll
        for (int k = 0; k < 8; ++k)
          tb.u[k] = f2bf(fmaxf(Sb[(g0*8+k)*HW + t]*scl[g0*8+k] + shl[g0*8+k], 0.f));
        *(short8*)&xb[((g0*NRW + rr)*22 + xp)*8] = tb.v;
      }
    }
  }
  __syncthreads();
  int w = t >> 6, l = t & 63, g = l >> 4, x = l & 15;
  int ct = cg*4 + w;
  f32x4 acc[8] = {};
  const short8* wp = (const short8*)Wb;
  for (int dx = 0; dx < 7; ++dx) {
    short8 aw[7];
    #pragma unroll
    for (int dy = 0; dy < 7; ++dy)
      aw[dy] = wp[((dx*7 + dy)*8 + ct)*64 + l];
    #pragma unroll
    for (int rs = 0; rs < 14; ++rs) {
      short8 bf = *(const short8*)&xb[((g*NRW + rs)*22 + x + dx)*8];
      #pragma unroll
      for (int r = 0; r < 8; ++r) {
        int dy = rs - r;
        if (dy >= 0 && dy <= 6)
          acc[r] = __builtin_amdgcn_mfma_f32_16x16x32_bf16(aw[dy], bf, acc[r], 0, 0, 0);
      }
    }
  }
  float ls[4] = {}, lq[4] = {};
  #pragma unroll
  for (int r = 0; r < 8; ++r) {
    int nt = row0 + r;
    bool valid = (x < 15) && (nt < 15);
    if (valid) {
      float* out = O + ((size_t)b*CC + ct*16 + g*4)*HW + nt*15 + x;
      #pragma unroll
      for (int q = 0; q < 4; ++q) out[q*HW] = acc[r][q];
    }
    #pragma unroll
    for (int q = 0; q < 4; ++q) {
      float v = valid ? acc[r][q] : 0.f;
      ls[q] += v; lq[q] += v*v;
    }
  }
  #pragma unroll
  for (int q = 0; q < 4; ++q) {
    float s = ls[q], qq = lq[q];
    #pragma unroll
    for (int m = 1; m < 16; m <<= 1) { s += __shfl_xor(s, m); qq += __shfl_xor(qq, m); }
    if (x == 0) { pS[w*16 + g*4 + q] = s; pQ[w*16 + g*4 + q] = qq; }
  }
  __syncthreads();
  if (t < 64) {
    int c = cg*64 + t;
    ps[(size_t)c*NPMAX + b*2 + half] = pS[t];
    pq[(size_t)c*NPMAX + b*2 + half] = pQ[t];
  }
}

// ---------- final: D *= sigmoid(bn5(A)), float4 ----------
__global__ __launch_bounds__(256) void k_final4(f32x4* __restrict__ D, const f32x4* __restrict__ A,
                        const float* __restrict__ sc, const float* __restrict__ sh) {
  size_t i = (size_t)blockIdx.x*256 + threadIdx.x;
  f32x4 a = A[i], d = D[i];
  size_t e = i*4;
  #pragma unroll
  for (int k = 0; k < 4; ++k) {
    int c = (int)(((e + k) / HW) % CC);
    float s = a[k]*sc[c] + sh[c];
    d[k] *= 1.f/(1.f + expf(-s));
  }
  D[i] = d;
}

extern "C" void kernel_launch(void* const* d_in, const int* in_sizes, int n_in,
                              void* d_out, int out_size, void* d_ws, size_t ws_size,
                              hipStream_t stream) {
  (void)in_sizes; (void)n_in; (void)out_size;
  const float* x1    = (const float*)d_in[0];
  const float* x2    = (const float*)d_in[1];
  const float* lam   = (const float*)d_in[2];
  const float* bn1_g = (const float*)d_in[3];
  const float* bn1_b = (const float*)d_in[4];
  const float* pW1   = (const float*)d_in[5];
  const float* dW1   = (const float*)d_in[6];
  const float* db1   = (const float*)d_in[7];
  const float* bn2_g = (const float*)d_in[8];
  const float* bn2_b = (const float*)d_in[9];
  const float* pW2   = (const float*)d_in[10];
  const float* dW2   = (const float*)d_in[11];
  const float* db2   = (const float*)d_in[12];
  const float* qkvW  = (const float*)d_in[13];
  const float* bn3_g = (const float*)d_in[14];
  const float* bn3_b = (const float*)d_in[15];
  const float* ca_w1 = (const float*)d_in[16];
  const float* ca_b1 = (const float*)d_in[17];
  const float* ca_w2 = (const float*)d_in[18];
  const float* ca_b2 = (const float*)d_in[19];
  const float* sa_w1 = (const float*)d_in[20];
  const float* sbn1_g= (const float*)d_in[22];
  const float* sbn1_b= (const float*)d_in[23];
  const float* sa_w2 = (const float*)d_in[24];
  const float* sbn2_g= (const float*)d_in[26];
  const float* sbn2_b= (const float*)d_in[27];

  float* D = (float*)d_out;
  float* A = (float*)d_ws;                          // (512,128,225) f32
  float* S = A + (size_t)BB*CC*HW;                  // (512,32,225)  f32
  float* part = S + (size_t)BB*32*HW;               // 512*4*3*256 f32
  float* st = part + (size_t)BB*4*3*256;            // 1280 f32 stats
  float *sc1 = st,      *sh1 = st+128,  *sc2 = st+256, *sh2 = st+384,
        *sc3 = st+512,  *sh3 = st+640,  *sc4 = st+768, *sh4 = st+800,
        *sc5 = st+832,  *sh5 = st+960;
  float* ps = st + 1280;                            // 128*NPMAX
  float* pq = ps + (size_t)CC*NPMAX;                // 128*NPMAX
  float* cent = pq + (size_t)CC*NPMAX;              // 512*128
  float* sim  = cent + (size_t)BB*CC;               // 512*225
  float* am   = sim + (size_t)BB*HW;                // 512*225
  unsigned short* Wa  = (unsigned short*)(am + (size_t)BB*HW);
  unsigned short* Wb  = Wa + 49*4096;
  unsigned short* W1h = Wb + 49*4096;
  unsigned short* W1l = W1h + 16384;
  unsigned short* W2h = W1l + 16384;
  unsigned short* W2l = W2h + 16384;
  unsigned short* Wk  = W2l + 16384;
  unsigned short* Wv  = Wk  + 16384;
  unsigned short* Wc1 = Wv  + 16384;
  unsigned short* Wc2 = Wc1 + 4096;
  unsigned short* D2  = Wc2 + 4096;                 // (512,225,136) bf16
  unsigned short* X2  = D2 + (size_t)BB*HW*CIP;     // (512,16,225,8) bf16
  size_t needD2 = (size_t)((char*)(D2 + (size_t)BB*HW*CIP) - (char*)d_ws);
  size_t needX2 = (size_t)((char*)(X2 + (size_t)BB*16*HW*8) - (char*)d_ws);
  bool useD2 = ws_size >= needD2;
  bool useX2 = ws_size >= needX2;

  const int NB4 = BB*4;

  k_prep_all<<<1792, 256, 0, stream>>>(sa_w1, sa_w2, pW1, pW2, qkvW, ca_w1, ca_w2,
                                       Wa, Wb, W1h, W1l, W2h, W2l, Wk, Wv, Wc1, Wc2);

  k_at1a <<<dim3(BB,4), 256, 0, stream>>>(x1, x2, part);
  k_at1b <<<BB, 256, 0, stream>>>(x1, x2, part, lam, am);
  k_at1c <<<dim3(BB,4), 256, 0, stream>>>(x1, x2, am, A, ps, pq);
  k_bnfin2<<<CC, 256, 0, stream>>>(ps, pq, BB, bn1_g, bn1_b, sc1, sh1);
  k_pw_v3<1><<<NB4, 256, 0, stream>>>(A, W1h, W1l, sc1, sh1, dW1, db1, ps, pq);
  k_bnfin2<<<CC, 256, 0, stream>>>(ps, pq, NB4, bn2_g, bn2_b, sc2, sh2);
  k_pw_v3<2><<<NB4, 256, 0, stream>>>(A, W2h, W2l, sc2, sh2, nullptr, nullptr, nullptr, nullptr);
  k_dw3   <<<dim3(BB,8), 256, 0, stream>>>(A, dW2, db2, useX2 ? X2 : nullptr);
  k_cent  <<<BB, 128, 0, stream>>>(A, qkvW, cent);
  if (useX2) k_attn2a<1><<<NB4, 256, 0, stream>>>(A, X2, cent, Wk, sim);
  else       k_attn2a<0><<<NB4, 256, 0, stream>>>(A, nullptr, cent, Wk, sim);
  k_soft  <<<BB, 256, 0, stream>>>(sim);
  if (useX2) k_attn2b<1><<<NB4, 256, 0, stream>>>(A, X2, sim, Wv, ps, pq);
  else       k_attn2b<0><<<NB4, 256, 0, stream>>>(A, nullptr, sim, Wv, ps, pq);
  k_bnfin2<<<CC, 256, 0, stream>>>(ps, pq, NB4, bn3_g, bn3_b, sc3, sh3);
  k_chatt_v3<<<NB4, 256, 0, stream>>>(A, D, useD2 ? D2 : nullptr, sc3, sh3, Wc1, ca_b1, Wc2, ca_b2);
  if (useD2) k_conv7a_mfma<1><<<dim3(BB,2), 256, 0, stream>>>(D, D2, Wa, S, ps, pq);
  else       k_conv7a_mfma<0><<<dim3(BB,2), 256, 0, stream>>>(D, nullptr, Wa, S, ps, pq);
  k_bnfin2<<<32, 256, 0, stream>>>(ps, pq, BB*2, sbn1_g, sbn1_b, sc4, sh4);
  k_conv7b_mfma<<<dim3(BB,2,2), 256, 0, stream>>>(S, sc4, sh4, Wb, A, ps, pq);
  k_bnfin2<<<CC, 256, 0, stream>>>(ps, pq, BB*2, sbn2_g, sbn2_b, sc5, sh5);
  k_final4<<<(BB*CC*HW)/1024, 256, 0, stream>>>((f32x4*)D, (const f32x4*)A, sc5, sh5);
}

// Round 17
// 470.571 us; speedup vs baseline: 1.6268x; 1.0146x over previous
//
#include <hip/hip_runtime.h>
#include <hip/hip_bf16.h>
#include <cmath>

#define BB 512
#define CC 128
#define HW 225
#define CIP 136     // ushort stride of D2 [px][ci] rows (272 B)
#define CIPH 40     // ushort stride for 32-ch hidden rows
#define NPMAX 2048  // max partial-stat blocks
#define NRW 14      // padded-row window for row-split convs
#define OCT (NRW*22*8 + 8)   // padded per-octet LDS stride (ushorts): +16B breaks g-aliasing

typedef __attribute__((ext_vector_type(8))) short short8;
typedef __attribute__((ext_vector_type(4))) float f32x4;
typedef __attribute__((ext_vector_type(4))) unsigned short us4;

union U8 { unsigned short u[8]; short8 v; };

__device__ __forceinline__ unsigned short f2bf(float v) {
  __hip_bfloat16 h = __float2bfloat16(v);
  return *(unsigned short*)&h;
}
__device__ __forceinline__ float bf2f(unsigned short u) {
  __hip_bfloat16 h = *(__hip_bfloat16*)&u;
  return __bfloat162float(h);
}

template<int NT>
__device__ __forceinline__ float br_max(float v, float* red, int t) {
  red[t] = v; __syncthreads();
  for (int st = NT/2; st > 0; st >>= 1) { if (t < st) red[t] = fmaxf(red[t], red[t+st]); __syncthreads(); }
  float r = red[0]; __syncthreads();
  return r;
}
template<int NT>
__device__ __forceinline__ float br_sum(float v, float* red, int t) {
  red[t] = v; __syncthreads();
  for (int st = NT/2; st > 0; st >>= 1) { if (t < st) red[t] += red[t+st]; __syncthreads(); }
  float r = red[0]; __syncthreads();
  return r;
}

// finalize fused per-block partials ps/pq[c][NPMAX], np valid slots
__global__ __launch_bounds__(256) void k_bnfin2(const float* __restrict__ ps, const float* __restrict__ pq,
                         int np,
                         const float* __restrict__ g, const float* __restrict__ bt,
                         float* __restrict__ scale, float* __restrict__ shift) {
  int c = blockIdx.x, t = threadIdx.x;
  __shared__ float rs[256], rq[256];
  float s = 0.f, q = 0.f;
  for (int i = t; i < np; i += 256) { s += ps[(size_t)c*NPMAX + i]; q += pq[(size_t)c*NPMAX + i]; }
  rs[t] = s; rq[t] = q; __syncthreads();
  for (int st = 128; st > 0; st >>= 1) { if (t < st) { rs[t]+=rs[t+st]; rq[t]+=rq[t+st]; } __syncthreads(); }
  if (t == 0) {
    const float N = (float)BB*HW;
    float mean = rs[0]/N, var = rq[0]/N - mean*mean;
    float sc = g[c]*rsqrtf(var + 1e-5f);
    scale[c] = sc; shift[c] = bt[c] - mean*sc;
  }
}

// ---------- attn1 stage A ----------
__global__ __launch_bounds__(256) void k_at1a(const float* __restrict__ x1, const float* __restrict__ x2,
                       float* __restrict__ part) {
  int b = blockIdx.x, cg = blockIdx.y, t = threadIdx.x;
  __shared__ float cent[32];
  const float* xb1 = x1 + (size_t)b*64*HW;
  const float* xb2 = x2 + (size_t)b*64*HW;
  if (t < 32) { int c = cg*32 + t; cent[t] = (c < 64) ? xb1[c*HW + 112] : xb2[(c-64)*HW + 112]; }
  __syncthreads();
  if (t < HW) {
    float e2 = 0.f, dot = 0.f, qn2 = 0.f;
    for (int k = 0; k < 32; ++k) {
      int c = cg*32 + k;
      float xv = (c < 64) ? xb1[c*HW + t] : xb2[(c-64)*HW + t];
      float ce = cent[k];
      float d = xv - ce;
      e2 += d*d; dot += xv*ce; qn2 += xv*xv;
    }
    size_t base = ((size_t)(b*4 + cg)*3)*256;
    part[base + t] = e2; part[base + 256 + t] = dot; part[base + 512 + t] = qn2;
  }
}

// ---------- attn1 stage B ----------
__global__ __launch_bounds__(256) void k_at1b(const float* __restrict__ x1, const float* __restrict__ x2,
                       const float* __restrict__ part, const float* __restrict__ lam,
                       float* __restrict__ am) {
  int b = blockIdx.x, t = threadIdx.x;
  __shared__ float red[256];
  float cv = 0.f;
  if (t < CC) {
    float ce = (t < 64) ? x1[(size_t)b*64*HW + t*HW + 112] : x2[(size_t)b*64*HW + (t-64)*HW + 112];
    cv = ce*ce;
  }
  float cn2 = br_sum<256>(cv, red, t);
  float e2 = 0.f, dot = 0.f, qn2 = 0.f;
  if (t < HW) {
    #pragma unroll
    for (int cg = 0; cg < 4; ++cg) {
      size_t base = ((size_t)(b*4 + cg)*3)*256;
      e2 += part[base + t]; dot += part[base + 256 + t]; qn2 += part[base + 512 + t];
    }
  }
  float sim_e = 0.f, sim_c = 0.f;
  if (t < HW) {
    sim_e = 1.f/(1.f + sqrtf(e2));
    float qn = sqrtf(qn2), cn = sqrtf(cn2);
    sim_c = dot / (fmaxf(cn, 1e-8f) * fmaxf(qn, 1e-8f));
  }
  float m1 = br_max<256>((t<HW)? sim_e : -1e30f, red, t);
  float e1v = (t<HW)? expf(sim_e - m1) : 0.f;
  float s1 = br_sum<256>(e1v, red, t);
  float m2 = br_max<256>((t<HW)? sim_c : -1e30f, red, t);
  float e2v = (t<HW)? expf(sim_c - m2) : 0.f;
  float s2 = br_sum<256>(e2v, red, t);
  float lmd = 1.f/(1.f + expf(-lam[0]));
  if (t < HW) am[(size_t)b*HW + t] = 1.f + lmd*e1v/s1 + (1.f - lmd)*e2v/s2;
}

// ---------- attn1 stage C ----------
__global__ __launch_bounds__(256) void k_at1c(const float* __restrict__ x1, const float* __restrict__ x2,
                       const float* __restrict__ am, float* __restrict__ A,
                       float* __restrict__ ps, float* __restrict__ pq) {
  int b = blockIdx.x, cg = blockIdx.y, t = threadIdx.x;
  __shared__ float pS[4][32], pQ[4][32];
  const float* xb1 = x1 + (size_t)b*64*HW;
  const float* xb2 = x2 + (size_t)b*64*HW;
  float* Ab = A + (size_t)b*CC*HW;
  float amv = (t < HW) ? am[(size_t)b*HW + t] : 0.f;
  int w = t >> 6, lane = t & 63;
  for (int k = 0; k < 32; ++k) {
    int c = cg*32 + k;
    float xv = 0.f;
    if (t < HW) xv = (c < 64) ? xb1[c*HW + t] : xb2[(c-64)*HW + t];
    float val = xv*amv;
    if (t < HW) Ab[(size_t)c*HW + t] = val;
    float s = val, q = val*val;
    #pragma unroll
    for (int m = 1; m < 64; m <<= 1) { s += __shfl_xor(s, m); q += __shfl_xor(q, m); }
    if (lane == 0) { pS[w][k] = s; pQ[w][k] = q; }
  }
  __syncthreads();
  if (t < 32) {
    int c = cg*32 + t;
    ps[(size_t)c*NPMAX + b] = pS[0][t]+pS[1][t]+pS[2][t]+pS[3][t];
    pq[(size_t)c*NPMAX + b] = pQ[0][t]+pQ[1][t]+pQ[2][t]+pQ[3][t];
  }
}

// ---------- merged weight pre-pack ----------
// Wa: [ck(4)][dx(7)][dy(7)][ct(2)][lane64][j8]
// Wb: [dx(7)][dy(7)][ct(8)][lane64][j8]
__global__ __launch_bounds__(256) void k_prep_all(
    const float* __restrict__ sa_w1, const float* __restrict__ sa_w2,
    const float* __restrict__ pW1, const float* __restrict__ pW2,
    const float* __restrict__ qkvW, const float* __restrict__ ca_w1, const float* __restrict__ ca_w2,
    unsigned short* __restrict__ Wa, unsigned short* __restrict__ Wb,
    unsigned short* __restrict__ W1h, unsigned short* __restrict__ W1l,
    unsigned short* __restrict__ W2h, unsigned short* __restrict__ W2l,
    unsigned short* __restrict__ Wk, unsigned short* __restrict__ Wv,
    unsigned short* __restrict__ Wc1, unsigned short* __restrict__ Wc2) {
  int id = blockIdx.x*256 + threadIdx.x;
  const int NA = 49*4096;
  if (id < NA) {
    int j = id & 7, l = (id >> 3) & 63, ct = (id >> 9) & 1;
    int r = id >> 10;
    int dy = r % 7; r /= 7;
    int dx = r % 7; int ck = r / 7;
    int co = ct*16 + (l & 15);
    int ci = ck*32 + ((l >> 4) << 3) + j;
    Wa[id] = f2bf(sa_w1[(co*128 + ci)*49 + dy*7 + dx]);
    return;
  }
  id -= NA;
  if (id < NA) {
    int j = id & 7, l = (id >> 3) & 63, ct = (id >> 9) & 7;
    int r = id >> 12;
    int dy = r % 7, dx = r / 7;
    int co = ct*16 + (l & 15);
    int ci = ((l >> 4) << 3) + j;
    Wb[id] = f2bf(sa_w2[(co*32 + ci)*49 + dy*7 + dx]);
    return;
  }
  id -= NA;
  if (id < 16384) {
    int j = id & 7, l = (id >> 3) & 63, ct = (id >> 9) & 7, cs = id >> 12;
    int co = ct*16 + (l & 15);
    int ci = cs*32 + ((l >> 4) << 3) + j;
    float v = pW1[co*128 + ci];
    __hip_bfloat16 h = __float2bfloat16(v);
    W1h[id] = *(unsigned short*)&h;
    W1l[id] = f2bf(v - __bfloat162float(h));
    return;
  }
  id -= 16384;
  if (id < 16384) {
    int j = id & 7, l = (id >> 3) & 63, ct = (id >> 9) & 7, cs = id >> 12;
    int co = ct*16 + (l & 15);
    int ci = cs*32 + ((l >> 4) << 3) + j;
    float v = pW2[co*128 + ci];
    __hip_bfloat16 h = __float2bfloat16(v);
    W2h[id] = *(unsigned short*)&h;
    W2l[id] = f2bf(v - __bfloat162float(h));
    return;
  }
  id -= 16384;
  if (id < 16384) {
    int j = id & 7, l = (id >> 3) & 63, ct = (id >> 9) & 7, cs = id >> 12;
    int co = ct*16 + (l & 15);
    int ci = cs*32 + ((l >> 4) << 3) + j;
    Wk[id] = f2bf(qkvW[(size_t)(128 + co)*128 + ci]);
    Wv[id] = f2bf(qkvW[(size_t)(256 + co)*128 + ci]);
    return;
  }
  id -= 16384;
  if (id < 4096) {
    int j = id & 7, l = (id >> 3) & 63, ct = (id >> 9) & 1, cs = (id >> 10) & 3;
    int co = ct*16 + (l & 15);
    int ci = cs*32 + ((l >> 4) << 3) + j;
    Wc1[id] = f2bf(ca_w1[co*128 + ci]);
    return;
  }
  id -= 4096;
  {
    int j = id & 7, l = (id >> 3) & 63, ct = (id >> 9) & 7;
    int co = ct*16 + (l & 15);
    int ci = ((l >> 4) << 3) + j;
    Wc2[id] = f2bf(ca_w2[co*32 + ci]);
  }
}

// ---------- fused BN + 1x1 conv, pixel-tile GEMM, ct-split waves, in-place ----------
template<int MODE>
__global__ __launch_bounds__(256) void k_pw_v3(float* __restrict__ A,
        const unsigned short* __restrict__ Whi, const unsigned short* __restrict__ Wlo,
        const float* __restrict__ scale, const float* __restrict__ shift,
        const float* __restrict__ dw, const float* __restrict__ db,
        float* __restrict__ ps, float* __restrict__ pq) {
  int blk = blockIdx.x;
  int b = blk >> 2, tile = blk & 3, p0 = tile*64;
  int t = threadIdx.x;
  __shared__ __align__(16) unsigned short xh[16*64*8];
  __shared__ __align__(16) unsigned short xl[16*64*8];
  __shared__ float scl[CC], shf[CC], dwl[CC], dbl[CC];
  __shared__ float pS[CC], pQ[CC];
  if (t < CC) {
    scl[t] = scale[t]; shf[t] = shift[t];
    if (MODE == 1) { dwl[t] = dw[t]; dbl[t] = db[t]; }
  }
  __syncthreads();
  float* Ab = A + (size_t)b*CC*HW;
  {
    int px = t & 63, cig = t >> 6;
    int p = p0 + px;
    bool pv = p < HW;
    #pragma unroll
    for (int k0 = 0; k0 < 32; k0 += 8) {
      U8 th, tl;
      #pragma unroll
      for (int j = 0; j < 8; ++j) {
        int ci = cig*32 + k0 + j;
        float v = pv ? Ab[(size_t)ci*HW + p]*scl[ci] + shf[ci] : 0.f;
        __hip_bfloat16 h = __float2bfloat16(v);
        th.u[j] = *(unsigned short*)&h;
        tl.u[j] = f2bf(v - __bfloat162float(h));
      }
      int oo = cig*4 + (k0 >> 3);
      *(short8*)&xh[(oo*64 + px)*8] = th.v;
      *(short8*)&xl[(oo*64 + px)*8] = tl.v;
    }
  }
  __syncthreads();
  int w = t >> 6, l = t & 63, g = l >> 4, n = l & 15;
  const short8* whp = (const short8*)Whi;
  const short8* wlp = (const short8*)Wlo;
  short8 ah[4][2], al[4][2];
  #pragma unroll
  for (int cs = 0; cs < 4; ++cs)
    #pragma unroll
    for (int ctl = 0; ctl < 2; ++ctl) {
      ah[cs][ctl] = whp[(cs*8 + w*2 + ctl)*64 + l];
      al[cs][ctl] = wlp[(cs*8 + w*2 + ctl)*64 + l];
    }
  float ls[2][4] = {}, lq[2][4] = {};
  for (int pt = 0; pt < 4; ++pt) {
    int p = p0 + pt*16 + n;
    bool pv = p < HW;
    short8 bh[4], bl[4];
    #pragma unroll
    for (int cs = 0; cs < 4; ++cs) {
      bh[cs] = *(const short8*)&xh[((cs*4 + g)*64 + pt*16 + n)*8];
      bl[cs] = *(const short8*)&xl[((cs*4 + g)*64 + pt*16 + n)*8];
    }
    f32x4 acc[2] = {};
    #pragma unroll
    for (int cs = 0; cs < 4; ++cs)
      #pragma unroll
      for (int ctl = 0; ctl < 2; ++ctl) {
        acc[ctl] = __builtin_amdgcn_mfma_f32_16x16x32_bf16(ah[cs][ctl], bh[cs], acc[ctl], 0, 0, 0);
        acc[ctl] = __builtin_amdgcn_mfma_f32_16x16x32_bf16(ah[cs][ctl], bl[cs], acc[ctl], 0, 0, 0);
        acc[ctl] = __builtin_amdgcn_mfma_f32_16x16x32_bf16(al[cs][ctl], bh[cs], acc[ctl], 0, 0, 0);
      }
    #pragma unroll
    for (int ctl = 0; ctl < 2; ++ctl)
      #pragma unroll
      for (int r = 0; r < 4; ++r) {
        int co = (w*2 + ctl)*16 + g*4 + r;
        float y = acc[ctl][r];
        y = (y >= 0.f) ? y : 0.01f*y;
        if (MODE == 1) { y = y*dwl[co] + dbl[co]; y = fmaxf(y, 0.f); }
        if (pv) Ab[(size_t)co*HW + p] = y;
        if (MODE == 1) {
          float vs = pv ? y : 0.f;
          ls[ctl][r] += vs; lq[ctl][r] += vs*vs;
        }
      }
  }
  if (MODE == 1) {
    #pragma unroll
    for (int ctl = 0; ctl < 2; ++ctl)
      #pragma unroll
      for (int r = 0; r < 4; ++r) {
        float s = ls[ctl][r], q = lq[ctl][r];
        #pragma unroll
        for (int m = 1; m < 16; m <<= 1) { s += __shfl_xor(s, m); q += __shfl_xor(q, m); }
        if (n == 0) { pS[(w*2 + ctl)*16 + g*4 + r] = s; pQ[(w*2 + ctl)*16 + g*4 + r] = q; }
      }
    __syncthreads();
    if (t < CC) {
      ps[(size_t)t*NPMAX + blk] = pS[t];
      pq[(size_t)t*NPMAX + blk] = pQ[t];
    }
  }
}

// ---------- depthwise 3x3 pad1 + bias + relu, grid (B, 8 ch-groups); emits bf16 X2 ----------
__global__ __launch_bounds__(256) void k_dw3(float* __restrict__ A, const float* __restrict__ w,
                      const float* __restrict__ db, unsigned short* __restrict__ X2) {
  int b = blockIdx.x, cg = blockIdx.y, t = threadIdx.x;
  __shared__ float xin[16][HW];
  float* Ab = A + ((size_t)b*CC + cg*16)*HW;
  for (int i = t; i < 16*HW; i += 256) xin[i/HW][i%HW] = Ab[i];
  __syncthreads();
  if (t < HW) {
    int y = t/15, x = t - y*15;
    U8 o0, o1;
    for (int c = 0; c < 16; ++c) {
      int ch = cg*16 + c;
      float acc = db[ch];
      #pragma unroll
      for (int ky = 0; ky < 3; ++ky) {
        int iy = y + ky - 1;
        if (iy < 0 || iy >= 15) continue;
        #pragma unroll
        for (int kx = 0; kx < 3; ++kx) {
          int ix = x + kx - 1;
          if (ix < 0 || ix >= 15) continue;
          acc += w[ch*9 + ky*3 + kx]*xin[c][iy*15 + ix];
        }
      }
      float val = fmaxf(acc, 0.f);
      Ab[c*HW + t] = val;
      if (c < 8) o0.u[c] = f2bf(val); else o1.u[c-8] = f2bf(val);
    }
    if (X2) {
      *(short8*)&X2[(((size_t)b*16 + cg*2 + 0)*HW + t)*8] = o0.v;
      *(short8*)&X2[(((size_t)b*16 + cg*2 + 1)*HW + t)*8] = o1.v;
    }
  }
}

// ---------- attn2 stage 1: center Q projection ----------
__global__ __launch_bounds__(128) void k_cent(const float* __restrict__ A,
        const float* __restrict__ Wq, float* __restrict__ cent) {
  int b = blockIdx.x, t = threadIdx.x;
  __shared__ float xc[CC];
  const float* Ab = A + (size_t)b*CC*HW;
  xc[t] = bf2f(f2bf(Ab[(size_t)t*HW + 112]));
  __syncthreads();
  const float* wq = Wq + (size_t)t*CC;
  float acc = 0.f;
  for (int ci = 0; ci < CC; ++ci) acc += wq[ci]*xc[ci];
  cent[(size_t)b*CC + t] = acc;
}

// ---------- attn2 stage 2: K-proj + e2 logits ----------
template<int USEX2>
__global__ __launch_bounds__(256) void k_attn2a(const float* __restrict__ A,
        const unsigned short* __restrict__ X2,
        const float* __restrict__ cent, const unsigned short* __restrict__ Wk,
        float* __restrict__ sim) {
  int blk = blockIdx.x;
  int b = blk >> 2, tile = blk & 3, p0 = tile*64;
  int t = threadIdx.x;
  __shared__ __align__(16) unsigned short xh[16*64*8];
  __shared__ float cl[CC];
  const float* Ab = A + (size_t)b*CC*HW;
  if (t < CC) cl[t] = cent[(size_t)b*CC + t];
  {
    int px = t & 63, cig = t >> 6;
    int p = p0 + px;
    bool pv = p < HW;
    #pragma unroll
    for (int k0 = 0; k0 < 32; k0 += 8) {
      int oo = cig*4 + (k0>>3);
      short8 v;
      if (USEX2) {
        v = pv ? *(const short8*)&X2[(((size_t)b*16 + oo)*HW + p)*8] : short8{};
      } else {
        U8 th;
        #pragma unroll
        for (int j = 0; j < 8; ++j) {
          int ci = cig*32 + k0 + j;
          th.u[j] = pv ? f2bf(Ab[(size_t)ci*HW + p]) : 0;
        }
        v = th.v;
      }
      *(short8*)&xh[(oo*64 + px)*8] = v;
    }
  }
  __syncthreads();
  int w = t >> 6, l = t & 63, g = l >> 4, n = l & 15;
  int p = p0 + w*16 + n;
  bool pv = p < HW;
  const short8* wkp = (const short8*)Wk;
  short8 bf[4];
  #pragma unroll
  for (int cs = 0; cs < 4; ++cs)
    bf[cs] = *(const short8*)&xh[((cs*4 + g)*64 + w*16 + n)*8];
  float e2p = 0.f;
  #pragma unroll
  for (int ct = 0; ct < 8; ++ct) {
    f32x4 k = {};
    #pragma unroll
    for (int cs = 0; cs < 4; ++cs)
      k = __builtin_amdgcn_mfma_f32_16x16x32_bf16(wkp[(cs*8 + ct)*64 + l], bf[cs], k, 0, 0, 0);
    #pragma unroll
    for (int r = 0; r < 4; ++r) { float d = cl[ct*16 + g*4 + r] - k[r]; e2p += d*d; }
  }
  e2p += __shfl_xor(e2p, 16);
  e2p += __shfl_xor(e2p, 32);
  if (g == 0 && pv) sim[(size_t)b*HW + p] = 1.f/(1.f + sqrtf(e2p));
}

// ---------- attn2 stage 3: per-image softmax ----------
__global__ __launch_bounds__(256) void k_soft(float* __restrict__ sim) {
  int b = blockIdx.x, t = threadIdx.x;
  __shared__ float red[256];
  float val = (t < HW) ? sim[(size_t)b*HW + t] : -1e30f;
  float m = br_max<256>(val, red, t);
  float e = (t < HW) ? expf(val - m) : 0.f;
  float s = br_sum<256>(e, red, t);
  if (t < HW) sim[(size_t)b*HW + t] = e/s;
}

// ---------- attn2 stage 4: V-proj + residual + fused bn3 stats ----------
template<int USEX2>
__global__ __launch_bounds__(256) void k_attn2b(float* __restrict__ A,
        const unsigned short* __restrict__ X2,
        const float* __restrict__ att, const unsigned short* __restrict__ Wv,
        float* __restrict__ ps, float* __restrict__ pq) {
  int blk = blockIdx.x;
  int b = blk >> 2, tile = blk & 3, p0 = tile*64;
  int t = threadIdx.x;
  __shared__ __align__(16) unsigned short xh[16*64*8];
  __shared__ float pS[4][CC], pQ[4][CC];
  float* Ab = A + (size_t)b*CC*HW;
  {
    int px = t & 63, cig = t >> 6;
    int p = p0 + px;
    bool pv = p < HW;
    #pragma unroll
    for (int k0 = 0; k0 < 32; k0 += 8) {
      int oo = cig*4 + (k0>>3);
      short8 v;
      if (USEX2) {
        v = pv ? *(const short8*)&X2[(((size_t)b*16 + oo)*HW + p)*8] : short8{};
      } else {
        U8 th;
        #pragma unroll
        for (int j = 0; j < 8; ++j) {
          int ci = cig*32 + k0 + j;
          th.u[j] = pv ? f2bf(Ab[(size_t)ci*HW + p]) : 0;
        }
        v = th.v;
      }
      *(short8*)&xh[(oo*64 + px)*8] = v;
    }
  }
  __syncthreads();
  int w = t >> 6, l = t & 63, g = l >> 4, n = l & 15;
  int p = p0 + w*16 + n;
  bool pv = p < HW;
  float ap = pv ? att[(size_t)b*HW + p] : 0.f;
  const short8* wvp = (const short8*)Wv;
  short8 bf[4];
  #pragma unroll
  for (int cs = 0; cs < 4; ++cs)
    bf[cs] = *(const short8*)&xh[((cs*4 + g)*64 + w*16 + n)*8];
  #pragma unroll
  for (int ct = 0; ct < 8; ++ct) {
    f32x4 v = {};
    #pragma unroll
    for (int cs = 0; cs < 4; ++cs)
      v = __builtin_amdgcn_mfma_f32_16x16x32_bf16(wvp[(cs*8 + ct)*64 + l], bf[cs], v, 0, 0, 0);
    #pragma unroll
    for (int r = 0; r < 4; ++r) {
      int co = ct*16 + g*4 + r;
      float val = 0.f;
      if (pv) {
        val = ap*v[r] + Ab[(size_t)co*HW + p];
        Ab[(size_t)co*HW + p] = val;
      }
      float s = val, q = val*val;
      #pragma unroll
      for (int m = 1; m < 16; m <<= 1) { s += __shfl_xor(s, m); q += __shfl_xor(q, m); }
      if (n == 0) { pS[w][co] = s; pQ[w][co] = q; }
    }
  }
  __syncthreads();
  if (t < CC) {
    ps[(size_t)t*NPMAX + blk] = pS[0][t]+pS[1][t]+pS[2][t]+pS[3][t];
    pq[(size_t)t*NPMAX + blk] = pQ[0][t]+pQ[1][t]+pQ[2][t]+pQ[3][t];
  }
}

// ---------- BN3 + channel-attention gate; writes D (+ bf16 D2) ----------
__global__ __launch_bounds__(256) void k_chatt_v3(const float* __restrict__ A, float* __restrict__ D,
        unsigned short* __restrict__ D2,
        const float* __restrict__ sc, const float* __restrict__ sh,
        const unsigned short* __restrict__ Wc1, const float* __restrict__ b1,
        const unsigned short* __restrict__ Wc2, const float* __restrict__ b2) {
  int blk = blockIdx.x;
  int b = blk >> 2, tile = blk & 3, p0 = tile*64;
  int t = threadIdx.x;
  __shared__ __align__(16) unsigned short xh[16*64*8];
  __shared__ __align__(16) unsigned short hb[64*CIPH];
  __shared__ float scl[CC], shl[CC], b2l[CC], b1l[32];
  const float* Ab = A + (size_t)b*CC*HW;
  float* Db = D + (size_t)b*CC*HW;
  if (t < CC) { scl[t] = sc[t]; shl[t] = sh[t]; b2l[t] = b2[t]; }
  if (t < 32) b1l[t] = b1[t];
  __syncthreads();
  {
    int px = t & 63, cig = t >> 6;
    int p = p0 + px;
    bool pv = p < HW;
    #pragma unroll
    for (int k0 = 0; k0 < 32; k0 += 8) {
      U8 th;
      #pragma unroll
      for (int j = 0; j < 8; ++j) {
        int ci = cig*32 + k0 + j;
        th.u[j] = pv ? f2bf(Ab[(size_t)ci*HW + p]*scl[ci] + shl[ci]) : 0;
      }
      *(short8*)&xh[((cig*4 + (k0>>3))*64 + px)*8] = th.v;
    }
  }
  __syncthreads();
  int w = t >> 6, l = t & 63, g = l >> 4, n = l & 15;
  int p = p0 + w*16 + n;
  bool pv = p < HW;
  const short8* w1p = (const short8*)Wc1;
  const short8* w2p = (const short8*)Wc2;
  short8 bf[4];
  #pragma unroll
  for (int cs = 0; cs < 4; ++cs)
    bf[cs] = *(const short8*)&xh[((cs*4 + g)*64 + w*16 + n)*8];
  #pragma unroll
  for (int ct = 0; ct < 2; ++ct) {
    f32x4 a = {};
    #pragma unroll
    for (int cs = 0; cs < 4; ++cs)
      a = __builtin_amdgcn_mfma_f32_16x16x32_bf16(w1p[(cs*2 + ct)*64 + l], bf[cs], a, 0, 0, 0);
    us4 hv;
    #pragma unroll
    for (int r = 0; r < 4; ++r) hv[r] = f2bf(fmaxf(a[r] + b1l[ct*16 + g*4 + r], 0.f));
    *(us4*)&hb[(w*16+n)*CIPH + ct*16 + g*4] = hv;
  }
  __syncthreads();
  short8 hf = *(const short8*)&hb[(w*16+n)*CIPH + g*8];
  #pragma unroll
  for (int ct = 0; ct < 8; ++ct) {
    f32x4 a = __builtin_amdgcn_mfma_f32_16x16x32_bf16(w2p[ct*64 + l], hf, f32x4{}, 0, 0, 0);
    if (pv) {
      us4 dv;
      #pragma unroll
      for (int r = 0; r < 4; ++r) {
        int co = ct*16 + g*4 + r;
        float s = a[r] + b2l[co];
        float gt = 1.f/(1.f + expf(-s));
        float xin = bf2f(xh[((co >> 3)*64 + w*16 + n)*8 + (co & 7)]);
        float o = xin*gt;
        Db[(size_t)co*HW + p] = o;
        dv[r] = f2bf(o);
      }
      if (D2) *(us4*)&D2[((size_t)b*HW + p)*CIP + ct*16 + g*4] = dv;
    }
  }
}

// ---------- 7x7 conv 128->32, row-split, ct/rh-split waves, dy-reuse rs-loop (+ bn4 stats) ----------
template<int USED2>
__global__ __launch_bounds__(256) void k_conv7a_mfma(const float* __restrict__ D,
        const unsigned short* __restrict__ D2,
        const unsigned short* __restrict__ Wa, float* __restrict__ S,
        float* __restrict__ ps, float* __restrict__ pq) {
  int b = blockIdx.x, half = blockIdx.y, t = threadIdx.x;
  __shared__ __align__(16) unsigned short xb[4*OCT];   // padded g-stride, ~19.8 KB
  __shared__ float pS[2][32], pQ[2][32];
  unsigned int* xw = (unsigned int*)xb;
  for (int i = t; i < 4*OCT/2; i += 256) xw[i] = 0u;
  int w = t >> 6, l = t & 63, g = l >> 4, x = l & 15;
  int ct = w & 1, rh = w >> 1;
  int row0 = half*8;
  f32x4 acc[4] = {};
  const short8* wp = (const short8*)Wa;
  bool prow = false; int rr = 0, xp = 0;
  if (t < HW) {
    int py = t/15, px = t - (t/15)*15;
    int gp = py + 3;
    prow = (gp >= row0) && (gp < row0 + NRW);
    rr = gp - row0; xp = px + 3;
  }
  for (int ck = 0; ck < 4; ++ck) {
    __syncthreads();
    if (prow) {
      if (USED2) {
        const unsigned short* src = &D2[((size_t)b*HW + t)*CIP + ck*32];
        #pragma unroll
        for (int g0 = 0; g0 < 4; ++g0)
          *(short8*)&xb[g0*OCT + (rr*22 + xp)*8] = *(const short8*)&src[g0*8];
      } else {
        const float* Dbp = D + ((size_t)b*CC + ck*32)*HW;
        #pragma unroll
        for (int g0 = 0; g0 < 4; ++g0) {
          U8 tb;
          #pragma unroll
          for (int k = 0; k < 8; ++k) tb.u[k] = f2bf(Dbp[(g0*8+k)*HW + t]);
          *(short8*)&xb[g0*OCT + (rr*22 + xp)*8] = tb.v;
        }
      }
    }
    __syncthreads();
    for (int dx = 0; dx < 7; ++dx) {
      short8 aw[7];
      #pragma unroll
      for (int dy = 0; dy < 7; ++dy)
        aw[dy] = wp[(((ck*7 + dx)*7 + dy)*2 + ct)*64 + l];
      #pragma unroll
      for (int rs = 0; rs < 10; ++rs) {
        short8 bf = *(const short8*)&xb[g*OCT + ((rh*4 + rs)*22 + x + dx)*8];
        #pragma unroll
        for (int r = 0; r < 4; ++r) {
          int dy = rs - r;
          if (dy >= 0 && dy <= 6)
            acc[r] = __builtin_amdgcn_mfma_f32_16x16x32_bf16(aw[dy], bf, acc[r], 0, 0, 0);
        }
      }
    }
  }
  float ls[4] = {}, lq[4] = {};
  #pragma unroll
  for (int r = 0; r < 4; ++r) {
    int nt = row0 + rh*4 + r;
    bool valid = (x < 15) && (nt < 15);
    if (valid) {
      float* out = S + ((size_t)b*32 + ct*16 + g*4)*HW + nt*15 + x;
      #pragma unroll
      for (int q = 0; q < 4; ++q) out[q*HW] = acc[r][q];
    }
    #pragma unroll
    for (int q = 0; q < 4; ++q) {
      float v = valid ? acc[r][q] : 0.f;
      ls[q] += v; lq[q] += v*v;
    }
  }
  #pragma unroll
  for (int q = 0; q < 4; ++q) {
    float s = ls[q], qq = lq[q];
    #pragma unroll
    for (int m = 1; m < 16; m <<= 1) { s += __shfl_xor(s, m); qq += __shfl_xor(qq, m); }
    if (x == 0) { pS[rh][ct*16 + g*4 + q] = s; pQ[rh][ct*16 + g*4 + q] = qq; }
  }
  __syncthreads();
  if (t < 32) {
    ps[(size_t)t*NPMAX + b*2 + half] = pS[0][t]+pS[1][t];
    pq[(size_t)t*NPMAX + b*2 + half] = pQ[0][t]+pQ[1][t];
  }
}

// ---------- 7x7 conv 32->128, grid (B,2,2): 1 ct per wave, dy-reuse rs-loop (+ bn5 stats) ----------
__global__ __launch_bounds__(256) void k_conv7b_mfma(const float* __restrict__ S,
        const float* __restrict__ sc, const float* __restrict__ sh,
        const unsigned short* __restrict__ Wb, float* __restrict__ O,
        float* __restrict__ ps, float* __restrict__ pq) {
  int b = blockIdx.x, half = blockIdx.y, cg = blockIdx.z, t = threadIdx.x;
  __shared__ __align__(16) unsigned short xb[4*OCT];
  __shared__ float scl[32], shl[32];
  __shared__ float pS[64], pQ[64];
  unsigned int* xw = (unsigned int*)xb;
  for (int i = t; i < 4*OCT/2; i += 256) xw[i] = 0u;
  if (t < 32) { scl[t] = sc[t]; shl[t] = sh[t]; }
  __syncthreads();
  int row0 = half*8;
  const float* Sb = S + (size_t)b*32*HW;
  if (t < HW) {
    int py = t/15, px = t - (t/15)*15;
    int gp = py + 3;
    if (gp >= row0 && gp < row0 + NRW) {
      int rr = gp - row0, xp = px + 3;
      #pragma unroll
      for (int g0 = 0; g0 < 4; ++g0) {
        U8 tb;
        #pragma unroll
        for (int k = 0; k < 8; ++k)
          tb.u[k] = f2bf(fmaxf(Sb[(g0*8+k)*HW + t]*scl[g0*8+k] + shl[g0*8+k], 0.f));
        *(short8*)&xb[g0*OCT + (rr*22 + xp)*8] = tb.v;
      }
    }
  }
  __syncthreads();
  int w = t >> 6, l = t & 63, g = l >> 4, x = l & 15;
  int ct = cg*4 + w;
  f32x4 acc[8] = {};
  const short8* wp = (const short8*)Wb;
  for (int dx = 0; dx < 7; ++dx) {
    short8 aw[7];
    #pragma unroll
    for (int dy = 0; dy < 7; ++dy)
      aw[dy] = wp[((dx*7 + dy)*8 + ct)*64 + l];
    #pragma unroll
    for (int rs = 0; rs < 14; ++rs) {
      short8 bf = *(const short8*)&xb[g*OCT + (rs*22 + x + dx)*8];
      #pragma unroll
      for (int r = 0; r < 8; ++r) {
        int dy = rs - r;
        if (dy >= 0 && dy <= 6)
          acc[r] = __builtin_amdgcn_mfma_f32_16x16x32_bf16(aw[dy], bf, acc[r], 0, 0, 0);
      }
    }
  }
  float ls[4] = {}, lq[4] = {};
  #pragma unroll
  for (int r = 0; r < 8; ++r) {
    int nt = row0 + r;
    bool valid = (x < 15) && (nt < 15);
    if (valid) {
      float* out = O + ((size_t)b*CC + ct*16 + g*4)*HW + nt*15 + x;
      #pragma unroll
      for (int q = 0; q < 4; ++q) out[q*HW] = acc[r][q];
    }
    #pragma unroll
    for (int q = 0; q < 4; ++q) {
      float v = valid ? acc[r][q] : 0.f;
      ls[q] += v; lq[q] += v*v;
    }
  }
  #pragma unroll
  for (int q = 0; q < 4; ++q) {
    float s = ls[q], qq = lq[q];
    #pragma unroll
    for (int m = 1; m < 16; m <<= 1) { s += __shfl_xor(s, m); qq += __shfl_xor(qq, m); }
    if (x == 0) { pS[w*16 + g*4 + q] = s; pQ[w*16 + g*4 + q] = qq; }
  }
  __syncthreads();
  if (t < 64) {
    int c = cg*64 + t;
    ps[(size_t)c*NPMAX + b*2 + half] = pS[t];
    pq[(size_t)c*NPMAX + b*2 + half] = pQ[t];
  }
}

// ---------- final: D *= sigmoid(bn5(A)), float4 ----------
__global__ __launch_bounds__(256) void k_final4(f32x4* __restrict__ D, const f32x4* __restrict__ A,
                        const float* __restrict__ sc, const float* __restrict__ sh) {
  size_t i = (size_t)blockIdx.x*256 + threadIdx.x;
  f32x4 a = A[i], d = D[i];
  size_t e = i*4;
  #pragma unroll
  for (int k = 0; k < 4; ++k) {
    int c = (int)(((e + k) / HW) % CC);
    float s = a[k]*sc[c] + sh[c];
    d[k] *= 1.f/(1.f + expf(-s));
  }
  D[i] = d;
}

extern "C" void kernel_launch(void* const* d_in, const int* in_sizes, int n_in,
                              void* d_out, int out_size, void* d_ws, size_t ws_size,
                              hipStream_t stream) {
  (void)in_sizes; (void)n_in; (void)out_size;
  const float* x1    = (const float*)d_in[0];
  const float* x2    = (const float*)d_in[1];
  const float* lam   = (const float*)d_in[2];
  const float* bn1_g = (const float*)d_in[3];
  const float* bn1_b = (const float*)d_in[4];
  const float* pW1   = (const float*)d_in[5];
  const float* dW1   = (const float*)d_in[6];
  const float* db1   = (const float*)d_in[7];
  const float* bn2_g = (const float*)d_in[8];
  const float* bn2_b = (const float*)d_in[9];
  const float* pW2   = (const float*)d_in[10];
  const float* dW2   = (const float*)d_in[11];
  const float* db2   = (const float*)d_in[12];
  const float* qkvW  = (const float*)d_in[13];
  const float* bn3_g = (const float*)d_in[14];
  const float* bn3_b = (const float*)d_in[15];
  const float* ca_w1 = (const float*)d_in[16];
  const float* ca_b1 = (const float*)d_in[17];
  const float* ca_w2 = (const float*)d_in[18];
  const float* ca_b2 = (const float*)d_in[19];
  const float* sa_w1 = (const float*)d_in[20];
  const float* sbn1_g= (const float*)d_in[22];
  const float* sbn1_b= (const float*)d_in[23];
  const float* sa_w2 = (const float*)d_in[24];
  const float* sbn2_g= (const float*)d_in[26];
  const float* sbn2_b= (const float*)d_in[27];

  float* D = (float*)d_out;
  float* A = (float*)d_ws;                          // (512,128,225) f32
  float* S = A + (size_t)BB*CC*HW;                  // (512,32,225)  f32
  float* part = S + (size_t)BB*32*HW;               // 512*4*3*256 f32
  float* st = part + (size_t)BB*4*3*256;            // 1280 f32 stats
  float *sc1 = st,      *sh1 = st+128,  *sc2 = st+256, *sh2 = st+384,
        *sc3 = st+512,  *sh3 = st+640,  *sc4 = st+768, *sh4 = st+800,
        *sc5 = st+832,  *sh5 = st+960;
  float* ps = st + 1280;                            // 128*NPMAX
  float* pq = ps + (size_t)CC*NPMAX;                // 128*NPMAX
  float* cent = pq + (size_t)CC*NPMAX;              // 512*128
  float* sim  = cent + (size_t)BB*CC;               // 512*225
  float* am   = sim + (size_t)BB*HW;                // 512*225
  unsigned short* Wa  = (unsigned short*)(am + (size_t)BB*HW);
  unsigned short* Wb  = Wa + 49*4096;
  unsigned short* W1h = Wb + 49*4096;
  unsigned short* W1l = W1h + 16384;
  unsigned short* W2h = W1l + 16384;
  unsigned short* W2l = W2h + 16384;
  unsigned short* Wk  = W2l + 16384;
  unsigned short* Wv  = Wk  + 16384;
  unsigned short* Wc1 = Wv  + 16384;
  unsigned short* Wc2 = Wc1 + 4096;
  unsigned short* D2  = Wc2 + 4096;                 // (512,225,136) bf16
  unsigned short* X2  = D2 + (size_t)BB*HW*CIP;     // (512,16,225,8) bf16
  size_t needD2 = (size_t)((char*)(D2 + (size_t)BB*HW*CIP) - (char*)d_ws);
  size_t needX2 = (size_t)((char*)(X2 + (size_t)BB*16*HW*8) - (char*)d_ws);
  bool useD2 = ws_size >= needD2;
  bool useX2 = ws_size >= needX2;

  const int NB4 = BB*4;

  k_prep_all<<<1792, 256, 0, stream>>>(sa_w1, sa_w2, pW1, pW2, qkvW, ca_w1, ca_w2,
                                       Wa, Wb, W1h, W1l, W2h, W2l, Wk, Wv, Wc1, Wc2);

  k_at1a <<<dim3(BB,4), 256, 0, stream>>>(x1, x2, part);
  k_at1b <<<BB, 256, 0, stream>>>(x1, x2, part, lam, am);
  k_at1c <<<dim3(BB,4), 256, 0, stream>>>(x1, x2, am, A, ps, pq);
  k_bnfin2<<<CC, 256, 0, stream>>>(ps, pq, BB, bn1_g, bn1_b, sc1, sh1);
  k_pw_v3<1><<<NB4, 256, 0, stream>>>(A, W1h, W1l, sc1, sh1, dW1, db1, ps, pq);
  k_bnfin2<<<CC, 256, 0, stream>>>(ps, pq, NB4, bn2_g, bn2_b, sc2, sh2);
  k_pw_v3<2><<<NB4, 256, 0, stream>>>(A, W2h, W2l, sc2, sh2, nullptr, nullptr, nullptr, nullptr);
  k_dw3   <<<dim3(BB,8), 256, 0, stream>>>(A, dW2, db2, useX2 ? X2 : nullptr);
  k_cent  <<<BB, 128, 0, stream>>>(A, qkvW, cent);
  if (useX2) k_attn2a<1><<<NB4, 256, 0, stream>>>(A, X2, cent, Wk, sim);
  else       k_attn2a<0><<<NB4, 256, 0, stream>>>(A, nullptr, cent, Wk, sim);
  k_soft  <<<BB, 256, 0, stream>>>(sim);
  if (useX2) k_attn2b<1><<<NB4, 256, 0, stream>>>(A, X2, sim, Wv, ps, pq);
  else       k_attn2b<0><<<NB4, 256, 0, stream>>>(A, nullptr, sim, Wv, ps, pq);
  k_bnfin2<<<CC, 256, 0, stream>>>(ps, pq, NB4, bn3_g, bn3_b, sc3, sh3);
  k_chatt_v3<<<NB4, 256, 0, stream>>>(A, D, useD2 ? D2 : nullptr, sc3, sh3, Wc1, ca_b1, Wc2, ca_b2);
  if (useD2) k_conv7a_mfma<1><<<dim3(BB,2), 256, 0, stream>>>(D, D2, Wa, S, ps, pq);
  else       k_conv7a_mfma<0><<<dim3(BB,2), 256, 0, stream>>>(D, nullptr, Wa, S, ps, pq);
  k_bnfin2<<<32, 256, 0, stream>>>(ps, pq, BB*2, sbn1_g, sbn1_b, sc4, sh4);
  k_conv7b_mfma<<<dim3(BB,2,2), 256, 0, stream>>>(S, sc4, sh4, Wb, A, ps, pq);
  k_bnfin2<<<CC, 256, 0, stream>>>(ps, pq, BB*2, sbn2_g, sbn2_b, sc5, sh5);
  k_final4<<<(BB*CC*HW)/1024, 256, 0, stream>>>((f32x4*)D, (const f32x4*)A, sc5, sh5);
}